// Round 6
// baseline (4552.440 us; speedup 1.0000x reference)
//
#include <hip/hip_runtime.h>
#include <math.h>

#define NN 131072
#define EE 524288
#define GG 4096

__device__ __forceinline__ float sigmoidf_(float x){ return 1.0f/(1.0f+expf(-x)); }

// ---- grouping / CSR (integer atomics only) --------------------------------
__global__ void k_gptr(const int* batch, int* gptr){
  int g = blockIdx.x*256+threadIdx.x;
  if (g > GG) return;
  if (g == GG){ gptr[GG]=NN; return; }
  int lo=0, hi=NN;
  while(lo<hi){ int mid=(lo+hi)>>1; if(batch[mid]<g) lo=mid+1; else hi=mid; }
  gptr[g]=lo;
}

__global__ void k_deg(const int* dst, int* deg){
  int e = blockIdx.x*256+threadIdx.x;
  if(e<EE) atomicAdd(&deg[dst[e]], 1);
}

__global__ __launch_bounds__(1024) void k_scan(const int* deg, int* rowptr){
  __shared__ int part[1024];
  int t = threadIdx.x;
  int base = t*128;
  int s = 0;
  for(int i=0;i<128;i++) s += deg[base+i];
  part[t] = s;
  __syncthreads();
  for(int off=1; off<1024; off<<=1){
    int v = part[t];
    int add = (t>=off)? part[t-off] : 0;
    __syncthreads();
    part[t] = v + add;
    __syncthreads();
  }
  int run = (t==0)? 0 : part[t-1];
  for(int i=0;i<128;i++){ rowptr[base+i] = run; run += deg[base+i]; }
  if(t==1023) rowptr[NN] = run;
}

__global__ void k_fill(const int* dst, const int* rowptr, int* cursor, int* eord){
  int e = blockIdx.x*256+threadIdx.x;
  if(e>=EE) return;
  int d = dst[e];
  int pos = atomicAdd(&cursor[d], 1);
  eord[rowptr[d]+pos] = e;
}

// ---- h0 = relu(x @ lin1W.T + b) -------------------------------------------
__global__ __launch_bounds__(256) void k_lin1_s(const float* x, const float* W, const float* b, float* h){
  __shared__ float sW[2048];
  __shared__ float sb[64];
  int t=threadIdx.x;
  for(int i=t;i<2048;i+=256) sW[i]=W[i];
  if(t<64) sb[t]=b[t];
  __syncthreads();
  int n = blockIdx.x*4 + (t>>6);
  int j = t&63;
  float acc = sb[j];
  for(int k=0;k<32;k++) acc += x[n*32+k]*sW[j*32+k];
  h[n*64+j] = fmaxf(acc, 0.0f);
}

// ---- LITERAL gather: m = prW @ [h_dst, h_src, e_nn] + prb, then agg -------
__global__ __launch_bounds__(256) void k_gather_lit(const int* rowptr, const int* eord, const int* src,
      const float* ea, const float* h, const float* preW, const float* preb,
      const float* eW, const float* eb, float* agg, float* s12, float avgdl){
  __shared__ float sprW[64][196];   // prW [64][192], padded
  __shared__ float seW[64][8];      // eW  [64][6], padded
  __shared__ float sprb[64];
  __shared__ float seb[64];
  int t=threadIdx.x;
  for(int i=t;i<12288;i+=256){ int j=i/192, k=i-j*192; sprW[j][k]=preW[i]; }
  for(int i=t;i<384;i+=256){ int j=i/6, d=i-j*6; seW[j][d]=eW[i]; }
  if(t<64){ sprb[t]=preb[t]; seb[t]=eb[t]; }
  __syncthreads();
  int w=t>>6, j=t&63;
  for(int it=0; it<8; ++it){
    int n = (blockIdx.x*4+w) + it*16384;
    int lo=rowptr[n], hi=rowptr[n+1];
    // dst-part of the message: identical for every edge of node n
    float mdst = sprb[j];
    for(int k=0;k<64;k++) mdst += sprW[j][k]*h[n*64+k];
    float sum=0.0f, sq=0.0f, mn=1e30f, mx=-1e30f;
    for(int idx=lo; idx<hi; ++idx){
      int e = eord[idx];
      int s = src[e];
      // e_nn: lane j computes its own channel, then shuffle-broadcast
      float en = seb[j];
      #pragma unroll
      for(int d=0;d<6;d++) en += seW[j][d]*ea[e*6+d];
      float acc = mdst;
      for(int k=0;k<64;k++) acc += sprW[j][64+k]*h[s*64+k];
      for(int k=0;k<64;k++) acc += sprW[j][128+k]*__shfl(en,k,64);
      sum += acc; sq += acc*acc; mn = fminf(mn,acc); mx = fmaxf(mx,acc);
    }
    int c = hi-lo;
    float cm = fmaxf((float)c, 1.0f);
    float mean = sum/cm;
    float sd = sqrtf(fmaxf(sq/cm - mean*mean, 0.0f)+1e-5f);
    bool has = c>0;
    int base = n*256;
    agg[base+j]     = mean;
    agg[base+64+j]  = has?mn:0.0f;
    agg[base+128+j] = has?mx:0.0f;
    agg[base+192+j] = sd;
    if(j==0){ float ld=logf(cm+1.0f); s12[n*2]=ld/avgdl; s12[n*2+1]=avgdl/ld; }
  }
}

// ---- y1[N,64] = A'[N,832] @ postW.T + postb (direct weights) --------------
__global__ __launch_bounds__(256) void k_post_lit(const float* h, const float* agg, const float* s12,
        const float* poW, const float* pob, float* y1){
  __shared__ float sA[64][65];
  __shared__ float sB[64][65];
  int t=threadIdx.x;
  int rb = blockIdx.x*64;
  int r0=(t>>4)*4, c0=(t&15)*4;
  float acc[4][4] = {};
  for(int kt=0; kt<832; kt+=64){
    for(int q=0;q<16;q++){
      int idx = t*16+q;
      int a = idx>>6, bb = idx&63;
      int gk = kt+bb;
      int n = rb+a;
      float v;
      if(gk<64) v = h[n*64+gk];
      else if(gk<320) v = agg[n*256+gk-64];
      else if(gk<576) v = s12[n*2]*agg[n*256+gk-320];
      else v = s12[n*2+1]*agg[n*256+gk-576];
      sA[a][bb] = v;
      sB[bb][a] = poW[a*832 + gk];
    }
    __syncthreads();
    for(int k=0;k<64;k++){
      float av[4], bv[4];
      #pragma unroll
      for(int i=0;i<4;i++) av[i]=sA[r0+i][k];
      #pragma unroll
      for(int jj=0;jj<4;jj++) bv[jj]=sB[k][c0+jj];
      #pragma unroll
      for(int i=0;i<4;i++){
        #pragma unroll
        for(int jj=0;jj<4;jj++) acc[i][jj]+=av[i]*bv[jj];
      }
    }
    __syncthreads();
  }
  for(int i=0;i<4;i++)
    for(int jj=0;jj<4;jj++)
      y1[(rb+r0+i)*64 + c0+jj] = acc[i][jj] + pob[c0+jj];
}

// ---- y2[N,64] = y1 @ clinW.T + clinb --------------------------------------
__global__ __launch_bounds__(256) void k_clin(const float* y1, const float* W, const float* b, float* y2){
  __shared__ float sW[64][65];
  __shared__ float sb[64];
  int t=threadIdx.x;
  for(int i=t;i<4096;i+=256){ int j=i>>6,k=i&63; sW[j][k]=W[i]; }
  if(t<64) sb[t]=b[t];
  __syncthreads();
  int w=t>>6, j=t&63;
  int n = blockIdx.x*4 + w;
  float acc=sb[j];
  for(int k=0;k<64;k++) acc += y1[n*64+k]*sW[j][k];
  y2[n*64+j]=acc;
}

// ---- BN: partials (double, no atomics) -> finalize -> apply + relu --------
__global__ __launch_bounds__(256) void k_bnpart(const float* y, double* part){
  __shared__ double sS[256], sQ[256];
  int t=threadIdx.x;
  int c=t&63, q=t>>6;
  int b=blockIdx.x;
  double s=0.0, s2=0.0;
  for(int i=0;i<64;i++){
    int n = b*256 + q + i*4;
    double v = (double)y[n*64+c];
    s += v; s2 += v*v;
  }
  sS[t]=s; sQ[t]=s2;
  __syncthreads();
  if(t<64){
    double S=sS[t]+sS[t+64]+sS[t+128]+sS[t+192];
    double Q=sQ[t]+sQ[t+64]+sQ[t+128]+sQ[t+192];
    part[b*128+t]=S; part[b*128+64+t]=Q;
  }
}

__global__ void k_bnfin(const double* part, const float* g, const float* bb, float* sc, float* sh){
  int c = threadIdx.x;
  if(c>=64) return;
  double S=0.0, Q=0.0;
  for(int b=0;b<512;b++){ S+=part[b*128+c]; Q+=part[b*128+64+c]; }
  double mean = S/(double)NN;
  double var  = Q/(double)NN - mean*mean;
  float scale = g[c] * (float)(1.0/sqrt(var+1e-5));
  sc[c]=scale;
  sh[c]=bb[c] - (float)mean*scale;
}

__global__ void k_bnapply2(const float* y, float* h, const float* sc, const float* sh){
  int idx = blockIdx.x*256+threadIdx.x;
  const float4* y4=(const float4*)y;
  float4* h4=(float4*)h;
  for(int i=idx; i<NN*16; i+=256*4096){
    int c4=(i&15)*4;
    float4 v=y4[i];
    float r[4]={v.x,v.y,v.z,v.w};
    #pragma unroll
    for(int qq=0;qq<4;qq++){ int c=c4+qq; r[qq]=fmaxf(r[qq]*sc[c]+sh[c], 0.0f); }
    h4[i]=make_float4(r[0],r[1],r[2],r[3]);
  }
}

// ---- set2set (literal LSTM: raw Wih/Whh) ----------------------------------
__global__ __launch_bounds__(256) void k_lstm_lit(float* A, float* cs,
      const float* Wih, const float* Whh, const float* bih, const float* bhh){
  __shared__ float sA[128]; __shared__ float sg[256];
  int g=blockIdx.x, t=threadIdx.x;
  if(t<128) sA[t]=A[g*128+t];
  __syncthreads();
  float a = bih[t] + bhh[t];
  for(int k=0;k<128;k++) a += Wih[t*128+k]*sA[k];   // q_star = [hs, r]
  for(int k=0;k<64;k++)  a += Whh[t*64+k]*sA[k];    // hs
  sg[t]=a;
  __syncthreads();
  if(t<64){
    float ig=sg[t], fg=sg[64+t], gg=sg[128+t], og=sg[192+t];
    float c = sigmoidf_(fg)*cs[g*64+t] + sigmoidf_(ig)*tanhf(gg);
    float hv = sigmoidf_(og)*tanhf(c);
    cs[g*64+t]=c;
    A[g*128+t]=hv;
  }
}

__global__ __launch_bounds__(256) void k_edot(const float* h, const float* A, const int* batch, float* e){
  int t=threadIdx.x, w=t>>6, j=t&63;
  for(int it=0;it<16;++it){
    int n=(blockIdx.x*4+w)+it*8192;
    int g=batch[n];
    float v=h[n*64+j]*A[g*128+j];
    #pragma unroll
    for(int m=32;m;m>>=1) v+=__shfl_xor(v,m,64);
    if(j==0) e[n]=v;
  }
}

__global__ __launch_bounds__(64) void k_attn(const float* h, const float* e, const int* gptr, float* A){
  int g=blockIdx.x, j=threadIdx.x;
  int lo=gptr[g], hi=gptr[g+1];
  if(lo>=hi){ A[g*128+64+j]=0.0f; return; }
  float mx=-1e30f;
  for(int n=lo+j;n<hi;n+=64) mx=fmaxf(mx,e[n]);
  #pragma unroll
  for(int m=32;m;m>>=1) mx=fmaxf(mx,__shfl_xor(mx,m,64));
  float s=0.0f;
  for(int n=lo+j;n<hi;n+=64) s+=expf(e[n]-mx);
  #pragma unroll
  for(int m=32;m;m>>=1) s+=__shfl_xor(s,m,64);
  float inv=1.0f/(s+1e-16f);
  float r=0.0f;
  for(int n=lo;n<hi;++n){
    float a=expf(e[n]-mx)*inv;
    r+=a*h[n*64+j];
  }
  A[g*128+64+j]=r;
}

__global__ __launch_bounds__(64) void k_mlp(const float* A, const float* tt, const float* pp,
     const float* W1,const float* b1,const float* W2,const float* b2,const float* W3,const float* b3,
     float* out){
  __shared__ float si[130]; __shared__ float o1[64]; __shared__ float o2[32];
  int g=blockIdx.x, t=threadIdx.x;
  si[t]=A[g*128+t]; si[64+t]=A[g*128+64+t];
  if(t==0){ si[128]=tt[g]; si[129]=pp[g]; }
  __syncthreads();
  float a=b1[t];
  for(int k=0;k<130;k++) a+=W1[t*130+k]*si[k];
  o1[t]=fmaxf(a,0.0f);
  __syncthreads();
  if(t<32){
    float a2=b2[t];
    #pragma unroll 4
    for(int k=0;k<64;k++) a2+=W2[t*64+k]*o1[k];
    o2[t]=fmaxf(a2,0.0f);
  }
  __syncthreads();
  float v = (t<32)? o2[t]*W3[t] : 0.0f;
  #pragma unroll
  for(int m=32;m;m>>=1) v+=__shfl_xor(v,m,64);
  if(t==0) out[g]=v+b3[0];
}

// ---- host -----------------------------------------------------------------
extern "C" void kernel_launch(void* const* d_in, const int* in_sizes, int n_in,
                              void* d_out, int out_size, void* d_ws, size_t ws_size,
                              hipStream_t stream) {
  static const int want[28] = {4194304,3145728,4096,4096,2048,64,1152,192,36864,192,
                               159744,192,12288,192,192,192,32768,16384,256,256,
                               8320,64,2048,32,32,1,1048576,131072};
  if (n_in != 28 || out_size != GG) return;
  for (int i=0;i<28;i++) if (in_sizes[i] != want[i]) return;

  const float* x     = (const float*)d_in[0];
  const float* ea    = (const float*)d_in[1];
  const float* tt    = (const float*)d_in[2];
  const float* pp    = (const float*)d_in[3];
  const float* lin1W = (const float*)d_in[4];
  const float* lin1b = (const float*)d_in[5];
  const float* edgeW = (const float*)d_in[6];
  const float* edgeb = (const float*)d_in[7];
  const float* preW  = (const float*)d_in[8];
  const float* preb  = (const float*)d_in[9];
  const float* postW = (const float*)d_in[10];
  const float* postb = (const float*)d_in[11];
  const float* clinW = (const float*)d_in[12];
  const float* clinb = (const float*)d_in[13];
  const float* bng   = (const float*)d_in[14];
  const float* bnb   = (const float*)d_in[15];
  const float* Wih   = (const float*)d_in[16];
  const float* Whh   = (const float*)d_in[17];
  const float* bih   = (const float*)d_in[18];
  const float* bhh   = (const float*)d_in[19];
  const float* W1    = (const float*)d_in[20];
  const float* b1    = (const float*)d_in[21];
  const float* W2    = (const float*)d_in[22];
  const float* b2    = (const float*)d_in[23];
  const float* W3    = (const float*)d_in[24];
  const float* b3    = (const float*)d_in[25];
  const int*   eidx  = (const int*)d_in[26];
  const int*   batch = (const int*)d_in[27];
  const int* esrc = eidx;
  const int* edst = eidx + EE;

  char* w = (char*)d_ws;
  auto alloc = [&](size_t bytes)->char*{ char* p=w; w += ((bytes+255)/256)*256; return p; };
  float* agg   = (float*)alloc((size_t)NN*256*4);   // 128MiB (y2 aliases after post)
  float* hbuf  = (float*)alloc((size_t)NN*64*4);    // 32MiB
  float* y1    = (float*)alloc((size_t)NN*64*4);    // 32MiB (set2set scratch later)
  int*   deg    = (int*)alloc((size_t)NN*4);
  int*   cursor = (int*)alloc((size_t)NN*4);
  int*   rowptr = (int*)alloc((size_t)(NN+1)*4);
  int*   eord   = (int*)alloc((size_t)EE*4);
  float* s12   = (float*)alloc((size_t)NN*2*4);
  double* part = (double*)alloc((size_t)512*128*8);
  float* bnsc  = (float*)alloc(256);
  float* bnsh  = (float*)alloc(256);
  int*   gptr  = (int*)alloc((GG+1)*4);
  size_t need = (size_t)(w - (char*)d_ws);
  if (need > ws_size) return;
  float* y2   = agg;                       // agg dead after k_post_lit
  float* A    = y1;                        // y1 dead after last k_clin
  float* cs   = y1 + (size_t)GG*128;
  float* escr = y1 + (size_t)GG*192;

  double num = 13107.0*log(2.0)+26214.0*log(3.0)+65536.0*log(4.0)+26215.0*log(5.0);
  float avgdl = (float)(num/131072.0);

  hipMemsetAsync(deg, 0, (size_t)NN*4, stream);
  hipMemsetAsync(cursor, 0, (size_t)NN*4, stream);
  hipLaunchKernelGGL(k_deg, dim3(2048), dim3(256), 0, stream, edst, deg);
  hipLaunchKernelGGL(k_scan, dim3(1), dim3(1024), 0, stream, deg, rowptr);
  hipLaunchKernelGGL(k_fill, dim3(2048), dim3(256), 0, stream, edst, rowptr, cursor, eord);

  hipLaunchKernelGGL(k_gptr, dim3(17), dim3(256), 0, stream, batch, gptr);
  hipLaunchKernelGGL(k_lin1_s, dim3(32768), dim3(256), 0, stream, x, lin1W, lin1b, hbuf);

  for (int i = 0; i < 3; ++i){
    hipLaunchKernelGGL(k_gather_lit, dim3(4096), dim3(256), 0, stream, rowptr, eord, esrc, ea, hbuf,
        preW + (size_t)i*64*192, preb + i*64, edgeW + (size_t)i*384, edgeb + i*64, agg, s12, avgdl);
    hipLaunchKernelGGL(k_post_lit, dim3(2048), dim3(256), 0, stream, hbuf, agg, s12,
        postW + (size_t)i*64*832, postb + i*64, y1);
    hipLaunchKernelGGL(k_clin, dim3(32768), dim3(256), 0, stream, y1,
        clinW + (size_t)i*4096, clinb + i*64, y2);
    hipLaunchKernelGGL(k_bnpart, dim3(512), dim3(256), 0, stream, y2, part);
    hipLaunchKernelGGL(k_bnfin, dim3(1), dim3(64), 0, stream, part, bng + i*64, bnb + i*64, bnsc, bnsh);
    hipLaunchKernelGGL(k_bnapply2, dim3(4096), dim3(256), 0, stream, y2, hbuf, bnsc, bnsh);
  }

  hipMemsetAsync(A, 0, (size_t)GG*128*4, stream);
  hipMemsetAsync(cs, 0, (size_t)GG*64*4, stream);
  for (int s = 0; s < 3; ++s){
    hipLaunchKernelGGL(k_lstm_lit, dim3(GG), dim3(256), 0, stream, A, cs, Wih, Whh, bih, bhh);
    hipLaunchKernelGGL(k_edot, dim3(2048), dim3(256), 0, stream, hbuf, A, batch, escr);
    hipLaunchKernelGGL(k_attn, dim3(GG), dim3(64), 0, stream, hbuf, escr, gptr, A);
  }
  hipLaunchKernelGGL(k_mlp, dim3(GG), dim3(64), 0, stream, A, tt, pp, W1, b1, W2, b2, W3, b3, (float*)d_out);
}

// Round 7
// 3175.942 us; speedup vs baseline: 1.4334x; 1.4334x over previous
//
#include <hip/hip_runtime.h>
#include <math.h>

#define NN 131072
#define EE 524288
#define GG 4096

__device__ __forceinline__ float sigmoidf_(float x){ return 1.0f/(1.0f+expf(-x)); }

// ---- grouping / CSR (integer atomics only) --------------------------------
__global__ void k_gptr(const int* batch, int* gptr){
  int g = blockIdx.x*256+threadIdx.x;
  if (g > GG) return;
  if (g == GG){ gptr[GG]=NN; return; }
  int lo=0, hi=NN;
  while(lo<hi){ int mid=(lo+hi)>>1; if(batch[mid]<g) lo=mid+1; else hi=mid; }
  gptr[g]=lo;
}

__global__ void k_deg(const int* dst, int* deg){
  int e = blockIdx.x*256+threadIdx.x;
  if(e<EE) atomicAdd(&deg[dst[e]], 1);
}

__global__ __launch_bounds__(1024) void k_scan(const int* deg, int* rowptr){
  __shared__ int part[1024];
  int t = threadIdx.x;
  int base = t*128;
  int s = 0;
  for(int i=0;i<128;i++) s += deg[base+i];
  part[t] = s;
  __syncthreads();
  for(int off=1; off<1024; off<<=1){
    int v = part[t];
    int add = (t>=off)? part[t-off] : 0;
    __syncthreads();
    part[t] = v + add;
    __syncthreads();
  }
  int run = (t==0)? 0 : part[t-1];
  for(int i=0;i<128;i++){ rowptr[base+i] = run; run += deg[base+i]; }
  if(t==1023) rowptr[NN] = run;
}

__global__ void k_fill(const int* dst, const int* rowptr, int* cursor, int* eord){
  int e = blockIdx.x*256+threadIdx.x;
  if(e>=EE) return;
  int d = dst[e];
  int pos = atomicAdd(&cursor[d], 1);
  eord[rowptr[d]+pos] = e;
}

// ---- h0 = relu(x @ lin1W.T + b) -------------------------------------------
__global__ __launch_bounds__(256) void k_lin1_s(const float* x, const float* W, const float* b, float* h){
  __shared__ float sW[2048];
  __shared__ float sb[64];
  int t=threadIdx.x;
  for(int i=t;i<2048;i+=256) sW[i]=W[i];
  if(t<64) sb[t]=b[t];
  __syncthreads();
  int n = blockIdx.x*4 + (t>>6);
  int j = t&63;
  float acc = sb[j];
  for(int k=0;k<32;k++) acc += x[n*32+k]*sW[j*32+k];
  h[n*64+j] = fmaxf(acc, 0.0f);
}

// ---- k_msg: g12[N][128] = h @ [prW_dst | prW_src].T (direct preW reads) ---
// col c<64:  g12[n][c]    = sum_k preW[c*192+k]     * h[n][k]   (dst proj)
// col c>=64: g12[n][64+c']= sum_k preW[c'*192+64+k] * h[n][k]   (src proj)
__global__ __launch_bounds__(256) void k_msg(const float* h, const float* preW, float* g12){
  __shared__ float sA[64][65];
  __shared__ float sB[64][65];
  int t=threadIdx.x;
  int rb = blockIdx.x*64;
  int coff = blockIdx.y ? 64 : 0;   // which 64-col half (and weight block offset)
  for(int q=0;q<16;q++){
    int idx = t*16+q;
    int a = idx>>6, bb = idx&63;
    sA[a][bb] = h[(rb+a)*64 + bb];
    sB[bb][a] = preW[a*192 + coff + bb];   // sB[k][col] = prW[col][coff+k]
  }
  __syncthreads();
  int r0=(t>>4)*4, c0=(t&15)*4;
  float acc[4][4] = {};
  for(int k=0;k<64;k++){
    float av[4], bv[4];
    #pragma unroll
    for(int i=0;i<4;i++) av[i]=sA[r0+i][k];
    #pragma unroll
    for(int jj=0;jj<4;jj++) bv[jj]=sB[k][c0+jj];
    #pragma unroll
    for(int i=0;i<4;i++){
      #pragma unroll
      for(int jj=0;jj<4;jj++) acc[i][jj]+=av[i]*bv[jj];
    }
  }
  for(int i=0;i<4;i++)
    for(int jj=0;jj<4;jj++)
      g12[(rb+r0+i)*128 + coff + c0+jj] = acc[i][jj];
}

// ---- gather: m = g12[dst][j] + g12[src][64+j] + Wf[j]·ea + bf[j] ----------
// Wf/bf computed in-block from raw preW/eW/eb (same math as literal r6 path).
__global__ __launch_bounds__(256) void k_gather_f(const int* rowptr, const int* eord, const int* src,
      const float* ea, const float* g12, const float* preW, const float* preb,
      const float* eW, const float* eb, float* agg, float* s12, float avgdl){
  __shared__ float sWf[64][6];
  __shared__ float sbf[64];
  int t=threadIdx.x;
  for(int i=t; i<384; i+=256){
    int j=i/6, d=i-j*6;
    float a=0.0f;
    for(int k=0;k<64;k++) a += preW[j*192+128+k]*eW[k*6+d];
    sWf[j][d]=a;
  }
  if(t<64){
    float a=preb[t];
    for(int k=0;k<64;k++) a += preW[t*192+128+k]*eb[k];
    sbf[t]=a;
  }
  __syncthreads();
  int w=t>>6, j=t&63;
  float wf0=sWf[j][0], wf1=sWf[j][1], wf2=sWf[j][2];
  float wf3=sWf[j][3], wf4=sWf[j][4], wf5=sWf[j][5];
  float bfj=sbf[j];
  for(int it=0; it<8; ++it){
    int n = (blockIdx.x*4+w) + it*16384;
    int lo=rowptr[n], hi=rowptr[n+1];
    float mdst = g12[n*128+j] + bfj;
    float sum=0.0f, sq=0.0f, mn=1e30f, mx=-1e30f;
    for(int idx=lo; idx<hi; ++idx){
      int e = eord[idx];
      int s = src[e];
      float m = mdst + g12[s*128+64+j];
      m += ea[e*6+0]*wf0 + ea[e*6+1]*wf1 + ea[e*6+2]*wf2
         + ea[e*6+3]*wf3 + ea[e*6+4]*wf4 + ea[e*6+5]*wf5;
      sum += m; sq += m*m; mn = fminf(mn,m); mx = fmaxf(mx,m);
    }
    int c = hi-lo;
    float cm = fmaxf((float)c, 1.0f);
    float mean = sum/cm;
    float sd = sqrtf(fmaxf(sq/cm - mean*mean, 0.0f)+1e-5f);
    bool has = c>0;
    int base = n*256;
    agg[base+j]     = mean;
    agg[base+64+j]  = has?mn:0.0f;
    agg[base+128+j] = has?mx:0.0f;
    agg[base+192+j] = sd;
    if(j==0){ float ld=logf(cm+1.0f); s12[n*2]=ld/avgdl; s12[n*2+1]=avgdl/ld; }
  }
}

// ---- y1[N,64] = A'[N,832] @ postW.T + postb (direct weights) --------------
__global__ __launch_bounds__(256) void k_post_lit(const float* h, const float* agg, const float* s12,
        const float* poW, const float* pob, float* y1){
  __shared__ float sA[64][65];
  __shared__ float sB[64][65];
  int t=threadIdx.x;
  int rb = blockIdx.x*64;
  int r0=(t>>4)*4, c0=(t&15)*4;
  float acc[4][4] = {};
  for(int kt=0; kt<832; kt+=64){
    for(int q=0;q<16;q++){
      int idx = t*16+q;
      int a = idx>>6, bb = idx&63;
      int gk = kt+bb;
      int n = rb+a;
      float v;
      if(gk<64) v = h[n*64+gk];
      else if(gk<320) v = agg[n*256+gk-64];
      else if(gk<576) v = s12[n*2]*agg[n*256+gk-320];
      else v = s12[n*2+1]*agg[n*256+gk-576];
      sA[a][bb] = v;
      sB[bb][a] = poW[a*832 + gk];
    }
    __syncthreads();
    for(int k=0;k<64;k++){
      float av[4], bv[4];
      #pragma unroll
      for(int i=0;i<4;i++) av[i]=sA[r0+i][k];
      #pragma unroll
      for(int jj=0;jj<4;jj++) bv[jj]=sB[k][c0+jj];
      #pragma unroll
      for(int i=0;i<4;i++){
        #pragma unroll
        for(int jj=0;jj<4;jj++) acc[i][jj]+=av[i]*bv[jj];
      }
    }
    __syncthreads();
  }
  for(int i=0;i<4;i++)
    for(int jj=0;jj<4;jj++)
      y1[(rb+r0+i)*64 + c0+jj] = acc[i][jj] + pob[c0+jj];
}

// ---- y2[N,64] = y1 @ clinW.T + clinb --------------------------------------
__global__ __launch_bounds__(256) void k_clin(const float* y1, const float* W, const float* b, float* y2){
  __shared__ float sW[64][65];
  __shared__ float sb[64];
  int t=threadIdx.x;
  for(int i=t;i<4096;i+=256){ int j=i>>6,k=i&63; sW[j][k]=W[i]; }
  if(t<64) sb[t]=b[t];
  __syncthreads();
  int w=t>>6, j=t&63;
  int n = blockIdx.x*4 + w;
  float acc=sb[j];
  for(int k=0;k<64;k++) acc += y1[n*64+k]*sW[j][k];
  y2[n*64+j]=acc;
}

// ---- BN: partials (double, no atomics) -> finalize -> apply + relu --------
__global__ __launch_bounds__(256) void k_bnpart(const float* y, double* part){
  __shared__ double sS[256], sQ[256];
  int t=threadIdx.x;
  int c=t&63, q=t>>6;
  int b=blockIdx.x;
  double s=0.0, s2=0.0;
  for(int i=0;i<64;i++){
    int n = b*256 + q + i*4;
    double v = (double)y[n*64+c];
    s += v; s2 += v*v;
  }
  sS[t]=s; sQ[t]=s2;
  __syncthreads();
  if(t<64){
    double S=sS[t]+sS[t+64]+sS[t+128]+sS[t+192];
    double Q=sQ[t]+sQ[t+64]+sQ[t+128]+sQ[t+192];
    part[b*128+t]=S; part[b*128+64+t]=Q;
  }
}

__global__ void k_bnfin(const double* part, const float* g, const float* bb, float* sc, float* sh){
  int c = threadIdx.x;
  if(c>=64) return;
  double S=0.0, Q=0.0;
  for(int b=0;b<512;b++){ S+=part[b*128+c]; Q+=part[b*128+64+c]; }
  double mean = S/(double)NN;
  double var  = Q/(double)NN - mean*mean;
  float scale = g[c] * (float)(1.0/sqrt(var+1e-5));
  sc[c]=scale;
  sh[c]=bb[c] - (float)mean*scale;
}

__global__ void k_bnapply2(const float* y, float* h, const float* sc, const float* sh){
  int idx = blockIdx.x*256+threadIdx.x;
  const float4* y4=(const float4*)y;
  float4* h4=(float4*)h;
  for(int i=idx; i<NN*16; i+=256*4096){
    int c4=(i&15)*4;
    float4 v=y4[i];
    float r[4]={v.x,v.y,v.z,v.w};
    #pragma unroll
    for(int qq=0;qq<4;qq++){ int c=c4+qq; r[qq]=fmaxf(r[qq]*sc[c]+sh[c], 0.0f); }
    h4[i]=make_float4(r[0],r[1],r[2],r[3]);
  }
}

// ---- set2set (literal LSTM: raw Wih/Whh) ----------------------------------
__global__ __launch_bounds__(256) void k_lstm_lit(float* A, float* cs,
      const float* Wih, const float* Whh, const float* bih, const float* bhh){
  __shared__ float sA[128]; __shared__ float sg[256];
  int g=blockIdx.x, t=threadIdx.x;
  if(t<128) sA[t]=A[g*128+t];
  __syncthreads();
  float a = bih[t] + bhh[t];
  for(int k=0;k<128;k++) a += Wih[t*128+k]*sA[k];   // q_star = [hs, r]
  for(int k=0;k<64;k++)  a += Whh[t*64+k]*sA[k];    // hs
  sg[t]=a;
  __syncthreads();
  if(t<64){
    float ig=sg[t], fg=sg[64+t], gg=sg[128+t], og=sg[192+t];
    float c = sigmoidf_(fg)*cs[g*64+t] + sigmoidf_(ig)*tanhf(gg);
    float hv = sigmoidf_(og)*tanhf(c);
    cs[g*64+t]=c;
    A[g*128+t]=hv;
  }
}

__global__ __launch_bounds__(256) void k_edot(const float* h, const float* A, const int* batch, float* e){
  int t=threadIdx.x, w=t>>6, j=t&63;
  for(int it=0;it<16;++it){
    int n=(blockIdx.x*4+w)+it*8192;
    int g=batch[n];
    float v=h[n*64+j]*A[g*128+j];
    #pragma unroll
    for(int m=32;m;m>>=1) v+=__shfl_xor(v,m,64);
    if(j==0) e[n]=v;
  }
}

__global__ __launch_bounds__(64) void k_attn(const float* h, const float* e, const int* gptr, float* A){
  int g=blockIdx.x, j=threadIdx.x;
  int lo=gptr[g], hi=gptr[g+1];
  if(lo>=hi){ A[g*128+64+j]=0.0f; return; }
  float mx=-1e30f;
  for(int n=lo+j;n<hi;n+=64) mx=fmaxf(mx,e[n]);
  #pragma unroll
  for(int m=32;m;m>>=1) mx=fmaxf(mx,__shfl_xor(mx,m,64));
  float s=0.0f;
  for(int n=lo+j;n<hi;n+=64) s+=expf(e[n]-mx);
  #pragma unroll
  for(int m=32;m;m>>=1) s+=__shfl_xor(s,m,64);
  float inv=1.0f/(s+1e-16f);
  float r=0.0f;
  for(int n=lo;n<hi;++n){
    float a=expf(e[n]-mx)*inv;
    r+=a*h[n*64+j];
  }
  A[g*128+64+j]=r;
}

__global__ __launch_bounds__(64) void k_mlp(const float* A, const float* tt, const float* pp,
     const float* W1,const float* b1,const float* W2,const float* b2,const float* W3,const float* b3,
     float* out){
  __shared__ float si[130]; __shared__ float o1[64]; __shared__ float o2[32];
  int g=blockIdx.x, t=threadIdx.x;
  si[t]=A[g*128+t]; si[64+t]=A[g*128+64+t];
  if(t==0){ si[128]=tt[g]; si[129]=pp[g]; }
  __syncthreads();
  float a=b1[t];
  for(int k=0;k<130;k++) a+=W1[t*130+k]*si[k];
  o1[t]=fmaxf(a,0.0f);
  __syncthreads();
  if(t<32){
    float a2=b2[t];
    #pragma unroll 4
    for(int k=0;k<64;k++) a2+=W2[t*64+k]*o1[k];
    o2[t]=fmaxf(a2,0.0f);
  }
  __syncthreads();
  float v = (t<32)? o2[t]*W3[t] : 0.0f;
  #pragma unroll
  for(int m=32;m;m>>=1) v+=__shfl_xor(v,m,64);
  if(t==0) out[g]=v+b3[0];
}

// ---- host -----------------------------------------------------------------
extern "C" void kernel_launch(void* const* d_in, const int* in_sizes, int n_in,
                              void* d_out, int out_size, void* d_ws, size_t ws_size,
                              hipStream_t stream) {
  static const int want[28] = {4194304,3145728,4096,4096,2048,64,1152,192,36864,192,
                               159744,192,12288,192,192,192,32768,16384,256,256,
                               8320,64,2048,32,32,1,1048576,131072};
  if (n_in != 28 || out_size != GG) return;
  for (int i=0;i<28;i++) if (in_sizes[i] != want[i]) return;

  const float* x     = (const float*)d_in[0];
  const float* ea    = (const float*)d_in[1];
  const float* tt    = (const float*)d_in[2];
  const float* pp    = (const float*)d_in[3];
  const float* lin1W = (const float*)d_in[4];
  const float* lin1b = (const float*)d_in[5];
  const float* edgeW = (const float*)d_in[6];
  const float* edgeb = (const float*)d_in[7];
  const float* preW  = (const float*)d_in[8];
  const float* preb  = (const float*)d_in[9];
  const float* postW = (const float*)d_in[10];
  const float* postb = (const float*)d_in[11];
  const float* clinW = (const float*)d_in[12];
  const float* clinb = (const float*)d_in[13];
  const float* bng   = (const float*)d_in[14];
  const float* bnb   = (const float*)d_in[15];
  const float* Wih   = (const float*)d_in[16];
  const float* Whh   = (const float*)d_in[17];
  const float* bih   = (const float*)d_in[18];
  const float* bhh   = (const float*)d_in[19];
  const float* W1    = (const float*)d_in[20];
  const float* b1    = (const float*)d_in[21];
  const float* W2    = (const float*)d_in[22];
  const float* b2    = (const float*)d_in[23];
  const float* W3    = (const float*)d_in[24];
  const float* b3    = (const float*)d_in[25];
  const int*   eidx  = (const int*)d_in[26];
  const int*   batch = (const int*)d_in[27];
  const int* esrc = eidx;
  const int* edst = eidx + EE;

  char* w = (char*)d_ws;
  auto alloc = [&](size_t bytes)->char*{ char* p=w; w += ((bytes+255)/256)*256; return p; };
  float* agg   = (float*)alloc((size_t)NN*256*4);   // 128MiB (y2 aliases after post)
  float* g12   = (float*)alloc((size_t)NN*128*4);   // 64MiB  (y1 + set2set scratch alias)
  float* hbuf  = (float*)alloc((size_t)NN*64*4);    // 32MiB
  int*   deg    = (int*)alloc((size_t)NN*4);
  int*   cursor = (int*)alloc((size_t)NN*4);
  int*   rowptr = (int*)alloc((size_t)(NN+1)*4);
  int*   eord   = (int*)alloc((size_t)EE*4);
  float* s12   = (float*)alloc((size_t)NN*2*4);
  double* part = (double*)alloc((size_t)512*128*8);
  float* bnsc  = (float*)alloc(256);
  float* bnsh  = (float*)alloc(256);
  int*   gptr  = (int*)alloc((GG+1)*4);
  size_t need = (size_t)(w - (char*)d_ws);
  if (need > ws_size) return;
  // time-sharing: y1 lives between k_post_lit and k_clin; g12 dead after k_gather_f
  float* y1   = g12;
  float* y2   = agg;                       // agg dead after k_post_lit
  float* A    = g12;                       // set2set scratch (all layer bufs dead)
  float* cs   = g12 + (size_t)GG*128;
  float* escr = g12 + (size_t)GG*192;

  double num = 13107.0*log(2.0)+26214.0*log(3.0)+65536.0*log(4.0)+26215.0*log(5.0);
  float avgdl = (float)(num/131072.0);

  hipMemsetAsync(deg, 0, (size_t)NN*4, stream);
  hipMemsetAsync(cursor, 0, (size_t)NN*4, stream);
  hipLaunchKernelGGL(k_deg, dim3(2048), dim3(256), 0, stream, edst, deg);
  hipLaunchKernelGGL(k_scan, dim3(1), dim3(1024), 0, stream, deg, rowptr);
  hipLaunchKernelGGL(k_fill, dim3(2048), dim3(256), 0, stream, edst, rowptr, cursor, eord);

  hipLaunchKernelGGL(k_gptr, dim3(17), dim3(256), 0, stream, batch, gptr);
  hipLaunchKernelGGL(k_lin1_s, dim3(32768), dim3(256), 0, stream, x, lin1W, lin1b, hbuf);

  for (int i = 0; i < 3; ++i){
    hipLaunchKernelGGL(k_msg, dim3(2048,2), dim3(256), 0, stream, hbuf,
        preW + (size_t)i*64*192, g12);
    hipLaunchKernelGGL(k_gather_f, dim3(4096), dim3(256), 0, stream, rowptr, eord, esrc, ea, g12,
        preW + (size_t)i*64*192, preb + i*64, edgeW + (size_t)i*384, edgeb + i*64, agg, s12, avgdl);
    hipLaunchKernelGGL(k_post_lit, dim3(2048), dim3(256), 0, stream, hbuf, agg, s12,
        postW + (size_t)i*64*832, postb + i*64, y1);
    hipLaunchKernelGGL(k_clin, dim3(32768), dim3(256), 0, stream, y1,
        clinW + (size_t)i*4096, clinb + i*64, y2);
    hipLaunchKernelGGL(k_bnpart, dim3(512), dim3(256), 0, stream, y2, part);
    hipLaunchKernelGGL(k_bnfin, dim3(1), dim3(64), 0, stream, part, bng + i*64, bnb + i*64, bnsc, bnsh);
    hipLaunchKernelGGL(k_bnapply2, dim3(4096), dim3(256), 0, stream, y2, hbuf, bnsc, bnsh);
  }

  hipMemsetAsync(A, 0, (size_t)GG*128*4, stream);
  hipMemsetAsync(cs, 0, (size_t)GG*64*4, stream);
  for (int s = 0; s < 3; ++s){
    hipLaunchKernelGGL(k_lstm_lit, dim3(GG), dim3(256), 0, stream, A, cs, Wih, Whh, bih, bhh);
    hipLaunchKernelGGL(k_edot, dim3(2048), dim3(256), 0, stream, hbuf, A, batch, escr);
    hipLaunchKernelGGL(k_attn, dim3(GG), dim3(64), 0, stream, hbuf, escr, gptr, A);
  }
  hipLaunchKernelGGL(k_mlp, dim3(GG), dim3(64), 0, stream, A, tt, pp, W1, b1, W2, b2, W3, b3, (float*)d_out);
}

// Round 8
// 2311.707 us; speedup vs baseline: 1.9693x; 1.3739x over previous
//
#include <hip/hip_runtime.h>
#include <math.h>

#define NN 131072
#define EE 524288
#define GG 4096

__device__ __forceinline__ float sigmoidf_(float x){ return 1.0f/(1.0f+expf(-x)); }

// ---- grouping / CSR (integer atomics only) --------------------------------
__global__ void k_gptr(const int* batch, int* gptr){
  int g = blockIdx.x*256+threadIdx.x;
  if (g > GG) return;
  if (g == GG){ gptr[GG]=NN; return; }
  int lo=0, hi=NN;
  while(lo<hi){ int mid=(lo+hi)>>1; if(batch[mid]<g) lo=mid+1; else hi=mid; }
  gptr[g]=lo;
}

__global__ void k_deg(const int* dst, int* deg){
  int e = blockIdx.x*256+threadIdx.x;
  if(e<EE) atomicAdd(&deg[dst[e]], 1);
}

__global__ __launch_bounds__(1024) void k_scan(const int* deg, int* rowptr){
  __shared__ int part[1024];
  int t = threadIdx.x;
  int base = t*128;
  int s = 0;
  for(int i=0;i<128;i++) s += deg[base+i];
  part[t] = s;
  __syncthreads();
  for(int off=1; off<1024; off<<=1){
    int v = part[t];
    int add = (t>=off)? part[t-off] : 0;
    __syncthreads();
    part[t] = v + add;
    __syncthreads();
  }
  int run = (t==0)? 0 : part[t-1];
  for(int i=0;i<128;i++){ rowptr[base+i] = run; run += deg[base+i]; }
  if(t==1023) rowptr[NN] = run;
}

__global__ void k_fill(const int* dst, const int* rowptr, int* cursor, int* eord){
  int e = blockIdx.x*256+threadIdx.x;
  if(e>=EE) return;
  int d = dst[e];
  int pos = atomicAdd(&cursor[d], 1);
  eord[rowptr[d]+pos] = e;
}

// ---- h0 = relu(x @ lin1W.T + b) -------------------------------------------
__global__ __launch_bounds__(256) void k_lin1_s(const float* x, const float* W, const float* b, float* h){
  __shared__ float sW[2048];
  __shared__ float sb[64];
  int t=threadIdx.x;
  for(int i=t;i<2048;i+=256) sW[i]=W[i];
  if(t<64) sb[t]=b[t];
  __syncthreads();
  int n = blockIdx.x*4 + (t>>6);
  int j = t&63;
  float acc = sb[j];
  for(int k=0;k<32;k++) acc += x[n*32+k]*sW[j*32+k];
  h[n*64+j] = fmaxf(acc, 0.0f);
}

// ---- k_msg: g12[N][128] = h @ [prW_dst | prW_src].T (direct preW reads) ---
__global__ __launch_bounds__(256) void k_msg(const float* h, const float* preW, float* g12){
  __shared__ float sA[64][65];
  __shared__ float sB[64][65];
  int t=threadIdx.x;
  int rb = blockIdx.x*64;
  int coff = blockIdx.y ? 64 : 0;
  for(int q=0;q<16;q++){
    int idx = t*16+q;
    int a = idx>>6, bb = idx&63;
    sA[a][bb] = h[(rb+a)*64 + bb];
    sB[bb][a] = preW[a*192 + coff + bb];
  }
  __syncthreads();
  int r0=(t>>4)*4, c0=(t&15)*4;
  float acc[4][4] = {};
  for(int k=0;k<64;k++){
    float av[4], bv[4];
    #pragma unroll
    for(int i=0;i<4;i++) av[i]=sA[r0+i][k];
    #pragma unroll
    for(int jj=0;jj<4;jj++) bv[jj]=sB[k][c0+jj];
    #pragma unroll
    for(int i=0;i<4;i++){
      #pragma unroll
      for(int jj=0;jj<4;jj++) acc[i][jj]+=av[i]*bv[jj];
    }
  }
  for(int i=0;i<4;i++)
    for(int jj=0;jj<4;jj++)
      g12[(rb+r0+i)*128 + coff + c0+jj] = acc[i][jj];
}

// ---- gather: m = g12[dst][j] + g12[src][64+j] + Wf[j]·ea + bf[j] ----------
__global__ __launch_bounds__(256) void k_gather_f(const int* rowptr, const int* eord, const int* src,
      const float* ea, const float* g12, const float* preW, const float* preb,
      const float* eW, const float* eb, float* agg, float* s12, float avgdl){
  __shared__ float sWf[64][6];
  __shared__ float sbf[64];
  int t=threadIdx.x;
  for(int i=t; i<384; i+=256){
    int j=i/6, d=i-j*6;
    float a=0.0f;
    for(int k=0;k<64;k++) a += preW[j*192+128+k]*eW[k*6+d];
    sWf[j][d]=a;
  }
  if(t<64){
    float a=preb[t];
    for(int k=0;k<64;k++) a += preW[t*192+128+k]*eb[k];
    sbf[t]=a;
  }
  __syncthreads();
  int w=t>>6, j=t&63;
  float wf0=sWf[j][0], wf1=sWf[j][1], wf2=sWf[j][2];
  float wf3=sWf[j][3], wf4=sWf[j][4], wf5=sWf[j][5];
  float bfj=sbf[j];
  for(int it=0; it<8; ++it){
    int n = (blockIdx.x*4+w) + it*16384;
    int lo=rowptr[n], hi=rowptr[n+1];
    float mdst = g12[n*128+j] + bfj;
    float sum=0.0f, sq=0.0f, mn=1e30f, mx=-1e30f;
    for(int idx=lo; idx<hi; ++idx){
      int e = eord[idx];
      int s = src[e];
      float m = mdst + g12[s*128+64+j];
      m += ea[e*6+0]*wf0 + ea[e*6+1]*wf1 + ea[e*6+2]*wf2
         + ea[e*6+3]*wf3 + ea[e*6+4]*wf4 + ea[e*6+5]*wf5;
      sum += m; sq += m*m; mn = fminf(mn,m); mx = fmaxf(mx,m);
    }
    int c = hi-lo;
    float cm = fmaxf((float)c, 1.0f);
    float mean = sum/cm;
    float sd = sqrtf(fmaxf(sq/cm - mean*mean, 0.0f)+1e-5f);
    bool has = c>0;
    int base = n*256;
    agg[base+j]     = mean;
    agg[base+64+j]  = has?mn:0.0f;
    agg[base+128+j] = has?mx:0.0f;
    agg[base+192+j] = sd;
    if(j==0){ float ld=logf(cm+1.0f); s12[n*2]=ld/avgdl; s12[n*2+1]=avgdl/ld; }
  }
}

// ---- k_tower: fused post_nn + scaler-combine + clin -----------------------
// y1[n][c] = postb[c] + sum_{k<64} postW[c][k] h[n][k]
//          + sum_{k<256} postW[c][64+k] agg[n][k]
//          + s1[n]*sum_{k<256} postW[c][320+k] agg[n][k]
//          + s2[n]*sum_{k<256} postW[c][576+k] agg[n][k]
// y2[n][c] = clinb[c] + sum_j clinW[c][j] y1[n][j]
// Pure sum-split of the r6/r7-verified math; no weight preprocessing.
__global__ __launch_bounds__(256) void k_tower(const float* h, const float* agg, const float* s12,
        const float* poW, const float* pob, const float* clW, const float* clb, float* y2){
  __shared__ float sA[64][68];         // A-tile (agg/h k-tiles), later y1
  __shared__ float sWT[3][64][68];     // weight planes, k-major; later clinW
  __shared__ float sS[128];            // s1,s2 per row
  __shared__ float sPB[64], sCB[64];
  int t=threadIdx.x;
  int rb = blockIdx.x*64;
  int tr=t>>4, tc=t&15;
  int r0=tr*4, c0=tc*4;
  if(t<128) sS[t] = s12[(size_t)(rb + (t>>1))*2 + (t&1)];
  if(t>=128 && t<192) sPB[t-128]=pob[t-128];
  if(t>=192) sCB[t-192]=clb[t-192];

  float acc0[4][4]={}, acc1[4][4]={}, acc2[4][4]={}, hacc[4][4]={};

  // ---- z-part: K=256 over agg, 3 weight planes ----
  for(int kt=0; kt<256; kt+=64){
    __syncthreads();
    {
      int k = t&63, rB = t>>6;
      #pragma unroll
      for(int rr=0;rr<16;rr++){
        int r = rB + rr*4;
        sA[r][k] = agg[(size_t)(rb+r)*256 + kt + k];
      }
      #pragma unroll
      for(int q=0;q<3;q++){
        #pragma unroll
        for(int rr=0;rr<16;rr++){
          int c = rB + rr*4;
          sWT[q][k][c] = poW[(size_t)c*832 + 64 + q*256 + kt + k];
        }
      }
    }
    __syncthreads();
    for(int k=0;k<64;++k){
      float av[4];
      #pragma unroll
      for(int i=0;i<4;i++) av[i]=sA[r0+i][k];
      float4 b0=*(const float4*)&sWT[0][k][c0];
      float4 b1=*(const float4*)&sWT[1][k][c0];
      float4 b2=*(const float4*)&sWT[2][k][c0];
      float bw0[4]={b0.x,b0.y,b0.z,b0.w};
      float bw1[4]={b1.x,b1.y,b1.z,b1.w};
      float bw2[4]={b2.x,b2.y,b2.z,b2.w};
      #pragma unroll
      for(int i=0;i<4;i++){
        #pragma unroll
        for(int jj=0;jj<4;jj++){
          acc0[i][jj]+=av[i]*bw0[jj];
          acc1[i][jj]+=av[i]*bw1[jj];
          acc2[i][jj]+=av[i]*bw2[jj];
        }
      }
    }
  }

  // ---- h-part: K=64 ----
  __syncthreads();
  {
    int k = t&63, rB = t>>6;
    #pragma unroll
    for(int rr=0;rr<16;rr++){
      int r = rB + rr*4;
      sA[r][k] = h[(size_t)(rb+r)*64 + k];
      sWT[0][k][r] = poW[(size_t)r*832 + k];
    }
  }
  __syncthreads();
  for(int k=0;k<64;++k){
    float av[4];
    #pragma unroll
    for(int i=0;i<4;i++) av[i]=sA[r0+i][k];
    float4 b0=*(const float4*)&sWT[0][k][c0];
    float bw0[4]={b0.x,b0.y,b0.z,b0.w};
    #pragma unroll
    for(int i=0;i<4;i++){
      #pragma unroll
      for(int jj=0;jj<4;jj++) hacc[i][jj]+=av[i]*bw0[jj];
    }
  }

  // ---- combine into y1 (in LDS) ----
  __syncthreads();
  #pragma unroll
  for(int i=0;i<4;i++){
    int lr = r0+i;
    float s1v = sS[lr*2], s2v = sS[lr*2+1];
    #pragma unroll
    for(int jj=0;jj<4;jj++){
      sA[lr][c0+jj] = hacc[i][jj] + acc0[i][jj] + s1v*acc1[i][jj] + s2v*acc2[i][jj] + sPB[c0+jj];
    }
  }
  // ---- clin weights ----
  {
    int k = t&63, rB = t>>6;
    #pragma unroll
    for(int rr=0;rr<16;rr++){
      int c = rB + rr*4;
      sWT[0][k][c] = clW[(size_t)c*64 + k];
    }
  }
  __syncthreads();
  float cacc[4][4]={};
  for(int k=0;k<64;++k){
    float av[4];
    #pragma unroll
    for(int i=0;i<4;i++) av[i]=sA[r0+i][k];
    float4 b0=*(const float4*)&sWT[0][k][c0];
    float bw0[4]={b0.x,b0.y,b0.z,b0.w};
    #pragma unroll
    for(int i=0;i<4;i++){
      #pragma unroll
      for(int jj=0;jj<4;jj++) cacc[i][jj]+=av[i]*bw0[jj];
    }
  }
  #pragma unroll
  for(int i=0;i<4;i++){
    #pragma unroll
    for(int jj=0;jj<4;jj++)
      y2[(size_t)(rb+r0+i)*64 + c0+jj] = cacc[i][jj] + sCB[c0+jj];
  }
}

// ---- BN: partials (double, no atomics) -> finalize -> apply + relu --------
__global__ __launch_bounds__(256) void k_bnpart(const float* y, double* part){
  __shared__ double sS[256], sQ[256];
  int t=threadIdx.x;
  int c=t&63, q=t>>6;
  int b=blockIdx.x;
  double s=0.0, s2=0.0;
  for(int i=0;i<64;i++){
    int n = b*256 + q + i*4;
    double v = (double)y[n*64+c];
    s += v; s2 += v*v;
  }
  sS[t]=s; sQ[t]=s2;
  __syncthreads();
  if(t<64){
    double S=sS[t]+sS[t+64]+sS[t+128]+sS[t+192];
    double Q=sQ[t]+sQ[t+64]+sQ[t+128]+sQ[t+192];
    part[b*128+t]=S; part[b*128+64+t]=Q;
  }
}

__global__ void k_bnfin(const double* part, const float* g, const float* bb, float* sc, float* sh){
  int c = threadIdx.x;
  if(c>=64) return;
  double S=0.0, Q=0.0;
  for(int b=0;b<512;b++){ S+=part[b*128+c]; Q+=part[b*128+64+c]; }
  double mean = S/(double)NN;
  double var  = Q/(double)NN - mean*mean;
  float scale = g[c] * (float)(1.0/sqrt(var+1e-5));
  sc[c]=scale;
  sh[c]=bb[c] - (float)mean*scale;
}

__global__ void k_bnapply2(const float* y, float* h, const float* sc, const float* sh){
  int idx = blockIdx.x*256+threadIdx.x;
  const float4* y4=(const float4*)y;
  float4* h4=(float4*)h;
  for(int i=idx; i<NN*16; i+=256*4096){
    int c4=(i&15)*4;
    float4 v=y4[i];
    float r[4]={v.x,v.y,v.z,v.w};
    #pragma unroll
    for(int qq=0;qq<4;qq++){ int c=c4+qq; r[qq]=fmaxf(r[qq]*sc[c]+sh[c], 0.0f); }
    h4[i]=make_float4(r[0],r[1],r[2],r[3]);
  }
}

// ---- set2set (literal LSTM: raw Wih/Whh) ----------------------------------
__global__ __launch_bounds__(256) void k_lstm_lit(float* A, float* cs,
      const float* Wih, const float* Whh, const float* bih, const float* bhh){
  __shared__ float sA[128]; __shared__ float sg[256];
  int g=blockIdx.x, t=threadIdx.x;
  if(t<128) sA[t]=A[g*128+t];
  __syncthreads();
  float a = bih[t] + bhh[t];
  for(int k=0;k<128;k++) a += Wih[t*128+k]*sA[k];
  for(int k=0;k<64;k++)  a += Whh[t*64+k]*sA[k];
  sg[t]=a;
  __syncthreads();
  if(t<64){
    float ig=sg[t], fg=sg[64+t], gg=sg[128+t], og=sg[192+t];
    float c = sigmoidf_(fg)*cs[g*64+t] + sigmoidf_(ig)*tanhf(gg);
    float hv = sigmoidf_(og)*tanhf(c);
    cs[g*64+t]=c;
    A[g*128+t]=hv;
  }
}

__global__ __launch_bounds__(256) void k_edot(const float* h, const float* A, const int* batch, float* e){
  int t=threadIdx.x, w=t>>6, j=t&63;
  for(int it=0;it<16;++it){
    int n=(blockIdx.x*4+w)+it*8192;
    int g=batch[n];
    float v=h[n*64+j]*A[g*128+j];
    #pragma unroll
    for(int m=32;m;m>>=1) v+=__shfl_xor(v,m,64);
    if(j==0) e[n]=v;
  }
}

__global__ __launch_bounds__(64) void k_attn(const float* h, const float* e, const int* gptr, float* A){
  int g=blockIdx.x, j=threadIdx.x;
  int lo=gptr[g], hi=gptr[g+1];
  if(lo>=hi){ A[g*128+64+j]=0.0f; return; }
  float mx=-1e30f;
  for(int n=lo+j;n<hi;n+=64) mx=fmaxf(mx,e[n]);
  #pragma unroll
  for(int m=32;m;m>>=1) mx=fmaxf(mx,__shfl_xor(mx,m,64));
  float s=0.0f;
  for(int n=lo+j;n<hi;n+=64) s+=expf(e[n]-mx);
  #pragma unroll
  for(int m=32;m;m>>=1) s+=__shfl_xor(s,m,64);
  float inv=1.0f/(s+1e-16f);
  float r=0.0f;
  for(int n=lo;n<hi;++n){
    float a=expf(e[n]-mx)*inv;
    r+=a*h[n*64+j];
  }
  A[g*128+64+j]=r;
}

__global__ __launch_bounds__(64) void k_mlp(const float* A, const float* tt, const float* pp,
     const float* W1,const float* b1,const float* W2,const float* b2,const float* W3,const float* b3,
     float* out){
  __shared__ float si[130]; __shared__ float o1[64]; __shared__ float o2[32];
  int g=blockIdx.x, t=threadIdx.x;
  si[t]=A[g*128+t]; si[64+t]=A[g*128+64+t];
  if(t==0){ si[128]=tt[g]; si[129]=pp[g]; }
  __syncthreads();
  float a=b1[t];
  for(int k=0;k<130;k++) a+=W1[t*130+k]*si[k];
  o1[t]=fmaxf(a,0.0f);
  __syncthreads();
  if(t<32){
    float a2=b2[t];
    #pragma unroll 4
    for(int k=0;k<64;k++) a2+=W2[t*64+k]*o1[k];
    o2[t]=fmaxf(a2,0.0f);
  }
  __syncthreads();
  float v = (t<32)? o2[t]*W3[t] : 0.0f;
  #pragma unroll
  for(int m=32;m;m>>=1) v+=__shfl_xor(v,m,64);
  if(t==0) out[g]=v+b3[0];
}

// ---- host -----------------------------------------------------------------
extern "C" void kernel_launch(void* const* d_in, const int* in_sizes, int n_in,
                              void* d_out, int out_size, void* d_ws, size_t ws_size,
                              hipStream_t stream) {
  static const int want[28] = {4194304,3145728,4096,4096,2048,64,1152,192,36864,192,
                               159744,192,12288,192,192,192,32768,16384,256,256,
                               8320,64,2048,32,32,1,1048576,131072};
  if (n_in != 28 || out_size != GG) return;
  for (int i=0;i<28;i++) if (in_sizes[i] != want[i]) return;

  const float* x     = (const float*)d_in[0];
  const float* ea    = (const float*)d_in[1];
  const float* tt    = (const float*)d_in[2];
  const float* pp    = (const float*)d_in[3];
  const float* lin1W = (const float*)d_in[4];
  const float* lin1b = (const float*)d_in[5];
  const float* edgeW = (const float*)d_in[6];
  const float* edgeb = (const float*)d_in[7];
  const float* preW  = (const float*)d_in[8];
  const float* preb  = (const float*)d_in[9];
  const float* postW = (const float*)d_in[10];
  const float* postb = (const float*)d_in[11];
  const float* clinW = (const float*)d_in[12];
  const float* clinb = (const float*)d_in[13];
  const float* bng   = (const float*)d_in[14];
  const float* bnb   = (const float*)d_in[15];
  const float* Wih   = (const float*)d_in[16];
  const float* Whh   = (const float*)d_in[17];
  const float* bih   = (const float*)d_in[18];
  const float* bhh   = (const float*)d_in[19];
  const float* W1    = (const float*)d_in[20];
  const float* b1    = (const float*)d_in[21];
  const float* W2    = (const float*)d_in[22];
  const float* b2    = (const float*)d_in[23];
  const float* W3    = (const float*)d_in[24];
  const float* b3    = (const float*)d_in[25];
  const int*   eidx  = (const int*)d_in[26];
  const int*   batch = (const int*)d_in[27];
  const int* esrc = eidx;
  const int* edst = eidx + EE;

  char* w = (char*)d_ws;
  auto alloc = [&](size_t bytes)->char*{ char* p=w; w += ((bytes+255)/256)*256; return p; };
  float* agg   = (float*)alloc((size_t)NN*256*4);   // 128MiB
  float* g12   = (float*)alloc((size_t)NN*128*4);   // 64MiB (y2 + set2set scratch alias)
  float* hbuf  = (float*)alloc((size_t)NN*64*4);    // 32MiB
  int*   deg    = (int*)alloc((size_t)NN*4);
  int*   cursor = (int*)alloc((size_t)NN*4);
  int*   rowptr = (int*)alloc((size_t)(NN+1)*4);
  int*   eord   = (int*)alloc((size_t)EE*4);
  float* s12   = (float*)alloc((size_t)NN*2*4);
  double* part = (double*)alloc((size_t)512*128*8);
  float* bnsc  = (float*)alloc(256);
  float* bnsh  = (float*)alloc(256);
  int*   gptr  = (int*)alloc((GG+1)*4);
  size_t need = (size_t)(w - (char*)d_ws);
  if (need > ws_size) return;
  // y2 goes in the g12 region (g12 dead after k_gather_f; NOT agg — k_tower reads agg)
  float* y2   = g12;
  float* A    = g12;                       // set2set scratch (after layers done)
  float* cs   = g12 + (size_t)GG*128;
  float* escr = g12 + (size_t)GG*192;

  double num = 13107.0*log(2.0)+26214.0*log(3.0)+65536.0*log(4.0)+26215.0*log(5.0);
  float avgdl = (float)(num/131072.0);

  hipMemsetAsync(deg, 0, (size_t)NN*4, stream);
  hipMemsetAsync(cursor, 0, (size_t)NN*4, stream);
  hipLaunchKernelGGL(k_deg, dim3(2048), dim3(256), 0, stream, edst, deg);
  hipLaunchKernelGGL(k_scan, dim3(1), dim3(1024), 0, stream, deg, rowptr);
  hipLaunchKernelGGL(k_fill, dim3(2048), dim3(256), 0, stream, edst, rowptr, cursor, eord);

  hipLaunchKernelGGL(k_gptr, dim3(17), dim3(256), 0, stream, batch, gptr);
  hipLaunchKernelGGL(k_lin1_s, dim3(32768), dim3(256), 0, stream, x, lin1W, lin1b, hbuf);

  for (int i = 0; i < 3; ++i){
    hipLaunchKernelGGL(k_msg, dim3(2048,2), dim3(256), 0, stream, hbuf,
        preW + (size_t)i*64*192, g12);
    hipLaunchKernelGGL(k_gather_f, dim3(4096), dim3(256), 0, stream, rowptr, eord, esrc, ea, g12,
        preW + (size_t)i*64*192, preb + i*64, edgeW + (size_t)i*384, edgeb + i*64, agg, s12, avgdl);
    hipLaunchKernelGGL(k_tower, dim3(2048), dim3(256), 0, stream, hbuf, agg, s12,
        postW + (size_t)i*64*832, postb + i*64, clinW + (size_t)i*4096, clinb + i*64, y2);
    hipLaunchKernelGGL(k_bnpart, dim3(512), dim3(256), 0, stream, y2, part);
    hipLaunchKernelGGL(k_bnfin, dim3(1), dim3(64), 0, stream, part, bng + i*64, bnb + i*64, bnsc, bnsh);
    hipLaunchKernelGGL(k_bnapply2, dim3(4096), dim3(256), 0, stream, y2, hbuf, bnsc, bnsh);
  }

  hipMemsetAsync(A, 0, (size_t)GG*128*4, stream);
  hipMemsetAsync(cs, 0, (size_t)GG*64*4, stream);
  for (int s = 0; s < 3; ++s){
    hipLaunchKernelGGL(k_lstm_lit, dim3(GG), dim3(256), 0, stream, A, cs, Wih, Whh, bih, bhh);
    hipLaunchKernelGGL(k_edot, dim3(2048), dim3(256), 0, stream, hbuf, A, batch, escr);
    hipLaunchKernelGGL(k_attn, dim3(GG), dim3(64), 0, stream, hbuf, escr, gptr, A);
  }
  hipLaunchKernelGGL(k_mlp, dim3(GG), dim3(64), 0, stream, A, tt, pp, W1, b1, W2, b2, W3, b3, (float*)d_out);
}

// Round 10
// 1791.202 us; speedup vs baseline: 2.5416x; 1.2906x over previous
//
#include <hip/hip_runtime.h>
#include <hip/hip_bf16.h>
#include <math.h>

#define NN 131072
#define EE 524288
#define GG 4096

typedef __attribute__((ext_vector_type(8))) _Float16 half8;
typedef __attribute__((ext_vector_type(4))) float f32x4;

__device__ __forceinline__ float sigmoidf_(float x){ return 1.0f/(1.0f+expf(-x)); }

// ---- grouping / CSR (integer atomics only) --------------------------------
__global__ void k_gptr(const int* batch, int* gptr){
  int g = blockIdx.x*256+threadIdx.x;
  if (g > GG) return;
  if (g == GG){ gptr[GG]=NN; return; }
  int lo=0, hi=NN;
  while(lo<hi){ int mid=(lo+hi)>>1; if(batch[mid]<g) lo=mid+1; else hi=mid; }
  gptr[g]=lo;
}

__global__ void k_deg(const int* dst, int* deg){
  int e = blockIdx.x*256+threadIdx.x;
  if(e<EE) atomicAdd(&deg[dst[e]], 1);
}

__global__ __launch_bounds__(1024) void k_scan(const int* deg, int* rowptr){
  __shared__ int part[1024];
  int t = threadIdx.x;
  int base = t*128;
  int s = 0;
  for(int i=0;i<128;i++) s += deg[base+i];
  part[t] = s;
  __syncthreads();
  for(int off=1; off<1024; off<<=1){
    int v = part[t];
    int add = (t>=off)? part[t-off] : 0;
    __syncthreads();
    part[t] = v + add;
    __syncthreads();
  }
  int run = (t==0)? 0 : part[t-1];
  for(int i=0;i<128;i++){ rowptr[base+i] = run; run += deg[base+i]; }
  if(t==1023) rowptr[NN] = run;
}

__global__ void k_fill(const int* dst, const int* rowptr, int* cursor, int* eord){
  int e = blockIdx.x*256+threadIdx.x;
  if(e>=EE) return;
  int d = dst[e];
  int pos = atomicAdd(&cursor[d], 1);
  eord[rowptr[d]+pos] = e;
}

// ---- h0 = relu(x @ lin1W.T + b) -------------------------------------------
__global__ __launch_bounds__(256) void k_lin1_s(const float* x, const float* W, const float* b, float* h){
  __shared__ float sW[2048];
  __shared__ float sb[64];
  int t=threadIdx.x;
  for(int i=t;i<2048;i+=256) sW[i]=W[i];
  if(t<64) sb[t]=b[t];
  __syncthreads();
  int n = blockIdx.x*4 + (t>>6);
  int j = t&63;
  float acc = sb[j];
  for(int k=0;k<32;k++) acc += x[n*32+k]*sW[j*32+k];
  h[n*64+j] = fmaxf(acc, 0.0f);
}

// ---- k_msg: g12[N][128] = h @ [prW_dst | prW_src].T (direct preW reads) ---
__global__ __launch_bounds__(256) void k_msg(const float* h, const float* preW, float* g12){
  __shared__ float sA[64][65];
  __shared__ float sB[64][65];
  int t=threadIdx.x;
  int rb = blockIdx.x*64;
  int coff = blockIdx.y ? 64 : 0;
  for(int q=0;q<16;q++){
    int idx = t*16+q;
    int a = idx>>6, bb = idx&63;
    sA[a][bb] = h[(rb+a)*64 + bb];
    sB[bb][a] = preW[a*192 + coff + bb];
  }
  __syncthreads();
  int r0=(t>>4)*4, c0=(t&15)*4;
  float acc[4][4] = {};
  for(int k=0;k<64;k++){
    float av[4], bv[4];
    #pragma unroll
    for(int i=0;i<4;i++) av[i]=sA[r0+i][k];
    #pragma unroll
    for(int jj=0;jj<4;jj++) bv[jj]=sB[k][c0+jj];
    #pragma unroll
    for(int i=0;i<4;i++){
      #pragma unroll
      for(int jj=0;jj<4;jj++) acc[i][jj]+=av[i]*bv[jj];
    }
  }
  for(int i=0;i<4;i++)
    for(int jj=0;jj<4;jj++)
      g12[(rb+r0+i)*128 + coff + c0+jj] = acc[i][jj];
}

// ---- gather: m = g12[dst][j] + g12[src][64+j] + Wf[j]·ea + bf[j] ----------
__global__ __launch_bounds__(256) void k_gather_f(const int* rowptr, const int* eord, const int* src,
      const float* ea, const float* g12, const float* preW, const float* preb,
      const float* eW, const float* eb, float* agg, float* s12, float avgdl){
  __shared__ float sWf[64][6];
  __shared__ float sbf[64];
  int t=threadIdx.x;
  for(int i=t; i<384; i+=256){
    int j=i/6, d=i-j*6;
    float a=0.0f;
    for(int k=0;k<64;k++) a += preW[j*192+128+k]*eW[k*6+d];
    sWf[j][d]=a;
  }
  if(t<64){
    float a=preb[t];
    for(int k=0;k<64;k++) a += preW[t*192+128+k]*eb[k];
    sbf[t]=a;
  }
  __syncthreads();
  int w=t>>6, j=t&63;
  float wf0=sWf[j][0], wf1=sWf[j][1], wf2=sWf[j][2];
  float wf3=sWf[j][3], wf4=sWf[j][4], wf5=sWf[j][5];
  float bfj=sbf[j];
  for(int it=0; it<8; ++it){
    int n = (blockIdx.x*4+w) + it*16384;
    int lo=rowptr[n], hi=rowptr[n+1];
    float mdst = g12[n*128+j] + bfj;
    float sum=0.0f, sq=0.0f, mn=1e30f, mx=-1e30f;
    for(int idx=lo; idx<hi; ++idx){
      int e = eord[idx];
      int s = src[e];
      float m = mdst + g12[s*128+64+j];
      m += ea[e*6+0]*wf0 + ea[e*6+1]*wf1 + ea[e*6+2]*wf2
         + ea[e*6+3]*wf3 + ea[e*6+4]*wf4 + ea[e*6+5]*wf5;
      sum += m; sq += m*m; mn = fminf(mn,m); mx = fmaxf(mx,m);
    }
    int c = hi-lo;
    float cm = fmaxf((float)c, 1.0f);
    float mean = sum/cm;
    float sd = sqrtf(fmaxf(sq/cm - mean*mean, 0.0f)+1e-5f);
    bool has = c>0;
    int base = n*256;
    agg[base+j]     = mean;
    agg[base+64+j]  = has?mn:0.0f;
    agg[base+128+j] = has?mx:0.0f;
    agg[base+192+j] = sd;
    if(j==0){ float ld=logf(cm+1.0f); s12[n*2]=ld/avgdl; s12[n*2+1]=avgdl/ld; }
  }
}

// ---- k_tower_mfma: fused post_nn + scaler-combine + clin via fp16 MFMA ----
// Same sum-split math as r8's verified fp32 k_tower; operands fp16 (10-bit
// mantissa, 4x less quant error than bf16 which measured 9.3e-3), fp32 accum.
// A'[n][k] over K=832 = [h(64) | agg(256) | s1*agg(256) | s2*agg(256)]
// y1 = A' @ postW.T + postb ; y2 = fp16(y1) @ clinW.T + clinb
__global__ __launch_bounds__(256) void k_tower_mfma(const float* h, const float* agg, const float* s12,
        const float* poW, const float* pob, const float* clW, const float* clb, float* y2){
  __shared__ _Float16 sAh[64][72];   // A' k-tile (fp16), later y1
  __shared__ _Float16 sBh[64][72];   // postW k-tile (fp16), later clinW
  __shared__ float sS[128];
  int t = threadIdx.x;
  int rb = blockIdx.x*64;
  int w = t>>6, l = t&63;
  int k = t&63, rB = t>>6;
  if (t < 128) sS[t] = s12[(size_t)(rb+(t>>1))*2 + (t&1)];
  f32x4 acc[4] = {};   // wave w owns output rows w*16..w*16+15; acc[n16]
  for (int kt=0; kt<13; ++kt){
    __syncthreads();
    #pragma unroll
    for (int rr=0; rr<16; ++rr){
      int r = rB + rr*4;
      float v;
      if (kt==0)      v = h[(size_t)(rb+r)*64 + k];
      else if (kt<5)  v = agg[(size_t)(rb+r)*256 + (kt-1)*64 + k];
      else if (kt<9)  v = sS[r*2]   * agg[(size_t)(rb+r)*256 + (kt-5)*64 + k];
      else            v = sS[r*2+1] * agg[(size_t)(rb+r)*256 + (kt-9)*64 + k];
      sAh[r][k] = (_Float16)v;
      sBh[r][k] = (_Float16)poW[(size_t)r*832 + kt*64 + k];   // r = output col c
    }
    __syncthreads();
    #pragma unroll
    for (int kk=0; kk<2; ++kk){
      half8 a = *(const half8*)&sAh[w*16 + (l&15)][kk*32 + (l>>4)*8];
      #pragma unroll
      for (int n16=0; n16<4; ++n16){
        half8 b = *(const half8*)&sBh[n16*16 + (l&15)][kk*32 + (l>>4)*8];
        acc[n16] = __builtin_amdgcn_mfma_f32_16x16x32_f16(a, b, acc[n16], 0, 0, 0);
      }
    }
  }
  __syncthreads();   // all MFMA reads of sAh/sBh done
  // y1 (+bias) -> fp16 into sAh. D layout: col=lane&15, row=(lane>>4)*4+reg.
  #pragma unroll
  for (int n16=0; n16<4; ++n16){
    #pragma unroll
    for (int reg=0; reg<4; ++reg){
      int row = w*16 + (l>>4)*4 + reg;
      int col = n16*16 + (l&15);
      sAh[row][col] = (_Float16)(acc[n16][reg] + pob[col]);
    }
  }
  #pragma unroll
  for (int rr=0; rr<16; ++rr){
    int c = rB + rr*4;
    sBh[c][k] = (_Float16)clW[(size_t)c*64 + k];
  }
  __syncthreads();
  f32x4 cacc[4] = {};
  #pragma unroll
  for (int kk=0; kk<2; ++kk){
    half8 a = *(const half8*)&sAh[w*16 + (l&15)][kk*32 + (l>>4)*8];
    #pragma unroll
    for (int n16=0; n16<4; ++n16){
      half8 b = *(const half8*)&sBh[n16*16 + (l&15)][kk*32 + (l>>4)*8];
      cacc[n16] = __builtin_amdgcn_mfma_f32_16x16x32_f16(a, b, cacc[n16], 0, 0, 0);
    }
  }
  #pragma unroll
  for (int n16=0; n16<4; ++n16){
    #pragma unroll
    for (int reg=0; reg<4; ++reg){
      int row = w*16 + (l>>4)*4 + reg;
      int col = n16*16 + (l&15);
      y2[(size_t)(rb+row)*64 + col] = cacc[n16][reg] + clb[col];
    }
  }
}

// ---- BN: partials (double, no atomics) -> finalize -> apply + relu --------
__global__ __launch_bounds__(256) void k_bnpart(const float* y, double* part){
  __shared__ double sS[256], sQ[256];
  int t=threadIdx.x;
  int c=t&63, q=t>>6;
  int b=blockIdx.x;
  double s=0.0, s2=0.0;
  for(int i=0;i<64;i++){
    int n = b*256 + q + i*4;
    double v = (double)y[n*64+c];
    s += v; s2 += v*v;
  }
  sS[t]=s; sQ[t]=s2;
  __syncthreads();
  if(t<64){
    double S=sS[t]+sS[t+64]+sS[t+128]+sS[t+192];
    double Q=sQ[t]+sQ[t+64]+sQ[t+128]+sQ[t+192];
    part[b*128+t]=S; part[b*128+64+t]=Q;
  }
}

__global__ void k_bnfin(const double* part, const float* g, const float* bb, float* sc, float* sh){
  int c = threadIdx.x;
  if(c>=64) return;
  double S=0.0, Q=0.0;
  for(int b=0;b<512;b++){ S+=part[b*128+c]; Q+=part[b*128+64+c]; }
  double mean = S/(double)NN;
  double var  = Q/(double)NN - mean*mean;
  float scale = g[c] * (float)(1.0/sqrt(var+1e-5));
  sc[c]=scale;
  sh[c]=bb[c] - (float)mean*scale;
}

__global__ void k_bnapply2(const float* y, float* h, const float* sc, const float* sh){
  int idx = blockIdx.x*256+threadIdx.x;
  const float4* y4=(const float4*)y;
  float4* h4=(float4*)h;
  for(int i=idx; i<NN*16; i+=256*4096){
    int c4=(i&15)*4;
    float4 v=y4[i];
    float r[4]={v.x,v.y,v.z,v.w};
    #pragma unroll
    for(int qq=0;qq<4;qq++){ int c=c4+qq; r[qq]=fmaxf(r[qq]*sc[c]+sh[c], 0.0f); }
    h4[i]=make_float4(r[0],r[1],r[2],r[3]);
  }
}

// ---- set2set (literal LSTM: raw Wih/Whh) ----------------------------------
__global__ __launch_bounds__(256) void k_lstm_lit(float* A, float* cs,
      const float* Wih, const float* Whh, const float* bih, const float* bhh){
  __shared__ float sA[128]; __shared__ float sg[256];
  int g=blockIdx.x, t=threadIdx.x;
  if(t<128) sA[t]=A[g*128+t];
  __syncthreads();
  float a = bih[t] + bhh[t];
  for(int k=0;k<128;k++) a += Wih[t*128+k]*sA[k];
  for(int k=0;k<64;k++)  a += Whh[t*64+k]*sA[k];
  sg[t]=a;
  __syncthreads();
  if(t<64){
    float ig=sg[t], fg=sg[64+t], gg=sg[128+t], og=sg[192+t];
    float c = sigmoidf_(fg)*cs[g*64+t] + sigmoidf_(ig)*tanhf(gg);
    float hv = sigmoidf_(og)*tanhf(c);
    cs[g*64+t]=c;
    A[g*128+t]=hv;
  }
}

__global__ __launch_bounds__(256) void k_edot(const float* h, const float* A, const int* batch, float* e){
  int t=threadIdx.x, w=t>>6, j=t&63;
  for(int it=0;it<16;++it){
    int n=(blockIdx.x*4+w)+it*8192;
    int g=batch[n];
    float v=h[n*64+j]*A[g*128+j];
    #pragma unroll
    for(int m=32;m;m>>=1) v+=__shfl_xor(v,m,64);
    if(j==0) e[n]=v;
  }
}

__global__ __launch_bounds__(64) void k_attn(const float* h, const float* e, const int* gptr, float* A){
  int g=blockIdx.x, j=threadIdx.x;
  int lo=gptr[g], hi=gptr[g+1];
  if(lo>=hi){ A[g*128+64+j]=0.0f; return; }
  float mx=-1e30f;
  for(int n=lo+j;n<hi;n+=64) mx=fmaxf(mx,e[n]);
  #pragma unroll
  for(int m=32;m;m>>=1) mx=fmaxf(mx,__shfl_xor(mx,m,64));
  float s=0.0f;
  for(int n=lo+j;n<hi;n+=64) s+=expf(e[n]-mx);
  #pragma unroll
  for(int m=32;m;m>>=1) s+=__shfl_xor(s,m,64);
  float inv=1.0f/(s+1e-16f);
  float r=0.0f;
  for(int n=lo;n<hi;++n){
    float a=expf(e[n]-mx)*inv;
    r+=a*h[n*64+j];
  }
  A[g*128+64+j]=r;
}

__global__ __launch_bounds__(64) void k_mlp(const float* A, const float* tt, const float* pp,
     const float* W1,const float* b1,const float* W2,const float* b2,const float* W3,const float* b3,
     float* out){
  __shared__ float si[130]; __shared__ float o1[64]; __shared__ float o2[32];
  int g=blockIdx.x, t=threadIdx.x;
  si[t]=A[g*128+t]; si[64+t]=A[g*128+64+t];
  if(t==0){ si[128]=tt[g]; si[129]=pp[g]; }
  __syncthreads();
  float a=b1[t];
  for(int k=0;k<130;k++) a+=W1[t*130+k]*si[k];
  o1[t]=fmaxf(a,0.0f);
  __syncthreads();
  if(t<32){
    float a2=b2[t];
    #pragma unroll 4
    for(int k=0;k<64;k++) a2+=W2[t*64+k]*o1[k];
    o2[t]=fmaxf(a2,0.0f);
  }
  __syncthreads();
  float v = (t<32)? o2[t]*W3[t] : 0.0f;
  #pragma unroll
  for(int m=32;m;m>>=1) v+=__shfl_xor(v,m,64);
  if(t==0) out[g]=v+b3[0];
}

// ---- host -----------------------------------------------------------------
extern "C" void kernel_launch(void* const* d_in, const int* in_sizes, int n_in,
                              void* d_out, int out_size, void* d_ws, size_t ws_size,
                              hipStream_t stream) {
  static const int want[28] = {4194304,3145728,4096,4096,2048,64,1152,192,36864,192,
                               159744,192,12288,192,192,192,32768,16384,256,256,
                               8320,64,2048,32,32,1,1048576,131072};
  if (n_in != 28 || out_size != GG) return;
  for (int i=0;i<28;i++) if (in_sizes[i] != want[i]) return;

  const float* x     = (const float*)d_in[0];
  const float* ea    = (const float*)d_in[1];
  const float* tt    = (const float*)d_in[2];
  const float* pp    = (const float*)d_in[3];
  const float* lin1W = (const float*)d_in[4];
  const float* lin1b = (const float*)d_in[5];
  const float* edgeW = (const float*)d_in[6];
  const float* edgeb = (const float*)d_in[7];
  const float* preW  = (const float*)d_in[8];
  const float* preb  = (const float*)d_in[9];
  const float* postW = (const float*)d_in[10];
  const float* postb = (const float*)d_in[11];
  const float* clinW = (const float*)d_in[12];
  const float* clinb = (const float*)d_in[13];
  const float* bng   = (const float*)d_in[14];
  const float* bnb   = (const float*)d_in[15];
  const float* Wih   = (const float*)d_in[16];
  const float* Whh   = (const float*)d_in[17];
  const float* bih   = (const float*)d_in[18];
  const float* bhh   = (const float*)d_in[19];
  const float* W1    = (const float*)d_in[20];
  const float* b1    = (const float*)d_in[21];
  const float* W2    = (const float*)d_in[22];
  const float* b2    = (const float*)d_in[23];
  const float* W3    = (const float*)d_in[24];
  const float* b3    = (const float*)d_in[25];
  const int*   eidx  = (const int*)d_in[26];
  const int*   batch = (const int*)d_in[27];
  const int* esrc = eidx;
  const int* edst = eidx + EE;

  char* w = (char*)d_ws;
  auto alloc = [&](size_t bytes)->char*{ char* p=w; w += ((bytes+255)/256)*256; return p; };
  float* agg   = (float*)alloc((size_t)NN*256*4);   // 128MiB
  float* g12   = (float*)alloc((size_t)NN*128*4);   // 64MiB (y2 + set2set scratch alias)
  float* hbuf  = (float*)alloc((size_t)NN*64*4);    // 32MiB
  int*   deg    = (int*)alloc((size_t)NN*4);
  int*   cursor = (int*)alloc((size_t)NN*4);
  int*   rowptr = (int*)alloc((size_t)(NN+1)*4);
  int*   eord   = (int*)alloc((size_t)EE*4);
  float* s12   = (float*)alloc((size_t)NN*2*4);
  double* part = (double*)alloc((size_t)512*128*8);
  float* bnsc  = (float*)alloc(256);
  float* bnsh  = (float*)alloc(256);
  int*   gptr  = (int*)alloc((GG+1)*4);
  size_t need = (size_t)(w - (char*)d_ws);
  if (need > ws_size) return;
  // y2 goes in the g12 region (g12 dead after k_gather_f; NOT agg — tower reads agg)
  float* y2   = g12;
  float* A    = g12;                       // set2set scratch (after layers done)
  float* cs   = g12 + (size_t)GG*128;
  float* escr = g12 + (size_t)GG*192;

  double num = 13107.0*log(2.0)+26214.0*log(3.0)+65536.0*log(4.0)+26215.0*log(5.0);
  float avgdl = (float)(num/131072.0);

  hipMemsetAsync(deg, 0, (size_t)NN*4, stream);
  hipMemsetAsync(cursor, 0, (size_t)NN*4, stream);
  hipLaunchKernelGGL(k_deg, dim3(2048), dim3(256), 0, stream, edst, deg);
  hipLaunchKernelGGL(k_scan, dim3(1), dim3(1024), 0, stream, deg, rowptr);
  hipLaunchKernelGGL(k_fill, dim3(2048), dim3(256), 0, stream, edst, rowptr, cursor, eord);

  hipLaunchKernelGGL(k_gptr, dim3(17), dim3(256), 0, stream, batch, gptr);
  hipLaunchKernelGGL(k_lin1_s, dim3(32768), dim3(256), 0, stream, x, lin1W, lin1b, hbuf);

  for (int i = 0; i < 3; ++i){
    hipLaunchKernelGGL(k_msg, dim3(2048,2), dim3(256), 0, stream, hbuf,
        preW + (size_t)i*64*192, g12);
    hipLaunchKernelGGL(k_gather_f, dim3(4096), dim3(256), 0, stream, rowptr, eord, esrc, ea, g12,
        preW + (size_t)i*64*192, preb + i*64, edgeW + (size_t)i*384, edgeb + i*64, agg, s12, avgdl);
    hipLaunchKernelGGL(k_tower_mfma, dim3(2048), dim3(256), 0, stream, hbuf, agg, s12,
        postW + (size_t)i*64*832, postb + i*64, clinW + (size_t)i*4096, clinb + i*64, y2);
    hipLaunchKernelGGL(k_bnpart, dim3(512), dim3(256), 0, stream, y2, part);
    hipLaunchKernelGGL(k_bnfin, dim3(1), dim3(64), 0, stream, part, bng + i*64, bnb + i*64, bnsc, bnsh);
    hipLaunchKernelGGL(k_bnapply2, dim3(4096), dim3(256), 0, stream, y2, hbuf, bnsc, bnsh);
  }

  hipMemsetAsync(A, 0, (size_t)GG*128*4, stream);
  hipMemsetAsync(cs, 0, (size_t)GG*64*4, stream);
  for (int s = 0; s < 3; ++s){
    hipLaunchKernelGGL(k_lstm_lit, dim3(GG), dim3(256), 0, stream, A, cs, Wih, Whh, bih, bhh);
    hipLaunchKernelGGL(k_edot, dim3(2048), dim3(256), 0, stream, hbuf, A, batch, escr);
    hipLaunchKernelGGL(k_attn, dim3(GG), dim3(64), 0, stream, hbuf, escr, gptr, A);
  }
  hipLaunchKernelGGL(k_mlp, dim3(GG), dim3(64), 0, stream, A, tt, pp, W1, b1, W2, b2, W3, b3, (float*)d_out);
}

// Round 11
// 1708.295 us; speedup vs baseline: 2.6649x; 1.0485x over previous
//
#include <hip/hip_runtime.h>
#include <hip/hip_bf16.h>
#include <math.h>

#define NN 131072
#define EE 524288
#define GG 4096

typedef __attribute__((ext_vector_type(8))) _Float16 half8;
typedef __attribute__((ext_vector_type(4))) float f32x4;

__device__ __forceinline__ float sigmoidf_(float x){ return 1.0f/(1.0f+expf(-x)); }

// ---- grouping / CSR (integer atomics only) --------------------------------
__global__ void k_gptr(const int* batch, int* gptr){
  int g = blockIdx.x*256+threadIdx.x;
  if (g > GG) return;
  if (g == GG){ gptr[GG]=NN; return; }
  int lo=0, hi=NN;
  while(lo<hi){ int mid=(lo+hi)>>1; if(batch[mid]<g) lo=mid+1; else hi=mid; }
  gptr[g]=lo;
}

__global__ void k_deg(const int* dst, int* deg){
  int e = blockIdx.x*256+threadIdx.x;
  if(e<EE) atomicAdd(&deg[dst[e]], 1);
}

__global__ __launch_bounds__(1024) void k_scan(const int* deg, int* rowptr){
  __shared__ int part[1024];
  int t = threadIdx.x;
  int base = t*128;
  int s = 0;
  for(int i=0;i<128;i++) s += deg[base+i];
  part[t] = s;
  __syncthreads();
  for(int off=1; off<1024; off<<=1){
    int v = part[t];
    int add = (t>=off)? part[t-off] : 0;
    __syncthreads();
    part[t] = v + add;
    __syncthreads();
  }
  int run = (t==0)? 0 : part[t-1];
  for(int i=0;i<128;i++){ rowptr[base+i] = run; run += deg[base+i]; }
  if(t==1023) rowptr[NN] = run;
}

__global__ void k_fill(const int* dst, const int* rowptr, int* cursor, int* eord){
  int e = blockIdx.x*256+threadIdx.x;
  if(e>=EE) return;
  int d = dst[e];
  int pos = atomicAdd(&cursor[d], 1);
  eord[rowptr[d]+pos] = e;
}

// ---- h0 = relu(x @ lin1W.T + b) -------------------------------------------
__global__ __launch_bounds__(256) void k_lin1_s(const float* x, const float* W, const float* b, float* h){
  __shared__ float sW[2048];
  __shared__ float sb[64];
  int t=threadIdx.x;
  for(int i=t;i<2048;i+=256) sW[i]=W[i];
  if(t<64) sb[t]=b[t];
  __syncthreads();
  int n = blockIdx.x*4 + (t>>6);
  int j = t&63;
  float acc = sb[j];
  for(int k=0;k<32;k++) acc += x[n*32+k]*sW[j*32+k];
  h[n*64+j] = fmaxf(acc, 0.0f);
}

// ---- k_msg: g12[N][128] = h @ [prW_dst | prW_src].T -> fp16 ---------------
__global__ __launch_bounds__(256) void k_msg(const float* h, const float* preW, _Float16* g12){
  __shared__ float sA[64][65];
  __shared__ float sB[64][65];
  int t=threadIdx.x;
  int rb = blockIdx.x*64;
  int coff = blockIdx.y ? 64 : 0;
  for(int q=0;q<16;q++){
    int idx = t*16+q;
    int a = idx>>6, bb = idx&63;
    sA[a][bb] = h[(rb+a)*64 + bb];
    sB[bb][a] = preW[a*192 + coff + bb];
  }
  __syncthreads();
  int r0=(t>>4)*4, c0=(t&15)*4;
  float acc[4][4] = {};
  for(int k=0;k<64;k++){
    float av[4], bv[4];
    #pragma unroll
    for(int i=0;i<4;i++) av[i]=sA[r0+i][k];
    #pragma unroll
    for(int jj=0;jj<4;jj++) bv[jj]=sB[k][c0+jj];
    #pragma unroll
    for(int i=0;i<4;i++){
      #pragma unroll
      for(int jj=0;jj<4;jj++) acc[i][jj]+=av[i]*bv[jj];
    }
  }
  for(int i=0;i<4;i++)
    for(int jj=0;jj<4;jj++)
      g12[(size_t)(rb+r0+i)*128 + coff + c0+jj] = (_Float16)acc[i][jj];
}

// ---- gather: m = g12[dst][j] + g12[src][64+j] + Wf[j]·ea + bf[j] ----------
// fp16 g12 in, fp32 math, fp16 agg out.
__global__ __launch_bounds__(256) void k_gather_f(const int* rowptr, const int* eord, const int* src,
      const float* ea, const _Float16* g12, const float* preW, const float* preb,
      const float* eW, const float* eb, _Float16* agg, float* s12, float avgdl){
  __shared__ float sWf[64][6];
  __shared__ float sbf[64];
  int t=threadIdx.x;
  for(int i=t; i<384; i+=256){
    int j=i/6, d=i-j*6;
    float a=0.0f;
    for(int k=0;k<64;k++) a += preW[j*192+128+k]*eW[k*6+d];
    sWf[j][d]=a;
  }
  if(t<64){
    float a=preb[t];
    for(int k=0;k<64;k++) a += preW[t*192+128+k]*eb[k];
    sbf[t]=a;
  }
  __syncthreads();
  int w=t>>6, j=t&63;
  float wf0=sWf[j][0], wf1=sWf[j][1], wf2=sWf[j][2];
  float wf3=sWf[j][3], wf4=sWf[j][4], wf5=sWf[j][5];
  float bfj=sbf[j];
  for(int it=0; it<8; ++it){
    int n = (blockIdx.x*4+w) + it*16384;
    int lo=rowptr[n], hi=rowptr[n+1];
    float mdst = (float)g12[(size_t)n*128+j] + bfj;
    float sum=0.0f, sq=0.0f, mn=1e30f, mx=-1e30f;
    for(int idx=lo; idx<hi; ++idx){
      int e = eord[idx];
      int s = src[e];
      float m = mdst + (float)g12[(size_t)s*128+64+j];
      m += ea[e*6+0]*wf0 + ea[e*6+1]*wf1 + ea[e*6+2]*wf2
         + ea[e*6+3]*wf3 + ea[e*6+4]*wf4 + ea[e*6+5]*wf5;
      sum += m; sq += m*m; mn = fminf(mn,m); mx = fmaxf(mx,m);
    }
    int c = hi-lo;
    float cm = fmaxf((float)c, 1.0f);
    float mean = sum/cm;
    float sd = sqrtf(fmaxf(sq/cm - mean*mean, 0.0f)+1e-5f);
    bool has = c>0;
    size_t base = (size_t)n*256;
    agg[base+j]     = (_Float16)mean;
    agg[base+64+j]  = (_Float16)(has?mn:0.0f);
    agg[base+128+j] = (_Float16)(has?mx:0.0f);
    agg[base+192+j] = (_Float16)sd;
    if(j==0){ float ld=logf(cm+1.0f); s12[n*2]=ld/avgdl; s12[n*2+1]=avgdl/ld; }
  }
}

// ---- k_tower_mfma: fused post_nn + scaler-combine + clin via fp16 MFMA ----
// A'[n][k] over K=832 = [h(64) | agg(256) | s1*agg(256) | s2*agg(256)]
// y1 = A' @ postW.T + postb ; y2 = fp16(y1) @ clinW.T + clinb
__global__ __launch_bounds__(256) void k_tower_mfma(const float* h, const _Float16* agg, const float* s12,
        const float* poW, const float* pob, const float* clW, const float* clb, float* y2){
  __shared__ _Float16 sAh[64][72];   // A' k-tile (fp16), later y1
  __shared__ _Float16 sBh[64][72];   // postW k-tile (fp16), later clinW
  __shared__ float sS[128];
  int t = threadIdx.x;
  int rb = blockIdx.x*64;
  int w = t>>6, l = t&63;
  int k = t&63, rB = t>>6;
  if (t < 128) sS[t] = s12[(size_t)(rb+(t>>1))*2 + (t&1)];
  f32x4 acc[4] = {};   // wave w owns output rows w*16..w*16+15
  for (int kt=0; kt<13; ++kt){
    __syncthreads();
    #pragma unroll
    for (int rr=0; rr<16; ++rr){
      int r = rB + rr*4;
      _Float16 v;
      if (kt==0)      v = (_Float16)h[(size_t)(rb+r)*64 + k];
      else if (kt<5)  v = agg[(size_t)(rb+r)*256 + (kt-1)*64 + k];
      else if (kt<9)  v = (_Float16)(sS[r*2]   * (float)agg[(size_t)(rb+r)*256 + (kt-5)*64 + k]);
      else            v = (_Float16)(sS[r*2+1] * (float)agg[(size_t)(rb+r)*256 + (kt-9)*64 + k]);
      sAh[r][k] = v;
      sBh[r][k] = (_Float16)poW[(size_t)r*832 + kt*64 + k];   // r = output col c
    }
    __syncthreads();
    #pragma unroll
    for (int kk=0; kk<2; ++kk){
      half8 a = *(const half8*)&sAh[w*16 + (l&15)][kk*32 + (l>>4)*8];
      #pragma unroll
      for (int n16=0; n16<4; ++n16){
        half8 b = *(const half8*)&sBh[n16*16 + (l&15)][kk*32 + (l>>4)*8];
        acc[n16] = __builtin_amdgcn_mfma_f32_16x16x32_f16(a, b, acc[n16], 0, 0, 0);
      }
    }
  }
  __syncthreads();   // all MFMA reads of sAh/sBh done
  // y1 (+bias) -> fp16 into sAh. D layout: col=lane&15, row=(lane>>4)*4+reg.
  #pragma unroll
  for (int n16=0; n16<4; ++n16){
    #pragma unroll
    for (int reg=0; reg<4; ++reg){
      int row = w*16 + (l>>4)*4 + reg;
      int col = n16*16 + (l&15);
      sAh[row][col] = (_Float16)(acc[n16][reg] + pob[col]);
    }
  }
  #pragma unroll
  for (int rr=0; rr<16; ++rr){
    int c = rB + rr*4;
    sBh[c][k] = (_Float16)clW[(size_t)c*64 + k];
  }
  __syncthreads();
  f32x4 cacc[4] = {};
  #pragma unroll
  for (int kk=0; kk<2; ++kk){
    half8 a = *(const half8*)&sAh[w*16 + (l&15)][kk*32 + (l>>4)*8];
    #pragma unroll
    for (int n16=0; n16<4; ++n16){
      half8 b = *(const half8*)&sBh[n16*16 + (l&15)][kk*32 + (l>>4)*8];
      cacc[n16] = __builtin_amdgcn_mfma_f32_16x16x32_f16(a, b, cacc[n16], 0, 0, 0);
    }
  }
  #pragma unroll
  for (int n16=0; n16<4; ++n16){
    #pragma unroll
    for (int reg=0; reg<4; ++reg){
      int row = w*16 + (l>>4)*4 + reg;
      int col = n16*16 + (l&15);
      y2[(size_t)(rb+row)*64 + col] = cacc[n16][reg] + clb[col];
    }
  }
}

// ---- BN: partials (double, no atomics) -> finalize -> apply + relu --------
__global__ __launch_bounds__(256) void k_bnpart(const float* y, double* part){
  __shared__ double sS[256], sQ[256];
  int t=threadIdx.x;
  int c=t&63, q=t>>6;
  int b=blockIdx.x;
  double s=0.0, s2=0.0;
  for(int i=0;i<64;i++){
    int n = b*256 + q + i*4;
    double v = (double)y[n*64+c];
    s += v; s2 += v*v;
  }
  sS[t]=s; sQ[t]=s2;
  __syncthreads();
  if(t<64){
    double S=sS[t]+sS[t+64]+sS[t+128]+sS[t+192];
    double Q=sQ[t]+sQ[t+64]+sQ[t+128]+sQ[t+192];
    part[b*128+t]=S; part[b*128+64+t]=Q;
  }
}

__global__ void k_bnfin(const double* part, const float* g, const float* bb, float* sc, float* sh){
  int c = threadIdx.x;
  if(c>=64) return;
  double S=0.0, Q=0.0;
  for(int b=0;b<512;b++){ S+=part[b*128+c]; Q+=part[b*128+64+c]; }
  double mean = S/(double)NN;
  double var  = Q/(double)NN - mean*mean;
  float scale = g[c] * (float)(1.0/sqrt(var+1e-5));
  sc[c]=scale;
  sh[c]=bb[c] - (float)mean*scale;
}

__global__ void k_bnapply2(const float* y, float* h, const float* sc, const float* sh){
  int idx = blockIdx.x*256+threadIdx.x;
  const float4* y4=(const float4*)y;
  float4* h4=(float4*)h;
  for(int i=idx; i<NN*16; i+=256*4096){
    int c4=(i&15)*4;
    float4 v=y4[i];
    float r[4]={v.x,v.y,v.z,v.w};
    #pragma unroll
    for(int qq=0;qq<4;qq++){ int c=c4+qq; r[qq]=fmaxf(r[qq]*sc[c]+sh[c], 0.0f); }
    h4[i]=make_float4(r[0],r[1],r[2],r[3]);
  }
}

// ---- set2set (literal LSTM: raw Wih/Whh) ----------------------------------
__global__ __launch_bounds__(256) void k_lstm_lit(float* A, float* cs,
      const float* Wih, const float* Whh, const float* bih, const float* bhh){
  __shared__ float sA[128]; __shared__ float sg[256];
  int g=blockIdx.x, t=threadIdx.x;
  if(t<128) sA[t]=A[g*128+t];
  __syncthreads();
  float a = bih[t] + bhh[t];
  for(int k=0;k<128;k++) a += Wih[t*128+k]*sA[k];
  for(int k=0;k<64;k++)  a += Whh[t*64+k]*sA[k];
  sg[t]=a;
  __syncthreads();
  if(t<64){
    float ig=sg[t], fg=sg[64+t], gg=sg[128+t], og=sg[192+t];
    float c = sigmoidf_(fg)*cs[g*64+t] + sigmoidf_(ig)*tanhf(gg);
    float hv = sigmoidf_(og)*tanhf(c);
    cs[g*64+t]=c;
    A[g*128+t]=hv;
  }
}

__global__ __launch_bounds__(256) void k_edot(const float* h, const float* A, const int* batch, float* e){
  int t=threadIdx.x, w=t>>6, j=t&63;
  for(int it=0;it<16;++it){
    int n=(blockIdx.x*4+w)+it*8192;
    int g=batch[n];
    float v=h[n*64+j]*A[g*128+j];
    #pragma unroll
    for(int m=32;m;m>>=1) v+=__shfl_xor(v,m,64);
    if(j==0) e[n]=v;
  }
}

__global__ __launch_bounds__(64) void k_attn(const float* h, const float* e, const int* gptr, float* A){
  int g=blockIdx.x, j=threadIdx.x;
  int lo=gptr[g], hi=gptr[g+1];
  if(lo>=hi){ A[g*128+64+j]=0.0f; return; }
  float mx=-1e30f;
  for(int n=lo+j;n<hi;n+=64) mx=fmaxf(mx,e[n]);
  #pragma unroll
  for(int m=32;m;m>>=1) mx=fmaxf(mx,__shfl_xor(mx,m,64));
  float s=0.0f;
  for(int n=lo+j;n<hi;n+=64) s+=expf(e[n]-mx);
  #pragma unroll
  for(int m=32;m;m>>=1) s+=__shfl_xor(s,m,64);
  float inv=1.0f/(s+1e-16f);
  float r=0.0f;
  for(int n=lo;n<hi;++n){
    float a=expf(e[n]-mx)*inv;
    r+=a*h[n*64+j];
  }
  A[g*128+64+j]=r;
}

__global__ __launch_bounds__(64) void k_mlp(const float* A, const float* tt, const float* pp,
     const float* W1,const float* b1,const float* W2,const float* b2,const float* W3,const float* b3,
     float* out){
  __shared__ float si[130]; __shared__ float o1[64]; __shared__ float o2[32];
  int g=blockIdx.x, t=threadIdx.x;
  si[t]=A[g*128+t]; si[64+t]=A[g*128+64+t];
  if(t==0){ si[128]=tt[g]; si[129]=pp[g]; }
  __syncthreads();
  float a=b1[t];
  for(int k=0;k<130;k++) a+=W1[t*130+k]*si[k];
  o1[t]=fmaxf(a,0.0f);
  __syncthreads();
  if(t<32){
    float a2=b2[t];
    #pragma unroll 4
    for(int k=0;k<64;k++) a2+=W2[t*64+k]*o1[k];
    o2[t]=fmaxf(a2,0.0f);
  }
  __syncthreads();
  float v = (t<32)? o2[t]*W3[t] : 0.0f;
  #pragma unroll
  for(int m=32;m;m>>=1) v+=__shfl_xor(v,m,64);
  if(t==0) out[g]=v+b3[0];
}

// ---- host -----------------------------------------------------------------
extern "C" void kernel_launch(void* const* d_in, const int* in_sizes, int n_in,
                              void* d_out, int out_size, void* d_ws, size_t ws_size,
                              hipStream_t stream) {
  static const int want[28] = {4194304,3145728,4096,4096,2048,64,1152,192,36864,192,
                               159744,192,12288,192,192,192,32768,16384,256,256,
                               8320,64,2048,32,32,1,1048576,131072};
  if (n_in != 28 || out_size != GG) return;
  for (int i=0;i<28;i++) if (in_sizes[i] != want[i]) return;

  const float* x     = (const float*)d_in[0];
  const float* ea    = (const float*)d_in[1];
  const float* tt    = (const float*)d_in[2];
  const float* pp    = (const float*)d_in[3];
  const float* lin1W = (const float*)d_in[4];
  const float* lin1b = (const float*)d_in[5];
  const float* edgeW = (const float*)d_in[6];
  const float* edgeb = (const float*)d_in[7];
  const float* preW  = (const float*)d_in[8];
  const float* preb  = (const float*)d_in[9];
  const float* postW = (const float*)d_in[10];
  const float* postb = (const float*)d_in[11];
  const float* clinW = (const float*)d_in[12];
  const float* clinb = (const float*)d_in[13];
  const float* bng   = (const float*)d_in[14];
  const float* bnb   = (const float*)d_in[15];
  const float* Wih   = (const float*)d_in[16];
  const float* Whh   = (const float*)d_in[17];
  const float* bih   = (const float*)d_in[18];
  const float* bhh   = (const float*)d_in[19];
  const float* W1    = (const float*)d_in[20];
  const float* b1    = (const float*)d_in[21];
  const float* W2    = (const float*)d_in[22];
  const float* b2    = (const float*)d_in[23];
  const float* W3    = (const float*)d_in[24];
  const float* b3    = (const float*)d_in[25];
  const int*   eidx  = (const int*)d_in[26];
  const int*   batch = (const int*)d_in[27];
  const int* esrc = eidx;
  const int* edst = eidx + EE;

  char* w = (char*)d_ws;
  auto alloc = [&](size_t bytes)->char*{ char* p=w; w += ((bytes+255)/256)*256; return p; };
  _Float16* agg  = (_Float16*)alloc((size_t)NN*256*2);  // 64MiB fp16
  _Float16* g12  = (_Float16*)alloc((size_t)NN*128*2);  // 32MiB fp16 (y2 fp32 aliases)
  float* hbuf    = (float*)alloc((size_t)NN*64*4);      // 32MiB
  int*   deg    = (int*)alloc((size_t)NN*4);
  int*   cursor = (int*)alloc((size_t)NN*4);
  int*   rowptr = (int*)alloc((size_t)(NN+1)*4);
  int*   eord   = (int*)alloc((size_t)EE*4);
  float* s12   = (float*)alloc((size_t)NN*2*4);
  double* part = (double*)alloc((size_t)512*128*8);
  float* bnsc  = (float*)alloc(256);
  float* bnsh  = (float*)alloc(256);
  int*   gptr  = (int*)alloc((GG+1)*4);
  size_t need = (size_t)(w - (char*)d_ws);
  if (need > ws_size) return;
  // y2 (fp32, 32MiB) aliases the g12 region (g12 dead after k_gather_f;
  // NN*128 fp16 = NN*64 fp32 bytes exactly)
  float* y2   = (float*)g12;
  float* A    = (float*)g12;               // set2set scratch (after layers done)
  float* cs   = (float*)g12 + (size_t)GG*128;
  float* escr = (float*)g12 + (size_t)GG*192;

  double num = 13107.0*log(2.0)+26214.0*log(3.0)+65536.0*log(4.0)+26215.0*log(5.0);
  float avgdl = (float)(num/131072.0);

  hipMemsetAsync(deg, 0, (size_t)NN*4, stream);
  hipMemsetAsync(cursor, 0, (size_t)NN*4, stream);
  hipLaunchKernelGGL(k_deg, dim3(2048), dim3(256), 0, stream, edst, deg);
  hipLaunchKernelGGL(k_scan, dim3(1), dim3(1024), 0, stream, deg, rowptr);
  hipLaunchKernelGGL(k_fill, dim3(2048), dim3(256), 0, stream, edst, rowptr, cursor, eord);

  hipLaunchKernelGGL(k_gptr, dim3(17), dim3(256), 0, stream, batch, gptr);
  hipLaunchKernelGGL(k_lin1_s, dim3(32768), dim3(256), 0, stream, x, lin1W, lin1b, hbuf);

  for (int i = 0; i < 3; ++i){
    hipLaunchKernelGGL(k_msg, dim3(2048,2), dim3(256), 0, stream, hbuf,
        preW + (size_t)i*64*192, g12);
    hipLaunchKernelGGL(k_gather_f, dim3(4096), dim3(256), 0, stream, rowptr, eord, esrc, ea, g12,
        preW + (size_t)i*64*192, preb + i*64, edgeW + (size_t)i*384, edgeb + i*64, agg, s12, avgdl);
    hipLaunchKernelGGL(k_tower_mfma, dim3(2048), dim3(256), 0, stream, hbuf, agg, s12,
        postW + (size_t)i*64*832, postb + i*64, clinW + (size_t)i*4096, clinb + i*64, y2);
    hipLaunchKernelGGL(k_bnpart, dim3(512), dim3(256), 0, stream, y2, part);
    hipLaunchKernelGGL(k_bnfin, dim3(1), dim3(64), 0, stream, part, bng + i*64, bnb + i*64, bnsc, bnsh);
    hipLaunchKernelGGL(k_bnapply2, dim3(4096), dim3(256), 0, stream, y2, hbuf, bnsc, bnsh);
  }

  hipMemsetAsync(A, 0, (size_t)GG*128*4, stream);
  hipMemsetAsync(cs, 0, (size_t)GG*64*4, stream);
  for (int s = 0; s < 3; ++s){
    hipLaunchKernelGGL(k_lstm_lit, dim3(GG), dim3(256), 0, stream, A, cs, Wih, Whh, bih, bhh);
    hipLaunchKernelGGL(k_edot, dim3(2048), dim3(256), 0, stream, hbuf, A, batch, escr);
    hipLaunchKernelGGL(k_attn, dim3(GG), dim3(64), 0, stream, hbuf, escr, gptr, A);
  }
  hipLaunchKernelGGL(k_mlp, dim3(GG), dim3(64), 0, stream, A, tt, pp, W1, b1, W2, b2, W3, b3, (float*)d_out);
}

// Round 12
// 1655.765 us; speedup vs baseline: 2.7494x; 1.0317x over previous
//
#include <hip/hip_runtime.h>
#include <hip/hip_bf16.h>
#include <math.h>

#define NN 131072
#define EE 524288
#define GG 4096

typedef __attribute__((ext_vector_type(8))) _Float16 half8;
typedef __attribute__((ext_vector_type(4))) float f32x4;

__device__ __forceinline__ float sigmoidf_(float x){ return 1.0f/(1.0f+expf(-x)); }

// ---- grouping / CSR (integer atomics only) --------------------------------
__global__ void k_gptr(const int* batch, int* gptr){
  int g = blockIdx.x*256+threadIdx.x;
  if (g > GG) return;
  if (g == GG){ gptr[GG]=NN; return; }
  int lo=0, hi=NN;
  while(lo<hi){ int mid=(lo+hi)>>1; if(batch[mid]<g) lo=mid+1; else hi=mid; }
  gptr[g]=lo;
}

__global__ void k_deg(const int* dst, int* deg){
  int e = blockIdx.x*256+threadIdx.x;
  if(e<EE) atomicAdd(&deg[dst[e]], 1);
}

__global__ __launch_bounds__(1024) void k_scan(const int* deg, int* rowptr){
  __shared__ int part[1024];
  int t = threadIdx.x;
  int base = t*128;
  int s = 0;
  for(int i=0;i<128;i++) s += deg[base+i];
  part[t] = s;
  __syncthreads();
  for(int off=1; off<1024; off<<=1){
    int v = part[t];
    int add = (t>=off)? part[t-off] : 0;
    __syncthreads();
    part[t] = v + add;
    __syncthreads();
  }
  int run = (t==0)? 0 : part[t-1];
  for(int i=0;i<128;i++){ rowptr[base+i] = run; run += deg[base+i]; }
  if(t==1023) rowptr[NN] = run;
}

// fill CSR-ordered edge streams: srcord[idx], eaord[idx][6]
__global__ void k_fill(const int* dst, const int* src, const float* ea,
                       const int* rowptr, int* cursor, int* srcord, float* eaord){
  int e = blockIdx.x*256+threadIdx.x;
  if(e>=EE) return;
  int d = dst[e];
  int pos = atomicAdd(&cursor[d], 1);
  int idx = rowptr[d]+pos;
  srcord[idx] = src[e];
  #pragma unroll
  for(int q=0;q<6;q++) eaord[(size_t)idx*6+q] = ea[(size_t)e*6+q];
}

// ---- h0 = relu(x @ lin1W.T + b) -------------------------------------------
__global__ __launch_bounds__(256) void k_lin1_s(const float* x, const float* W, const float* b, float* h){
  __shared__ float sW[2048];
  __shared__ float sb[64];
  int t=threadIdx.x;
  for(int i=t;i<2048;i+=256) sW[i]=W[i];
  if(t<64) sb[t]=b[t];
  __syncthreads();
  int n = blockIdx.x*4 + (t>>6);
  int j = t&63;
  float acc = sb[j];
  for(int k=0;k<32;k++) acc += x[n*32+k]*sW[j*32+k];
  h[n*64+j] = fmaxf(acc, 0.0f);
}

// ---- k_msg: g12[N][128] = h @ [prW_dst | prW_src].T -> fp16 ---------------
__global__ __launch_bounds__(256) void k_msg(const float* h, const float* preW, _Float16* g12){
  __shared__ float sA[64][65];
  __shared__ float sB[64][65];
  int t=threadIdx.x;
  int rb = blockIdx.x*64;
  int coff = blockIdx.y ? 64 : 0;
  for(int q=0;q<16;q++){
    int idx = t*16+q;
    int a = idx>>6, bb = idx&63;
    sA[a][bb] = h[(rb+a)*64 + bb];
    sB[bb][a] = preW[a*192 + coff + bb];
  }
  __syncthreads();
  int r0=(t>>4)*4, c0=(t&15)*4;
  float acc[4][4] = {};
  for(int k=0;k<64;k++){
    float av[4], bv[4];
    #pragma unroll
    for(int i=0;i<4;i++) av[i]=sA[r0+i][k];
    #pragma unroll
    for(int jj=0;jj<4;jj++) bv[jj]=sB[k][c0+jj];
    #pragma unroll
    for(int i=0;i<4;i++){
      #pragma unroll
      for(int jj=0;jj<4;jj++) acc[i][jj]+=av[i]*bv[jj];
    }
  }
  for(int i=0;i<4;i++)
    for(int jj=0;jj<4;jj++)
      g12[(size_t)(rb+r0+i)*128 + coff + c0+jj] = (_Float16)acc[i][jj];
}

// ---- gather: m = g12[dst][j] + g12[src][64+j] + Wf[j]·ea + bf[j] ----------
// CSR-ordered streams (srcord/eaord) kill the eord->src indirection; 2-way
// edge unroll gives 2 independent load chains per lane.
__global__ __launch_bounds__(256) void k_gather_f(const int* rowptr, const int* srcord,
      const float* eaord, const _Float16* g12, const float* preW, const float* preb,
      const float* eW, const float* eb, _Float16* agg, float* s12, float avgdl){
  __shared__ float sWf[64][6];
  __shared__ float sbf[64];
  int t=threadIdx.x;
  for(int i=t; i<384; i+=256){
    int j=i/6, d=i-j*6;
    float a=0.0f;
    for(int k=0;k<64;k++) a += preW[j*192+128+k]*eW[k*6+d];
    sWf[j][d]=a;
  }
  if(t<64){
    float a=preb[t];
    for(int k=0;k<64;k++) a += preW[t*192+128+k]*eb[k];
    sbf[t]=a;
  }
  __syncthreads();
  int w=t>>6, j=t&63;
  float wf0=sWf[j][0], wf1=sWf[j][1], wf2=sWf[j][2];
  float wf3=sWf[j][3], wf4=sWf[j][4], wf5=sWf[j][5];
  float bfj=sbf[j];
  for(int it=0; it<8; ++it){
    int n = (blockIdx.x*4+w) + it*16384;
    int lo=rowptr[n], hi=rowptr[n+1];
    float mdst = (float)g12[(size_t)n*128+j] + bfj;
    float sum=0.0f, sq=0.0f, mn=1e30f, mx=-1e30f;
    int idx=lo;
    for(; idx+1<hi; idx+=2){
      int s0 = srcord[idx], s1 = srcord[idx+1];
      float2 a0 = *(const float2*)&eaord[(size_t)idx*6];
      float2 a1 = *(const float2*)&eaord[(size_t)idx*6+2];
      float2 a2 = *(const float2*)&eaord[(size_t)idx*6+4];
      float2 b0 = *(const float2*)&eaord[(size_t)(idx+1)*6];
      float2 b1 = *(const float2*)&eaord[(size_t)(idx+1)*6+2];
      float2 b2 = *(const float2*)&eaord[(size_t)(idx+1)*6+4];
      float g0 = (float)g12[(size_t)s0*128+64+j];
      float g1 = (float)g12[(size_t)s1*128+64+j];
      float m0 = mdst + g0 + a0.x*wf0 + a0.y*wf1 + a1.x*wf2 + a1.y*wf3 + a2.x*wf4 + a2.y*wf5;
      float m1 = mdst + g1 + b0.x*wf0 + b0.y*wf1 + b1.x*wf2 + b1.y*wf3 + b2.x*wf4 + b2.y*wf5;
      sum += m0; sq += m0*m0; mn = fminf(mn,m0); mx = fmaxf(mx,m0);
      sum += m1; sq += m1*m1; mn = fminf(mn,m1); mx = fmaxf(mx,m1);
    }
    if(idx<hi){
      int s0 = srcord[idx];
      float2 a0 = *(const float2*)&eaord[(size_t)idx*6];
      float2 a1 = *(const float2*)&eaord[(size_t)idx*6+2];
      float2 a2 = *(const float2*)&eaord[(size_t)idx*6+4];
      float g0 = (float)g12[(size_t)s0*128+64+j];
      float m0 = mdst + g0 + a0.x*wf0 + a0.y*wf1 + a1.x*wf2 + a1.y*wf3 + a2.x*wf4 + a2.y*wf5;
      sum += m0; sq += m0*m0; mn = fminf(mn,m0); mx = fmaxf(mx,m0);
    }
    int c = hi-lo;
    float cm = fmaxf((float)c, 1.0f);
    float mean = sum/cm;
    float sd = sqrtf(fmaxf(sq/cm - mean*mean, 0.0f)+1e-5f);
    bool has = c>0;
    size_t base = (size_t)n*256;
    agg[base+j]     = (_Float16)mean;
    agg[base+64+j]  = (_Float16)(has?mn:0.0f);
    agg[base+128+j] = (_Float16)(has?mx:0.0f);
    agg[base+192+j] = (_Float16)sd;
    if(j==0){ float ld=logf(cm+1.0f); s12[n*2]=ld/avgdl; s12[n*2+1]=avgdl/ld; }
  }
}

// ---- k_tower_mfma: fused post_nn + scaler-combine + clin via fp16 MFMA ----
__global__ __launch_bounds__(256) void k_tower_mfma(const float* h, const _Float16* agg, const float* s12,
        const float* poW, const float* pob, const float* clW, const float* clb, float* y2){
  __shared__ _Float16 sAh[64][72];   // A' k-tile (fp16), later y1
  __shared__ _Float16 sBh[64][72];   // postW k-tile (fp16), later clinW
  __shared__ float sS[128];
  int t = threadIdx.x;
  int rb = blockIdx.x*64;
  int w = t>>6, l = t&63;
  int k = t&63, rB = t>>6;
  if (t < 128) sS[t] = s12[(size_t)(rb+(t>>1))*2 + (t&1)];
  f32x4 acc[4] = {};
  for (int kt=0; kt<13; ++kt){
    __syncthreads();
    #pragma unroll
    for (int rr=0; rr<16; ++rr){
      int r = rB + rr*4;
      _Float16 v;
      if (kt==0)      v = (_Float16)h[(size_t)(rb+r)*64 + k];
      else if (kt<5)  v = agg[(size_t)(rb+r)*256 + (kt-1)*64 + k];
      else if (kt<9)  v = (_Float16)(sS[r*2]   * (float)agg[(size_t)(rb+r)*256 + (kt-5)*64 + k]);
      else            v = (_Float16)(sS[r*2+1] * (float)agg[(size_t)(rb+r)*256 + (kt-9)*64 + k]);
      sAh[r][k] = v;
      sBh[r][k] = (_Float16)poW[(size_t)r*832 + kt*64 + k];
    }
    __syncthreads();
    #pragma unroll
    for (int kk=0; kk<2; ++kk){
      half8 a = *(const half8*)&sAh[w*16 + (l&15)][kk*32 + (l>>4)*8];
      #pragma unroll
      for (int n16=0; n16<4; ++n16){
        half8 b = *(const half8*)&sBh[n16*16 + (l&15)][kk*32 + (l>>4)*8];
        acc[n16] = __builtin_amdgcn_mfma_f32_16x16x32_f16(a, b, acc[n16], 0, 0, 0);
      }
    }
  }
  __syncthreads();
  #pragma unroll
  for (int n16=0; n16<4; ++n16){
    #pragma unroll
    for (int reg=0; reg<4; ++reg){
      int row = w*16 + (l>>4)*4 + reg;
      int col = n16*16 + (l&15);
      sAh[row][col] = (_Float16)(acc[n16][reg] + pob[col]);
    }
  }
  #pragma unroll
  for (int rr=0; rr<16; ++rr){
    int c = rB + rr*4;
    sBh[c][k] = (_Float16)clW[(size_t)c*64 + k];
  }
  __syncthreads();
  f32x4 cacc[4] = {};
  #pragma unroll
  for (int kk=0; kk<2; ++kk){
    half8 a = *(const half8*)&sAh[w*16 + (l&15)][kk*32 + (l>>4)*8];
    #pragma unroll
    for (int n16=0; n16<4; ++n16){
      half8 b = *(const half8*)&sBh[n16*16 + (l&15)][kk*32 + (l>>4)*8];
      cacc[n16] = __builtin_amdgcn_mfma_f32_16x16x32_f16(a, b, cacc[n16], 0, 0, 0);
    }
  }
  #pragma unroll
  for (int n16=0; n16<4; ++n16){
    #pragma unroll
    for (int reg=0; reg<4; ++reg){
      int row = w*16 + (l>>4)*4 + reg;
      int col = n16*16 + (l&15);
      y2[(size_t)(rb+row)*64 + col] = cacc[n16][reg] + clb[col];
    }
  }
}

// ---- BN: partials (double, no atomics) -> finalize -> apply + relu --------
__global__ __launch_bounds__(256) void k_bnpart(const float* y, double* part){
  __shared__ double sS[256], sQ[256];
  int t=threadIdx.x;
  int c=t&63, q=t>>6;
  int b=blockIdx.x;
  double s=0.0, s2=0.0;
  for(int i=0;i<64;i++){
    int n = b*256 + q + i*4;
    double v = (double)y[n*64+c];
    s += v; s2 += v*v;
  }
  sS[t]=s; sQ[t]=s2;
  __syncthreads();
  if(t<64){
    double S=sS[t]+sS[t+64]+sS[t+128]+sS[t+192];
    double Q=sQ[t]+sQ[t+64]+sQ[t+128]+sQ[t+192];
    part[b*128+t]=S; part[b*128+64+t]=Q;
  }
}

__global__ void k_bnfin(const double* part, const float* g, const float* bb, float* sc, float* sh){
  int c = threadIdx.x;
  if(c>=64) return;
  double S=0.0, Q=0.0;
  for(int b=0;b<512;b++){ S+=part[b*128+c]; Q+=part[b*128+64+c]; }
  double mean = S/(double)NN;
  double var  = Q/(double)NN - mean*mean;
  float scale = g[c] * (float)(1.0/sqrt(var+1e-5));
  sc[c]=scale;
  sh[c]=bb[c] - (float)mean*scale;
}

__global__ void k_bnapply2(const float* y, float* h, const float* sc, const float* sh){
  int idx = blockIdx.x*256+threadIdx.x;
  const float4* y4=(const float4*)y;
  float4* h4=(float4*)h;
  for(int i=idx; i<NN*16; i+=256*4096){
    int c4=(i&15)*4;
    float4 v=y4[i];
    float r[4]={v.x,v.y,v.z,v.w};
    #pragma unroll
    for(int qq=0;qq<4;qq++){ int c=c4+qq; r[qq]=fmaxf(r[qq]*sc[c]+sh[c], 0.0f); }
    h4[i]=make_float4(r[0],r[1],r[2],r[3]);
  }
}

// ---- set2set (literal LSTM: raw Wih/Whh) ----------------------------------
__global__ __launch_bounds__(256) void k_lstm_lit(float* A, float* cs,
      const float* Wih, const float* Whh, const float* bih, const float* bhh){
  __shared__ float sA[128]; __shared__ float sg[256];
  int g=blockIdx.x, t=threadIdx.x;
  if(t<128) sA[t]=A[g*128+t];
  __syncthreads();
  float a = bih[t] + bhh[t];
  for(int k=0;k<128;k++) a += Wih[t*128+k]*sA[k];
  for(int k=0;k<64;k++)  a += Whh[t*64+k]*sA[k];
  sg[t]=a;
  __syncthreads();
  if(t<64){
    float ig=sg[t], fg=sg[64+t], gg=sg[128+t], og=sg[192+t];
    float c = sigmoidf_(fg)*cs[g*64+t] + sigmoidf_(ig)*tanhf(gg);
    float hv = sigmoidf_(og)*tanhf(c);
    cs[g*64+t]=c;
    A[g*128+t]=hv;
  }
}

__global__ __launch_bounds__(256) void k_edot(const float* h, const float* A, const int* batch, float* e){
  int t=threadIdx.x, w=t>>6, j=t&63;
  for(int it=0;it<16;++it){
    int n=(blockIdx.x*4+w)+it*8192;
    int g=batch[n];
    float v=h[n*64+j]*A[g*128+j];
    #pragma unroll
    for(int m=32;m;m>>=1) v+=__shfl_xor(v,m,64);
    if(j==0) e[n]=v;
  }
}

__global__ __launch_bounds__(64) void k_attn(const float* h, const float* e, const int* gptr, float* A){
  int g=blockIdx.x, j=threadIdx.x;
  int lo=gptr[g], hi=gptr[g+1];
  if(lo>=hi){ A[g*128+64+j]=0.0f; return; }
  float mx=-1e30f;
  for(int n=lo+j;n<hi;n+=64) mx=fmaxf(mx,e[n]);
  #pragma unroll
  for(int m=32;m;m>>=1) mx=fmaxf(mx,__shfl_xor(mx,m,64));
  float s=0.0f;
  for(int n=lo+j;n<hi;n+=64) s+=expf(e[n]-mx);
  #pragma unroll
  for(int m=32;m;m>>=1) s+=__shfl_xor(s,m,64);
  float inv=1.0f/(s+1e-16f);
  float r=0.0f;
  for(int n=lo;n<hi;++n){
    float a=expf(e[n]-mx)*inv;
    r+=a*h[n*64+j];
  }
  A[g*128+64+j]=r;
}

__global__ __launch_bounds__(64) void k_mlp(const float* A, const float* tt, const float* pp,
     const float* W1,const float* b1,const float* W2,const float* b2,const float* W3,const float* b3,
     float* out){
  __shared__ float si[130]; __shared__ float o1[64]; __shared__ float o2[32];
  int g=blockIdx.x, t=threadIdx.x;
  si[t]=A[g*128+t]; si[64+t]=A[g*128+64+t];
  if(t==0){ si[128]=tt[g]; si[129]=pp[g]; }
  __syncthreads();
  float a=b1[t];
  for(int k=0;k<130;k++) a+=W1[t*130+k]*si[k];
  o1[t]=fmaxf(a,0.0f);
  __syncthreads();
  if(t<32){
    float a2=b2[t];
    #pragma unroll 4
    for(int k=0;k<64;k++) a2+=W2[t*64+k]*o1[k];
    o2[t]=fmaxf(a2,0.0f);
  }
  __syncthreads();
  float v = (t<32)? o2[t]*W3[t] : 0.0f;
  #pragma unroll
  for(int m=32;m;m>>=1) v+=__shfl_xor(v,m,64);
  if(t==0) out[g]=v+b3[0];
}

// ---- host -----------------------------------------------------------------
extern "C" void kernel_launch(void* const* d_in, const int* in_sizes, int n_in,
                              void* d_out, int out_size, void* d_ws, size_t ws_size,
                              hipStream_t stream) {
  static const int want[28] = {4194304,3145728,4096,4096,2048,64,1152,192,36864,192,
                               159744,192,12288,192,192,192,32768,16384,256,256,
                               8320,64,2048,32,32,1,1048576,131072};
  if (n_in != 28 || out_size != GG) return;
  for (int i=0;i<28;i++) if (in_sizes[i] != want[i]) return;

  const float* x     = (const float*)d_in[0];
  const float* ea    = (const float*)d_in[1];
  const float* tt    = (const float*)d_in[2];
  const float* pp    = (const float*)d_in[3];
  const float* lin1W = (const float*)d_in[4];
  const float* lin1b = (const float*)d_in[5];
  const float* edgeW = (const float*)d_in[6];
  const float* edgeb = (const float*)d_in[7];
  const float* preW  = (const float*)d_in[8];
  const float* preb  = (const float*)d_in[9];
  const float* postW = (const float*)d_in[10];
  const float* postb = (const float*)d_in[11];
  const float* clinW = (const float*)d_in[12];
  const float* clinb = (const float*)d_in[13];
  const float* bng   = (const float*)d_in[14];
  const float* bnb   = (const float*)d_in[15];
  const float* Wih   = (const float*)d_in[16];
  const float* Whh   = (const float*)d_in[17];
  const float* bih   = (const float*)d_in[18];
  const float* bhh   = (const float*)d_in[19];
  const float* W1    = (const float*)d_in[20];
  const float* b1    = (const float*)d_in[21];
  const float* W2    = (const float*)d_in[22];
  const float* b2    = (const float*)d_in[23];
  const float* W3    = (const float*)d_in[24];
  const float* b3    = (const float*)d_in[25];
  const int*   eidx  = (const int*)d_in[26];
  const int*   batch = (const int*)d_in[27];
  const int* esrc = eidx;
  const int* edst = eidx + EE;

  char* w = (char*)d_ws;
  auto alloc = [&](size_t bytes)->char*{ char* p=w; w += ((bytes+255)/256)*256; return p; };
  _Float16* agg  = (_Float16*)alloc((size_t)NN*256*2);  // 64MiB fp16
  _Float16* g12  = (_Float16*)alloc((size_t)NN*128*2);  // 32MiB fp16 (y2 fp32 aliases)
  float* hbuf    = (float*)alloc((size_t)NN*64*4);      // 32MiB
  int*   deg    = (int*)alloc((size_t)NN*4);
  int*   cursor = (int*)alloc((size_t)NN*4);
  int*   rowptr = (int*)alloc((size_t)(NN+1)*4);
  int*   srcord = (int*)alloc((size_t)EE*4);
  float* eaord  = (float*)alloc((size_t)EE*6*4);        // 12.6MB CSR-ordered edge attrs
  float* s12   = (float*)alloc((size_t)NN*2*4);
  double* part = (double*)alloc((size_t)512*128*8);
  float* bnsc  = (float*)alloc(256);
  float* bnsh  = (float*)alloc(256);
  int*   gptr  = (int*)alloc((GG+1)*4);
  size_t need = (size_t)(w - (char*)d_ws);
  if (need > ws_size) return;
  // y2 (fp32, 32MiB) aliases the g12 region (g12 dead after k_gather_f)
  float* y2   = (float*)g12;
  float* A    = (float*)g12;               // set2set scratch (after layers done)
  float* cs   = (float*)g12 + (size_t)GG*128;
  float* escr = (float*)g12 + (size_t)GG*192;

  double num = 13107.0*log(2.0)+26214.0*log(3.0)+65536.0*log(4.0)+26215.0*log(5.0);
  float avgdl = (float)(num/131072.0);

  hipMemsetAsync(deg, 0, (size_t)NN*4, stream);
  hipMemsetAsync(cursor, 0, (size_t)NN*4, stream);
  hipLaunchKernelGGL(k_deg, dim3(2048), dim3(256), 0, stream, edst, deg);
  hipLaunchKernelGGL(k_scan, dim3(1), dim3(1024), 0, stream, deg, rowptr);
  hipLaunchKernelGGL(k_fill, dim3(2048), dim3(256), 0, stream, edst, esrc, ea, rowptr, cursor, srcord, eaord);

  hipLaunchKernelGGL(k_gptr, dim3(17), dim3(256), 0, stream, batch, gptr);
  hipLaunchKernelGGL(k_lin1_s, dim3(32768), dim3(256), 0, stream, x, lin1W, lin1b, hbuf);

  for (int i = 0; i < 3; ++i){
    hipLaunchKernelGGL(k_msg, dim3(2048,2), dim3(256), 0, stream, hbuf,
        preW + (size_t)i*64*192, g12);
    hipLaunchKernelGGL(k_gather_f, dim3(4096), dim3(256), 0, stream, rowptr, srcord, eaord, g12,
        preW + (size_t)i*64*192, preb + i*64, edgeW + (size_t)i*384, edgeb + i*64, agg, s12, avgdl);
    hipLaunchKernelGGL(k_tower_mfma, dim3(2048), dim3(256), 0, stream, hbuf, agg, s12,
        postW + (size_t)i*64*832, postb + i*64, clinW + (size_t)i*4096, clinb + i*64, y2);
    hipLaunchKernelGGL(k_bnpart, dim3(512), dim3(256), 0, stream, y2, part);
    hipLaunchKernelGGL(k_bnfin, dim3(1), dim3(64), 0, stream, part, bng + i*64, bnb + i*64, bnsc, bnsh);
    hipLaunchKernelGGL(k_bnapply2, dim3(4096), dim3(256), 0, stream, y2, hbuf, bnsc, bnsh);
  }

  hipMemsetAsync(A, 0, (size_t)GG*128*4, stream);
  hipMemsetAsync(cs, 0, (size_t)GG*64*4, stream);
  for (int s = 0; s < 3; ++s){
    hipLaunchKernelGGL(k_lstm_lit, dim3(GG), dim3(256), 0, stream, A, cs, Wih, Whh, bih, bhh);
    hipLaunchKernelGGL(k_edot, dim3(2048), dim3(256), 0, stream, hbuf, A, batch, escr);
    hipLaunchKernelGGL(k_attn, dim3(GG), dim3(64), 0, stream, hbuf, escr, gptr, A);
  }
  hipLaunchKernelGGL(k_mlp, dim3(GG), dim3(64), 0, stream, A, tt, pp, W1, b1, W2, b2, W3, b3, (float*)d_out);
}

// Round 13
// 1483.659 us; speedup vs baseline: 3.0684x; 1.1160x over previous
//
#include <hip/hip_runtime.h>
#include <hip/hip_bf16.h>
#include <math.h>

#define NN 131072
#define EE 524288
#define GG 4096

typedef __attribute__((ext_vector_type(8))) _Float16 half8;
typedef __attribute__((ext_vector_type(4))) float f32x4;

__device__ __forceinline__ float sigmoidf_(float x){ return 1.0f/(1.0f+expf(-x)); }

// ---- grouping / CSR (integer atomics only) --------------------------------
__global__ void k_gptr(const int* batch, int* gptr){
  int g = blockIdx.x*256+threadIdx.x;
  if (g > GG) return;
  if (g == GG){ gptr[GG]=NN; return; }
  int lo=0, hi=NN;
  while(lo<hi){ int mid=(lo+hi)>>1; if(batch[mid]<g) lo=mid+1; else hi=mid; }
  gptr[g]=lo;
}

__global__ void k_deg(const int* dst, int* deg){
  int e = blockIdx.x*256+threadIdx.x;
  if(e<EE) atomicAdd(&deg[dst[e]], 1);
}

// hierarchical scan: part sums -> top exclusive scan -> apply
__global__ __launch_bounds__(256) void k_scan_part(const int* deg, int* part){
  __shared__ int red[256];
  int b=blockIdx.x, t=threadIdx.x;
  red[t] = deg[b*256+t];
  __syncthreads();
  for(int off=128; off>0; off>>=1){
    if(t<off) red[t]+=red[t+off];
    __syncthreads();
  }
  if(t==0) part[b]=red[0];
}

__global__ __launch_bounds__(512) void k_scan_top(int* part){  // 512 -> exclusive, in place
  __shared__ int s[512];
  int t=threadIdx.x;
  s[t]=part[t];
  __syncthreads();
  for(int off=1; off<512; off<<=1){
    int v=s[t];
    int add=(t>=off)?s[t-off]:0;
    __syncthreads();
    s[t]=v+add;
    __syncthreads();
  }
  part[t] = (t==0)?0:s[t-1];
}

__global__ __launch_bounds__(256) void k_scan_apply(const int* deg, const int* part, int* rowptr){
  __shared__ int s[256];
  int b=blockIdx.x, t=threadIdx.x;
  int v0=deg[b*256+t];
  s[t]=v0;
  __syncthreads();
  for(int off=1; off<256; off<<=1){
    int v=s[t];
    int add=(t>=off)?s[t-off]:0;
    __syncthreads();
    s[t]=v+add;
    __syncthreads();
  }
  rowptr[b*256+t] = part[b] + s[t]-v0;          // exclusive
  if(b==511 && t==255) rowptr[NN] = part[b] + s[t];
}

// fill CSR-ordered edge streams: srcord[idx], eaord[idx][6]
__global__ void k_fill(const int* dst, const int* src, const float* ea,
                       const int* rowptr, int* cursor, int* srcord, float* eaord){
  int e = blockIdx.x*256+threadIdx.x;
  if(e>=EE) return;
  int d = dst[e];
  int pos = atomicAdd(&cursor[d], 1);
  int idx = rowptr[d]+pos;
  srcord[idx] = src[e];
  #pragma unroll
  for(int q=0;q<6;q++) eaord[(size_t)idx*6+q] = ea[(size_t)e*6+q];
}

// ---- h0 = relu(x @ lin1W.T + b) -------------------------------------------
__global__ __launch_bounds__(256) void k_lin1_s(const float* x, const float* W, const float* b, float* h){
  __shared__ float sW[2048];
  __shared__ float sb[64];
  int t=threadIdx.x;
  for(int i=t;i<2048;i+=256) sW[i]=W[i];
  if(t<64) sb[t]=b[t];
  __syncthreads();
  int n = blockIdx.x*4 + (t>>6);
  int j = t&63;
  float acc = sb[j];
  for(int k=0;k<32;k++) acc += x[n*32+k]*sW[j*32+k];
  h[n*64+j] = fmaxf(acc, 0.0f);
}

// ---- k_msg: g12[N][128] = h @ [prW_dst | prW_src].T -> fp16 ---------------
__global__ __launch_bounds__(256) void k_msg(const float* h, const float* preW, _Float16* g12){
  __shared__ float sA[64][65];
  __shared__ float sB[64][65];
  int t=threadIdx.x;
  int rb = blockIdx.x*64;
  int coff = blockIdx.y ? 64 : 0;
  for(int q=0;q<16;q++){
    int idx = t*16+q;
    int a = idx>>6, bb = idx&63;
    sA[a][bb] = h[(rb+a)*64 + bb];
    sB[bb][a] = preW[a*192 + coff + bb];
  }
  __syncthreads();
  int r0=(t>>4)*4, c0=(t&15)*4;
  float acc[4][4] = {};
  for(int k=0;k<64;k++){
    float av[4], bv[4];
    #pragma unroll
    for(int i=0;i<4;i++) av[i]=sA[r0+i][k];
    #pragma unroll
    for(int jj=0;jj<4;jj++) bv[jj]=sB[k][c0+jj];
    #pragma unroll
    for(int i=0;i<4;i++){
      #pragma unroll
      for(int jj=0;jj<4;jj++) acc[i][jj]+=av[i]*bv[jj];
    }
  }
  for(int i=0;i<4;i++)
    for(int jj=0;jj<4;jj++)
      g12[(size_t)(rb+r0+i)*128 + coff + c0+jj] = (_Float16)acc[i][jj];
}

// ---- gather: m = g12[dst][j] + g12[src][64+j] + Wf[j]·ea + bf[j] ----------
__global__ __launch_bounds__(256) void k_gather_f(const int* rowptr, const int* srcord,
      const float* eaord, const _Float16* g12, const float* preW, const float* preb,
      const float* eW, const float* eb, _Float16* agg, float* s12, float avgdl){
  __shared__ float sWf[64][6];
  __shared__ float sbf[64];
  int t=threadIdx.x;
  for(int i=t; i<384; i+=256){
    int j=i/6, d=i-j*6;
    float a=0.0f;
    for(int k=0;k<64;k++) a += preW[j*192+128+k]*eW[k*6+d];
    sWf[j][d]=a;
  }
  if(t<64){
    float a=preb[t];
    for(int k=0;k<64;k++) a += preW[t*192+128+k]*eb[k];
    sbf[t]=a;
  }
  __syncthreads();
  int w=t>>6, j=t&63;
  float wf0=sWf[j][0], wf1=sWf[j][1], wf2=sWf[j][2];
  float wf3=sWf[j][3], wf4=sWf[j][4], wf5=sWf[j][5];
  float bfj=sbf[j];
  for(int it=0; it<8; ++it){
    int n = (blockIdx.x*4+w) + it*16384;
    int lo=rowptr[n], hi=rowptr[n+1];
    float mdst = (float)g12[(size_t)n*128+j] + bfj;
    float sum=0.0f, sq=0.0f, mn=1e30f, mx=-1e30f;
    int idx=lo;
    for(; idx+1<hi; idx+=2){
      int s0 = srcord[idx], s1 = srcord[idx+1];
      float2 a0 = *(const float2*)&eaord[(size_t)idx*6];
      float2 a1 = *(const float2*)&eaord[(size_t)idx*6+2];
      float2 a2 = *(const float2*)&eaord[(size_t)idx*6+4];
      float2 b0 = *(const float2*)&eaord[(size_t)(idx+1)*6];
      float2 b1 = *(const float2*)&eaord[(size_t)(idx+1)*6+2];
      float2 b2 = *(const float2*)&eaord[(size_t)(idx+1)*6+4];
      float g0 = (float)g12[(size_t)s0*128+64+j];
      float g1 = (float)g12[(size_t)s1*128+64+j];
      float m0 = mdst + g0 + a0.x*wf0 + a0.y*wf1 + a1.x*wf2 + a1.y*wf3 + a2.x*wf4 + a2.y*wf5;
      float m1 = mdst + g1 + b0.x*wf0 + b0.y*wf1 + b1.x*wf2 + b1.y*wf3 + b2.x*wf4 + b2.y*wf5;
      sum += m0; sq += m0*m0; mn = fminf(mn,m0); mx = fmaxf(mx,m0);
      sum += m1; sq += m1*m1; mn = fminf(mn,m1); mx = fmaxf(mx,m1);
    }
    if(idx<hi){
      int s0 = srcord[idx];
      float2 a0 = *(const float2*)&eaord[(size_t)idx*6];
      float2 a1 = *(const float2*)&eaord[(size_t)idx*6+2];
      float2 a2 = *(const float2*)&eaord[(size_t)idx*6+4];
      float g0 = (float)g12[(size_t)s0*128+64+j];
      float m0 = mdst + g0 + a0.x*wf0 + a0.y*wf1 + a1.x*wf2 + a1.y*wf3 + a2.x*wf4 + a2.y*wf5;
      sum += m0; sq += m0*m0; mn = fminf(mn,m0); mx = fmaxf(mx,m0);
    }
    int c = hi-lo;
    float cm = fmaxf((float)c, 1.0f);
    float mean = sum/cm;
    float sd = sqrtf(fmaxf(sq/cm - mean*mean, 0.0f)+1e-5f);
    bool has = c>0;
    size_t base = (size_t)n*256;
    agg[base+j]     = (_Float16)mean;
    agg[base+64+j]  = (_Float16)(has?mn:0.0f);
    agg[base+128+j] = (_Float16)(has?mx:0.0f);
    agg[base+192+j] = (_Float16)sd;
    if(j==0){ float ld=logf(cm+1.0f); s12[n*2]=ld/avgdl; s12[n*2+1]=avgdl/ld; }
  }
}

// ---- k_tower_mfma: fused post_nn + scaler-combine + clin via fp16 MFMA ----
__global__ __launch_bounds__(256) void k_tower_mfma(const float* h, const _Float16* agg, const float* s12,
        const float* poW, const float* pob, const float* clW, const float* clb, float* y2){
  __shared__ _Float16 sAh[64][72];   // A' k-tile (fp16), later y1
  __shared__ _Float16 sBh[64][72];   // postW k-tile (fp16), later clinW
  __shared__ float sS[128];
  int t = threadIdx.x;
  int rb = blockIdx.x*64;
  int w = t>>6, l = t&63;
  int k = t&63, rB = t>>6;
  if (t < 128) sS[t] = s12[(size_t)(rb+(t>>1))*2 + (t&1)];
  f32x4 acc[4] = {};
  for (int kt=0; kt<13; ++kt){
    __syncthreads();
    #pragma unroll
    for (int rr=0; rr<16; ++rr){
      int r = rB + rr*4;
      _Float16 v;
      if (kt==0)      v = (_Float16)h[(size_t)(rb+r)*64 + k];
      else if (kt<5)  v = agg[(size_t)(rb+r)*256 + (kt-1)*64 + k];
      else if (kt<9)  v = (_Float16)(sS[r*2]   * (float)agg[(size_t)(rb+r)*256 + (kt-5)*64 + k]);
      else            v = (_Float16)(sS[r*2+1] * (float)agg[(size_t)(rb+r)*256 + (kt-9)*64 + k]);
      sAh[r][k] = v;
      sBh[r][k] = (_Float16)poW[(size_t)r*832 + kt*64 + k];
    }
    __syncthreads();
    #pragma unroll
    for (int kk=0; kk<2; ++kk){
      half8 a = *(const half8*)&sAh[w*16 + (l&15)][kk*32 + (l>>4)*8];
      #pragma unroll
      for (int n16=0; n16<4; ++n16){
        half8 b = *(const half8*)&sBh[n16*16 + (l&15)][kk*32 + (l>>4)*8];
        acc[n16] = __builtin_amdgcn_mfma_f32_16x16x32_f16(a, b, acc[n16], 0, 0, 0);
      }
    }
  }
  __syncthreads();
  #pragma unroll
  for (int n16=0; n16<4; ++n16){
    #pragma unroll
    for (int reg=0; reg<4; ++reg){
      int row = w*16 + (l>>4)*4 + reg;
      int col = n16*16 + (l&15);
      sAh[row][col] = (_Float16)(acc[n16][reg] + pob[col]);
    }
  }
  #pragma unroll
  for (int rr=0; rr<16; ++rr){
    int c = rB + rr*4;
    sBh[c][k] = (_Float16)clW[(size_t)c*64 + k];
  }
  __syncthreads();
  f32x4 cacc[4] = {};
  #pragma unroll
  for (int kk=0; kk<2; ++kk){
    half8 a = *(const half8*)&sAh[w*16 + (l&15)][kk*32 + (l>>4)*8];
    #pragma unroll
    for (int n16=0; n16<4; ++n16){
      half8 b = *(const half8*)&sBh[n16*16 + (l&15)][kk*32 + (l>>4)*8];
      cacc[n16] = __builtin_amdgcn_mfma_f32_16x16x32_f16(a, b, cacc[n16], 0, 0, 0);
    }
  }
  #pragma unroll
  for (int n16=0; n16<4; ++n16){
    #pragma unroll
    for (int reg=0; reg<4; ++reg){
      int row = w*16 + (l>>4)*4 + reg;
      int col = n16*16 + (l&15);
      y2[(size_t)(rb+row)*64 + col] = cacc[n16][reg] + clb[col];
    }
  }
}

// ---- BN: partials (double, no atomics) -> finalize -> apply + relu --------
__global__ __launch_bounds__(256) void k_bnpart(const float* y, double* part){
  __shared__ double sS[256], sQ[256];
  int t=threadIdx.x;
  int c=t&63, q=t>>6;
  int b=blockIdx.x;
  double s=0.0, s2=0.0;
  for(int i=0;i<64;i++){
    int n = b*256 + q + i*4;
    double v = (double)y[n*64+c];
    s += v; s2 += v*v;
  }
  sS[t]=s; sQ[t]=s2;
  __syncthreads();
  if(t<64){
    double S=sS[t]+sS[t+64]+sS[t+128]+sS[t+192];
    double Q=sQ[t]+sQ[t+64]+sQ[t+128]+sQ[t+192];
    part[b*128+t]=S; part[b*128+64+t]=Q;
  }
}

__global__ void k_bnfin(const double* part, const float* g, const float* bb, float* sc, float* sh){
  int c = threadIdx.x;
  if(c>=64) return;
  double S=0.0, Q=0.0;
  for(int b=0;b<512;b++){ S+=part[b*128+c]; Q+=part[b*128+64+c]; }
  double mean = S/(double)NN;
  double var  = Q/(double)NN - mean*mean;
  float scale = g[c] * (float)(1.0/sqrt(var+1e-5));
  sc[c]=scale;
  sh[c]=bb[c] - (float)mean*scale;
}

__global__ void k_bnapply2(const float* y, float* h, const float* sc, const float* sh){
  int idx = blockIdx.x*256+threadIdx.x;
  const float4* y4=(const float4*)y;
  float4* h4=(float4*)h;
  for(int i=idx; i<NN*16; i+=256*4096){
    int c4=(i&15)*4;
    float4 v=y4[i];
    float r[4]={v.x,v.y,v.z,v.w};
    #pragma unroll
    for(int qq=0;qq<4;qq++){ int c=c4+qq; r[qq]=fmaxf(r[qq]*sc[c]+sh[c], 0.0f); }
    h4[i]=make_float4(r[0],r[1],r[2],r[3]);
  }
}

// ---- set2set (literal LSTM: raw Wih/Whh) ----------------------------------
__global__ __launch_bounds__(256) void k_lstm_lit(float* A, float* cs,
      const float* Wih, const float* Whh, const float* bih, const float* bhh){
  __shared__ float sA[128]; __shared__ float sg[256];
  int g=blockIdx.x, t=threadIdx.x;
  if(t<128) sA[t]=A[g*128+t];
  __syncthreads();
  float a = bih[t] + bhh[t];
  for(int k=0;k<128;k++) a += Wih[t*128+k]*sA[k];
  for(int k=0;k<64;k++)  a += Whh[t*64+k]*sA[k];
  sg[t]=a;
  __syncthreads();
  if(t<64){
    float ig=sg[t], fg=sg[64+t], gg=sg[128+t], og=sg[192+t];
    float c = sigmoidf_(fg)*cs[g*64+t] + sigmoidf_(ig)*tanhf(gg);
    float hv = sigmoidf_(og)*tanhf(c);
    cs[g*64+t]=c;
    A[g*128+t]=hv;
  }
}

__global__ __launch_bounds__(256) void k_edot(const float* h, const float* A, const int* batch, float* e){
  int t=threadIdx.x, w=t>>6, j=t&63;
  for(int it=0;it<16;++it){
    int n=(blockIdx.x*4+w)+it*8192;
    int g=batch[n];
    float v=h[n*64+j]*A[g*128+j];
    #pragma unroll
    for(int m=32;m;m>>=1) v+=__shfl_xor(v,m,64);
    if(j==0) e[n]=v;
  }
}

__global__ __launch_bounds__(64) void k_attn(const float* h, const float* e, const int* gptr, float* A){
  int g=blockIdx.x, j=threadIdx.x;
  int lo=gptr[g], hi=gptr[g+1];
  if(lo>=hi){ A[g*128+64+j]=0.0f; return; }
  float mx=-1e30f;
  for(int n=lo+j;n<hi;n+=64) mx=fmaxf(mx,e[n]);
  #pragma unroll
  for(int m=32;m;m>>=1) mx=fmaxf(mx,__shfl_xor(mx,m,64));
  float s=0.0f;
  for(int n=lo+j;n<hi;n+=64) s+=expf(e[n]-mx);
  #pragma unroll
  for(int m=32;m;m>>=1) s+=__shfl_xor(s,m,64);
  float inv=1.0f/(s+1e-16f);
  float r=0.0f;
  for(int n=lo;n<hi;++n){
    float a=expf(e[n]-mx)*inv;
    r+=a*h[n*64+j];
  }
  A[g*128+64+j]=r;
}

__global__ __launch_bounds__(64) void k_mlp(const float* A, const float* tt, const float* pp,
     const float* W1,const float* b1,const float* W2,const float* b2,const float* W3,const float* b3,
     float* out){
  __shared__ float si[130]; __shared__ float o1[64]; __shared__ float o2[32];
  int g=blockIdx.x, t=threadIdx.x;
  si[t]=A[g*128+t]; si[64+t]=A[g*128+64+t];
  if(t==0){ si[128]=tt[g]; si[129]=pp[g]; }
  __syncthreads();
  float a=b1[t];
  for(int k=0;k<130;k++) a+=W1[t*130+k]*si[k];
  o1[t]=fmaxf(a,0.0f);
  __syncthreads();
  if(t<32){
    float a2=b2[t];
    #pragma unroll 4
    for(int k=0;k<64;k++) a2+=W2[t*64+k]*o1[k];
    o2[t]=fmaxf(a2,0.0f);
  }
  __syncthreads();
  float v = (t<32)? o2[t]*W3[t] : 0.0f;
  #pragma unroll
  for(int m=32;m;m>>=1) v+=__shfl_xor(v,m,64);
  if(t==0) out[g]=v+b3[0];
}

// ---- host -----------------------------------------------------------------
extern "C" void kernel_launch(void* const* d_in, const int* in_sizes, int n_in,
                              void* d_out, int out_size, void* d_ws, size_t ws_size,
                              hipStream_t stream) {
  static const int want[28] = {4194304,3145728,4096,4096,2048,64,1152,192,36864,192,
                               159744,192,12288,192,192,192,32768,16384,256,256,
                               8320,64,2048,32,32,1,1048576,131072};
  if (n_in != 28 || out_size != GG) return;
  for (int i=0;i<28;i++) if (in_sizes[i] != want[i]) return;

  const float* x     = (const float*)d_in[0];
  const float* ea    = (const float*)d_in[1];
  const float* tt    = (const float*)d_in[2];
  const float* pp    = (const float*)d_in[3];
  const float* lin1W = (const float*)d_in[4];
  const float* lin1b = (const float*)d_in[5];
  const float* edgeW = (const float*)d_in[6];
  const float* edgeb = (const float*)d_in[7];
  const float* preW  = (const float*)d_in[8];
  const float* preb  = (const float*)d_in[9];
  const float* postW = (const float*)d_in[10];
  const float* postb = (const float*)d_in[11];
  const float* clinW = (const float*)d_in[12];
  const float* clinb = (const float*)d_in[13];
  const float* bng   = (const float*)d_in[14];
  const float* bnb   = (const float*)d_in[15];
  const float* Wih   = (const float*)d_in[16];
  const float* Whh   = (const float*)d_in[17];
  const float* bih   = (const float*)d_in[18];
  const float* bhh   = (const float*)d_in[19];
  const float* W1    = (const float*)d_in[20];
  const float* b1    = (const float*)d_in[21];
  const float* W2    = (const float*)d_in[22];
  const float* b2    = (const float*)d_in[23];
  const float* W3    = (const float*)d_in[24];
  const float* b3    = (const float*)d_in[25];
  const int*   eidx  = (const int*)d_in[26];
  const int*   batch = (const int*)d_in[27];
  const int* esrc = eidx;
  const int* edst = eidx + EE;

  char* w = (char*)d_ws;
  auto alloc = [&](size_t bytes)->char*{ char* p=w; w += ((bytes+255)/256)*256; return p; };
  _Float16* agg  = (_Float16*)alloc((size_t)NN*256*2);  // 64MiB fp16
  _Float16* g12  = (_Float16*)alloc((size_t)NN*128*2);  // 32MiB fp16 (y2 fp32 aliases)
  float* hbuf    = (float*)alloc((size_t)NN*64*4);      // 32MiB
  int*   deg    = (int*)alloc((size_t)NN*4);
  int*   cursor = (int*)alloc((size_t)NN*4);
  int*   rowptr = (int*)alloc((size_t)(NN+1)*4);
  int*   spart  = (int*)alloc(512*4);
  int*   srcord = (int*)alloc((size_t)EE*4);
  float* eaord  = (float*)alloc((size_t)EE*6*4);        // 12.6MB CSR-ordered edge attrs
  float* s12   = (float*)alloc((size_t)NN*2*4);
  double* part = (double*)alloc((size_t)512*128*8);
  float* bnsc  = (float*)alloc(256);
  float* bnsh  = (float*)alloc(256);
  int*   gptr  = (int*)alloc((GG+1)*4);
  size_t need = (size_t)(w - (char*)d_ws);
  if (need > ws_size) return;
  // y2 (fp32, 32MiB) aliases the g12 region (g12 dead after k_gather_f)
  float* y2   = (float*)g12;
  float* A    = (float*)g12;               // set2set scratch (after layers done)
  float* cs   = (float*)g12 + (size_t)GG*128;
  float* escr = (float*)g12 + (size_t)GG*192;

  double num = 13107.0*log(2.0)+26214.0*log(3.0)+65536.0*log(4.0)+26215.0*log(5.0);
  float avgdl = (float)(num/131072.0);

  hipMemsetAsync(deg, 0, (size_t)NN*4, stream);
  hipMemsetAsync(cursor, 0, (size_t)NN*4, stream);
  hipLaunchKernelGGL(k_deg, dim3(2048), dim3(256), 0, stream, edst, deg);
  hipLaunchKernelGGL(k_scan_part, dim3(512), dim3(256), 0, stream, deg, spart);
  hipLaunchKernelGGL(k_scan_top, dim3(1), dim3(512), 0, stream, spart);
  hipLaunchKernelGGL(k_scan_apply, dim3(512), dim3(256), 0, stream, deg, spart, rowptr);
  hipLaunchKernelGGL(k_fill, dim3(2048), dim3(256), 0, stream, edst, esrc, ea, rowptr, cursor, srcord, eaord);

  hipLaunchKernelGGL(k_gptr, dim3(17), dim3(256), 0, stream, batch, gptr);
  hipLaunchKernelGGL(k_lin1_s, dim3(32768), dim3(256), 0, stream, x, lin1W, lin1b, hbuf);

  for (int i = 0; i < 3; ++i){
    hipLaunchKernelGGL(k_msg, dim3(2048,2), dim3(256), 0, stream, hbuf,
        preW + (size_t)i*64*192, g12);
    hipLaunchKernelGGL(k_gather_f, dim3(4096), dim3(256), 0, stream, rowptr, srcord, eaord, g12,
        preW + (size_t)i*64*192, preb + i*64, edgeW + (size_t)i*384, edgeb + i*64, agg, s12, avgdl);
    hipLaunchKernelGGL(k_tower_mfma, dim3(2048), dim3(256), 0, stream, hbuf, agg, s12,
        postW + (size_t)i*64*832, postb + i*64, clinW + (size_t)i*4096, clinb + i*64, y2);
    hipLaunchKernelGGL(k_bnpart, dim3(512), dim3(256), 0, stream, y2, part);
    hipLaunchKernelGGL(k_bnfin, dim3(1), dim3(64), 0, stream, part, bng + i*64, bnb + i*64, bnsc, bnsh);
    hipLaunchKernelGGL(k_bnapply2, dim3(4096), dim3(256), 0, stream, y2, hbuf, bnsc, bnsh);
  }

  hipMemsetAsync(A, 0, (size_t)GG*128*4, stream);
  hipMemsetAsync(cs, 0, (size_t)GG*64*4, stream);
  for (int s = 0; s < 3; ++s){
    hipLaunchKernelGGL(k_lstm_lit, dim3(GG), dim3(256), 0, stream, A, cs, Wih, Whh, bih, bhh);
    hipLaunchKernelGGL(k_edot, dim3(2048), dim3(256), 0, stream, hbuf, A, batch, escr);
    hipLaunchKernelGGL(k_attn, dim3(GG), dim3(64), 0, stream, hbuf, escr, gptr, A);
  }
  hipLaunchKernelGGL(k_mlp, dim3(GG), dim3(64), 0, stream, A, tt, pp, W1, b1, W2, b2, W3, b3, (float*)d_out);
}

// Round 14
// 1378.941 us; speedup vs baseline: 3.3014x; 1.0759x over previous
//
#include <hip/hip_runtime.h>
#include <hip/hip_bf16.h>
#include <math.h>

#define NN 131072
#define EE 524288
#define GG 4096

typedef __attribute__((ext_vector_type(8))) _Float16 half8;
typedef __attribute__((ext_vector_type(4))) _Float16 half4;
typedef __attribute__((ext_vector_type(4))) float f32x4;

__device__ __forceinline__ float sigmoidf_(float x){ return 1.0f/(1.0f+expf(-x)); }

// ---- grouping / CSR (integer atomics only) --------------------------------
__global__ void k_gptr(const int* batch, int* gptr){
  int g = blockIdx.x*256+threadIdx.x;
  if (g > GG) return;
  if (g == GG){ gptr[GG]=NN; return; }
  int lo=0, hi=NN;
  while(lo<hi){ int mid=(lo+hi)>>1; if(batch[mid]<g) lo=mid+1; else hi=mid; }
  gptr[g]=lo;
}

__global__ void k_deg(const int* dst, int* deg){
  int e = blockIdx.x*256+threadIdx.x;
  if(e<EE) atomicAdd(&deg[dst[e]], 1);
}

// hierarchical scan: part sums -> top exclusive scan -> apply
__global__ __launch_bounds__(256) void k_scan_part(const int* deg, int* part){
  __shared__ int red[256];
  int b=blockIdx.x, t=threadIdx.x;
  red[t] = deg[b*256+t];
  __syncthreads();
  for(int off=128; off>0; off>>=1){
    if(t<off) red[t]+=red[t+off];
    __syncthreads();
  }
  if(t==0) part[b]=red[0];
}

__global__ __launch_bounds__(512) void k_scan_top(int* part){
  __shared__ int s[512];
  int t=threadIdx.x;
  s[t]=part[t];
  __syncthreads();
  for(int off=1; off<512; off<<=1){
    int v=s[t];
    int add=(t>=off)?s[t-off]:0;
    __syncthreads();
    s[t]=v+add;
    __syncthreads();
  }
  part[t] = (t==0)?0:s[t-1];
}

__global__ __launch_bounds__(256) void k_scan_apply(const int* deg, const int* part, int* rowptr){
  __shared__ int s[256];
  int b=blockIdx.x, t=threadIdx.x;
  int v0=deg[b*256+t];
  s[t]=v0;
  __syncthreads();
  for(int off=1; off<256; off<<=1){
    int v=s[t];
    int add=(t>=off)?s[t-off]:0;
    __syncthreads();
    s[t]=v+add;
    __syncthreads();
  }
  rowptr[b*256+t] = part[b] + s[t]-v0;
  if(b==511 && t==255) rowptr[NN] = part[b] + s[t];
}

// fill CSR-ordered edge streams: srcord[idx], eaord[idx][6]
__global__ void k_fill(const int* dst, const int* src, const float* ea,
                       const int* rowptr, int* cursor, int* srcord, float* eaord){
  int e = blockIdx.x*256+threadIdx.x;
  if(e>=EE) return;
  int d = dst[e];
  int pos = atomicAdd(&cursor[d], 1);
  int idx = rowptr[d]+pos;
  srcord[idx] = src[e];
  #pragma unroll
  for(int q=0;q<6;q++) eaord[(size_t)idx*6+q] = ea[(size_t)e*6+q];
}

// ---- y0 = x @ lin1W.T + b (pre-activation; relu applied in k_bnmsg) -------
__global__ __launch_bounds__(256) void k_lin1_s(const float* x, const float* W, const float* b, float* y0){
  __shared__ float sW[2048];
  __shared__ float sb[64];
  int t=threadIdx.x;
  for(int i=t;i<2048;i+=256) sW[i]=W[i];
  if(t<64) sb[t]=b[t];
  __syncthreads();
  int n = blockIdx.x*4 + (t>>6);
  int j = t&63;
  float acc = sb[j];
  for(int k=0;k<32;k++) acc += x[n*32+k]*sW[j*32+k];
  y0[(size_t)n*64+j] = acc;
}

// ---- k_bnmsg: h = relu(y*sc+sh) [fp16, stored]; g12 = h @ [Wd|Ws].T fp16 --
// y aliases g12 byte-range block-diagonally: each block reads exactly the
// 64-row tile it later overwrites; y staged to LDS + barrier before writes.
__global__ __launch_bounds__(256) void k_bnmsg(const float* y, const float* sc, const float* sh,
      const float* preW, _Float16* h16, _Float16* g12){
  __shared__ _Float16 sAh[64][72];
  __shared__ _Float16 sB0[64][72];   // sB0[c][k] = preW[c*192+k]     (dst proj)
  __shared__ _Float16 sB1[64][72];   // sB1[c][k] = preW[c*192+64+k]  (src proj)
  int t=threadIdx.x;
  int rb = blockIdx.x*64;
  int k = t&63, rB = t>>6;
  float scv=1.0f, shv=0.0f;
  if(sc){ scv=sc[k]; shv=sh[k]; }
  #pragma unroll
  for(int rr=0; rr<16; ++rr){
    int r = rB + rr*4;
    float v = y[(size_t)(rb+r)*64 + k];
    v = fmaxf(v*scv + shv, 0.0f);
    _Float16 hv = (_Float16)v;
    sAh[r][k] = hv;
    h16[(size_t)(rb+r)*64 + k] = hv;
    sB0[r][k] = (_Float16)preW[(size_t)r*192 + k];
    sB1[r][k] = (_Float16)preW[(size_t)r*192 + 64 + k];
  }
  __syncthreads();
  int w=t>>6, l=t&63;
  f32x4 acc0[4]={}, acc1[4]={};
  #pragma unroll
  for(int kk=0; kk<2; ++kk){
    half8 a = *(const half8*)&sAh[w*16+(l&15)][kk*32+(l>>4)*8];
    #pragma unroll
    for(int n16=0;n16<4;++n16){
      half8 b0 = *(const half8*)&sB0[n16*16+(l&15)][kk*32+(l>>4)*8];
      half8 b1 = *(const half8*)&sB1[n16*16+(l&15)][kk*32+(l>>4)*8];
      acc0[n16] = __builtin_amdgcn_mfma_f32_16x16x32_f16(a,b0,acc0[n16],0,0,0);
      acc1[n16] = __builtin_amdgcn_mfma_f32_16x16x32_f16(a,b1,acc1[n16],0,0,0);
    }
  }
  #pragma unroll
  for(int n16=0;n16<4;++n16){
    #pragma unroll
    for(int reg=0; reg<4; ++reg){
      int row = w*16+(l>>4)*4+reg;
      int col = n16*16+(l&15);
      g12[(size_t)(rb+row)*128 + col]      = (_Float16)acc0[n16][reg];
      g12[(size_t)(rb+row)*128 + 64 + col] = (_Float16)acc1[n16][reg];
    }
  }
}

// ---- gather: m = g12[dst][j] + g12[src][64+j] + Wf[j]·ea + bf[j] ----------
__global__ __launch_bounds__(256) void k_gather_f(const int* rowptr, const int* srcord,
      const float* eaord, const _Float16* g12, const float* preW, const float* preb,
      const float* eW, const float* eb, _Float16* agg, float* s12, float avgdl){
  __shared__ float sWf[64][6];
  __shared__ float sbf[64];
  int t=threadIdx.x;
  for(int i=t; i<384; i+=256){
    int j=i/6, d=i-j*6;
    float a=0.0f;
    for(int k=0;k<64;k++) a += preW[j*192+128+k]*eW[k*6+d];
    sWf[j][d]=a;
  }
  if(t<64){
    float a=preb[t];
    for(int k=0;k<64;k++) a += preW[t*192+128+k]*eb[k];
    sbf[t]=a;
  }
  __syncthreads();
  int w=t>>6, j=t&63;
  float wf0=sWf[j][0], wf1=sWf[j][1], wf2=sWf[j][2];
  float wf3=sWf[j][3], wf4=sWf[j][4], wf5=sWf[j][5];
  float bfj=sbf[j];
  for(int it=0; it<8; ++it){
    int n = (blockIdx.x*4+w) + it*16384;
    int lo=rowptr[n], hi=rowptr[n+1];
    float mdst = (float)g12[(size_t)n*128+j] + bfj;
    float sum=0.0f, sq=0.0f, mn=1e30f, mx=-1e30f;
    int idx=lo;
    for(; idx+1<hi; idx+=2){
      int s0 = srcord[idx], s1 = srcord[idx+1];
      float2 a0 = *(const float2*)&eaord[(size_t)idx*6];
      float2 a1 = *(const float2*)&eaord[(size_t)idx*6+2];
      float2 a2 = *(const float2*)&eaord[(size_t)idx*6+4];
      float2 b0 = *(const float2*)&eaord[(size_t)(idx+1)*6];
      float2 b1 = *(const float2*)&eaord[(size_t)(idx+1)*6+2];
      float2 b2 = *(const float2*)&eaord[(size_t)(idx+1)*6+4];
      float g0 = (float)g12[(size_t)s0*128+64+j];
      float g1 = (float)g12[(size_t)s1*128+64+j];
      float m0 = mdst + g0 + a0.x*wf0 + a0.y*wf1 + a1.x*wf2 + a1.y*wf3 + a2.x*wf4 + a2.y*wf5;
      float m1 = mdst + g1 + b0.x*wf0 + b0.y*wf1 + b1.x*wf2 + b1.y*wf3 + b2.x*wf4 + b2.y*wf5;
      sum += m0; sq += m0*m0; mn = fminf(mn,m0); mx = fmaxf(mx,m0);
      sum += m1; sq += m1*m1; mn = fminf(mn,m1); mx = fmaxf(mx,m1);
    }
    if(idx<hi){
      int s0 = srcord[idx];
      float2 a0 = *(const float2*)&eaord[(size_t)idx*6];
      float2 a1 = *(const float2*)&eaord[(size_t)idx*6+2];
      float2 a2 = *(const float2*)&eaord[(size_t)idx*6+4];
      float g0 = (float)g12[(size_t)s0*128+64+j];
      float m0 = mdst + g0 + a0.x*wf0 + a0.y*wf1 + a1.x*wf2 + a1.y*wf3 + a2.x*wf4 + a2.y*wf5;
      sum += m0; sq += m0*m0; mn = fminf(mn,m0); mx = fmaxf(mx,m0);
    }
    int c = hi-lo;
    float cm = fmaxf((float)c, 1.0f);
    float mean = sum/cm;
    float sd = sqrtf(fmaxf(sq/cm - mean*mean, 0.0f)+1e-5f);
    bool has = c>0;
    size_t base = (size_t)n*256;
    agg[base+j]     = (_Float16)mean;
    agg[base+64+j]  = (_Float16)(has?mn:0.0f);
    agg[base+128+j] = (_Float16)(has?mx:0.0f);
    agg[base+192+j] = (_Float16)sd;
    if(j==0){ float ld=logf(cm+1.0f); s12[n*2]=ld/avgdl; s12[n*2+1]=avgdl/ld; }
  }
}

// ---- k_tower_mfma: fused post_nn + scaler-combine + clin via fp16 MFMA ----
__global__ __launch_bounds__(256) void k_tower_mfma(const _Float16* h16, const _Float16* agg, const float* s12,
        const float* poW, const float* pob, const float* clW, const float* clb, float* y2){
  __shared__ _Float16 sAh[64][72];   // A' k-tile (fp16), later y1
  __shared__ _Float16 sBh[64][72];   // postW k-tile (fp16), later clinW
  __shared__ float sS[128];
  int t = threadIdx.x;
  int rb = blockIdx.x*64;
  int w = t>>6, l = t&63;
  int k = t&63, rB = t>>6;
  if (t < 128) sS[t] = s12[(size_t)(rb+(t>>1))*2 + (t&1)];
  f32x4 acc[4] = {};
  for (int kt=0; kt<13; ++kt){
    __syncthreads();
    #pragma unroll
    for (int rr=0; rr<16; ++rr){
      int r = rB + rr*4;
      _Float16 v;
      if (kt==0)      v = h16[(size_t)(rb+r)*64 + k];
      else if (kt<5)  v = agg[(size_t)(rb+r)*256 + (kt-1)*64 + k];
      else if (kt<9)  v = (_Float16)(sS[r*2]   * (float)agg[(size_t)(rb+r)*256 + (kt-5)*64 + k]);
      else            v = (_Float16)(sS[r*2+1] * (float)agg[(size_t)(rb+r)*256 + (kt-9)*64 + k]);
      sAh[r][k] = v;
      sBh[r][k] = (_Float16)poW[(size_t)r*832 + kt*64 + k];
    }
    __syncthreads();
    #pragma unroll
    for (int kk=0; kk<2; ++kk){
      half8 a = *(const half8*)&sAh[w*16 + (l&15)][kk*32 + (l>>4)*8];
      #pragma unroll
      for (int n16=0; n16<4; ++n16){
        half8 b = *(const half8*)&sBh[n16*16 + (l&15)][kk*32 + (l>>4)*8];
        acc[n16] = __builtin_amdgcn_mfma_f32_16x16x32_f16(a, b, acc[n16], 0, 0, 0);
      }
    }
  }
  __syncthreads();
  #pragma unroll
  for (int n16=0; n16<4; ++n16){
    #pragma unroll
    for (int reg=0; reg<4; ++reg){
      int row = w*16 + (l>>4)*4 + reg;
      int col = n16*16 + (l&15);
      sAh[row][col] = (_Float16)(acc[n16][reg] + pob[col]);
    }
  }
  #pragma unroll
  for (int rr=0; rr<16; ++rr){
    int c = rB + rr*4;
    sBh[c][k] = (_Float16)clW[(size_t)c*64 + k];
  }
  __syncthreads();
  f32x4 cacc[4] = {};
  #pragma unroll
  for (int kk=0; kk<2; ++kk){
    half8 a = *(const half8*)&sAh[w*16 + (l&15)][kk*32 + (l>>4)*8];
    #pragma unroll
    for (int n16=0; n16<4; ++n16){
      half8 b = *(const half8*)&sBh[n16*16 + (l&15)][kk*32 + (l>>4)*8];
      cacc[n16] = __builtin_amdgcn_mfma_f32_16x16x32_f16(a, b, cacc[n16], 0, 0, 0);
    }
  }
  #pragma unroll
  for (int n16=0; n16<4; ++n16){
    #pragma unroll
    for (int reg=0; reg<4; ++reg){
      int row = w*16 + (l>>4)*4 + reg;
      int col = n16*16 + (l&15);
      y2[(size_t)(rb+row)*64 + col] = cacc[n16][reg] + clb[col];
    }
  }
}

// ---- BN: partials (double, no atomics) -> finalize ------------------------
__global__ __launch_bounds__(256) void k_bnpart(const float* y, double* part){
  __shared__ double sS[256], sQ[256];
  int t=threadIdx.x;
  int c=t&63, q=t>>6;
  int b=blockIdx.x;
  double s=0.0, s2=0.0;
  for(int i=0;i<64;i++){
    int n = b*256 + q + i*4;
    double v = (double)y[(size_t)n*64+c];
    s += v; s2 += v*v;
  }
  sS[t]=s; sQ[t]=s2;
  __syncthreads();
  if(t<64){
    double S=sS[t]+sS[t+64]+sS[t+128]+sS[t+192];
    double Q=sQ[t]+sQ[t+64]+sQ[t+128]+sQ[t+192];
    part[b*128+t]=S; part[b*128+64+t]=Q;
  }
}

__global__ void k_bnfin(const double* part, const float* g, const float* bb, float* sc, float* sh){
  int c = threadIdx.x;
  if(c>=64) return;
  double S=0.0, Q=0.0;
  for(int b=0;b<512;b++){ S+=part[b*128+c]; Q+=part[b*128+64+c]; }
  double mean = S/(double)NN;
  double var  = Q/(double)NN - mean*mean;
  float scale = g[c] * (float)(1.0/sqrt(var+1e-5));
  sc[c]=scale;
  sh[c]=bb[c] - (float)mean*scale;
}

// ---- final BN apply -> h16 (for set2set) ----------------------------------
__global__ void k_bnapply16(const float* y, _Float16* h16, const float* sc, const float* sh){
  int idx = blockIdx.x*256+threadIdx.x;
  const float4* y4=(const float4*)y;
  for(int i=idx; i<NN*16; i+=256*4096){
    int c4=(i&15)*4;
    float4 v=y4[i];
    half4 r;
    r.x=(_Float16)fmaxf(v.x*sc[c4+0]+sh[c4+0],0.0f);
    r.y=(_Float16)fmaxf(v.y*sc[c4+1]+sh[c4+1],0.0f);
    r.z=(_Float16)fmaxf(v.z*sc[c4+2]+sh[c4+2],0.0f);
    r.w=(_Float16)fmaxf(v.w*sc[c4+3]+sh[c4+3],0.0f);
    *(half4*)&h16[(size_t)i*4] = r;
  }
}

// ---- set2set (literal LSTM: raw Wih/Whh) ----------------------------------
__global__ __launch_bounds__(256) void k_lstm_lit(float* A, float* cs,
      const float* Wih, const float* Whh, const float* bih, const float* bhh){
  __shared__ float sA[128]; __shared__ float sg[256];
  int g=blockIdx.x, t=threadIdx.x;
  if(t<128) sA[t]=A[g*128+t];
  __syncthreads();
  float a = bih[t] + bhh[t];
  for(int k=0;k<128;k++) a += Wih[t*128+k]*sA[k];
  for(int k=0;k<64;k++)  a += Whh[t*64+k]*sA[k];
  sg[t]=a;
  __syncthreads();
  if(t<64){
    float ig=sg[t], fg=sg[64+t], gg=sg[128+t], og=sg[192+t];
    float c = sigmoidf_(fg)*cs[g*64+t] + sigmoidf_(ig)*tanhf(gg);
    float hv = sigmoidf_(og)*tanhf(c);
    cs[g*64+t]=c;
    A[g*128+t]=hv;
  }
}

__global__ __launch_bounds__(256) void k_edot(const _Float16* h16, const float* A, const int* batch, float* e){
  int t=threadIdx.x, w=t>>6, j=t&63;
  for(int it=0;it<16;++it){
    int n=(blockIdx.x*4+w)+it*8192;
    int g=batch[n];
    float v=(float)h16[(size_t)n*64+j]*A[g*128+j];
    #pragma unroll
    for(int m=32;m;m>>=1) v+=__shfl_xor(v,m,64);
    if(j==0) e[n]=v;
  }
}

__global__ __launch_bounds__(64) void k_attn(const _Float16* h16, const float* e, const int* gptr, float* A){
  int g=blockIdx.x, j=threadIdx.x;
  int lo=gptr[g], hi=gptr[g+1];
  if(lo>=hi){ A[g*128+64+j]=0.0f; return; }
  float mx=-1e30f;
  for(int n=lo+j;n<hi;n+=64) mx=fmaxf(mx,e[n]);
  #pragma unroll
  for(int m=32;m;m>>=1) mx=fmaxf(mx,__shfl_xor(mx,m,64));
  float s=0.0f;
  for(int n=lo+j;n<hi;n+=64) s+=expf(e[n]-mx);
  #pragma unroll
  for(int m=32;m;m>>=1) s+=__shfl_xor(s,m,64);
  float inv=1.0f/(s+1e-16f);
  float r=0.0f;
  for(int n=lo;n<hi;++n){
    float a=expf(e[n]-mx)*inv;
    r+=a*(float)h16[(size_t)n*64+j];
  }
  A[g*128+64+j]=r;
}

__global__ __launch_bounds__(64) void k_mlp(const float* A, const float* tt, const float* pp,
     const float* W1,const float* b1,const float* W2,const float* b2,const float* W3,const float* b3,
     float* out){
  __shared__ float si[130]; __shared__ float o1[64]; __shared__ float o2[32];
  int g=blockIdx.x, t=threadIdx.x;
  si[t]=A[g*128+t]; si[64+t]=A[g*128+64+t];
  if(t==0){ si[128]=tt[g]; si[129]=pp[g]; }
  __syncthreads();
  float a=b1[t];
  for(int k=0;k<130;k++) a+=W1[t*130+k]*si[k];
  o1[t]=fmaxf(a,0.0f);
  __syncthreads();
  if(t<32){
    float a2=b2[t];
    #pragma unroll 4
    for(int k=0;k<64;k++) a2+=W2[t*64+k]*o1[k];
    o2[t]=fmaxf(a2,0.0f);
  }
  __syncthreads();
  float v = (t<32)? o2[t]*W3[t] : 0.0f;
  #pragma unroll
  for(int m=32;m;m>>=1) v+=__shfl_xor(v,m,64);
  if(t==0) out[g]=v+b3[0];
}

// ---- host -----------------------------------------------------------------
extern "C" void kernel_launch(void* const* d_in, const int* in_sizes, int n_in,
                              void* d_out, int out_size, void* d_ws, size_t ws_size,
                              hipStream_t stream) {
  static const int want[28] = {4194304,3145728,4096,4096,2048,64,1152,192,36864,192,
                               159744,192,12288,192,192,192,32768,16384,256,256,
                               8320,64,2048,32,32,1,1048576,131072};
  if (n_in != 28 || out_size != GG) return;
  for (int i=0;i<28;i++) if (in_sizes[i] != want[i]) return;

  const float* x     = (const float*)d_in[0];
  const float* ea    = (const float*)d_in[1];
  const float* tt    = (const float*)d_in[2];
  const float* pp    = (const float*)d_in[3];
  const float* lin1W = (const float*)d_in[4];
  const float* lin1b = (const float*)d_in[5];
  const float* edgeW = (const float*)d_in[6];
  const float* edgeb = (const float*)d_in[7];
  const float* preW  = (const float*)d_in[8];
  const float* preb  = (const float*)d_in[9];
  const float* postW = (const float*)d_in[10];
  const float* postb = (const float*)d_in[11];
  const float* clinW = (const float*)d_in[12];
  const float* clinb = (const float*)d_in[13];
  const float* bng   = (const float*)d_in[14];
  const float* bnb   = (const float*)d_in[15];
  const float* Wih   = (const float*)d_in[16];
  const float* Whh   = (const float*)d_in[17];
  const float* bih   = (const float*)d_in[18];
  const float* bhh   = (const float*)d_in[19];
  const float* W1    = (const float*)d_in[20];
  const float* b1    = (const float*)d_in[21];
  const float* W2    = (const float*)d_in[22];
  const float* b2    = (const float*)d_in[23];
  const float* W3    = (const float*)d_in[24];
  const float* b3    = (const float*)d_in[25];
  const int*   eidx  = (const int*)d_in[26];
  const int*   batch = (const int*)d_in[27];
  const int* esrc = eidx;
  const int* edst = eidx + EE;

  char* w = (char*)d_ws;
  auto alloc = [&](size_t bytes)->char*{ char* p=w; w += ((bytes+255)/256)*256; return p; };
  _Float16* agg  = (_Float16*)alloc((size_t)NN*256*2);  // 64MiB fp16
  _Float16* g12  = (_Float16*)alloc((size_t)NN*128*2);  // 32MiB fp16 (ybuf fp32 aliases)
  _Float16* h16  = (_Float16*)alloc((size_t)NN*64*2);   // 16MiB fp16
  int*   deg    = (int*)alloc((size_t)NN*4);
  int*   cursor = (int*)alloc((size_t)NN*4);
  int*   rowptr = (int*)alloc((size_t)(NN+1)*4);
  int*   spart  = (int*)alloc(512*4);
  int*   srcord = (int*)alloc((size_t)EE*4);
  float* eaord  = (float*)alloc((size_t)EE*6*4);
  float* s12   = (float*)alloc((size_t)NN*2*4);
  double* part = (double*)alloc((size_t)512*128*8);
  float* bnsc  = (float*)alloc(256);
  float* bnsh  = (float*)alloc(256);
  int*   gptr  = (int*)alloc((GG+1)*4);
  size_t need = (size_t)(w - (char*)d_ws);
  if (need > ws_size) return;
  // ybuf (fp32, 32MiB) aliases the g12 region. Per-layer timeline:
  // bnmsg reads ybuf tile -> writes g12 same bytes (block-diagonal, staged);
  // gather reads g12; tower overwrites region with y2; bnpart reads y2.
  float* ybuf = (float*)g12;
  float* A    = (float*)g12;               // set2set scratch (after layers done)
  float* cs   = (float*)g12 + (size_t)GG*128;
  float* escr = (float*)g12 + (size_t)GG*192;

  double num = 13107.0*log(2.0)+26214.0*log(3.0)+65536.0*log(4.0)+26215.0*log(5.0);
  float avgdl = (float)(num/131072.0);

  hipMemsetAsync(deg, 0, (size_t)NN*4, stream);
  hipMemsetAsync(cursor, 0, (size_t)NN*4, stream);
  hipLaunchKernelGGL(k_deg, dim3(2048), dim3(256), 0, stream, edst, deg);
  hipLaunchKernelGGL(k_scan_part, dim3(512), dim3(256), 0, stream, deg, spart);
  hipLaunchKernelGGL(k_scan_top, dim3(1), dim3(512), 0, stream, spart);
  hipLaunchKernelGGL(k_scan_apply, dim3(512), dim3(256), 0, stream, deg, spart, rowptr);
  hipLaunchKernelGGL(k_fill, dim3(2048), dim3(256), 0, stream, edst, esrc, ea, rowptr, cursor, srcord, eaord);

  hipLaunchKernelGGL(k_gptr, dim3(17), dim3(256), 0, stream, batch, gptr);
  hipLaunchKernelGGL(k_lin1_s, dim3(32768), dim3(256), 0, stream, x, lin1W, lin1b, ybuf);

  for (int i = 0; i < 3; ++i){
    const float* sc_i = (i==0)? nullptr : bnsc;
    const float* sh_i = (i==0)? nullptr : bnsh;
    hipLaunchKernelGGL(k_bnmsg, dim3(2048), dim3(256), 0, stream, ybuf, sc_i, sh_i,
        preW + (size_t)i*64*192, h16, g12);
    hipLaunchKernelGGL(k_gather_f, dim3(4096), dim3(256), 0, stream, rowptr, srcord, eaord, g12,
        preW + (size_t)i*64*192, preb + i*64, edgeW + (size_t)i*384, edgeb + i*64, agg, s12, avgdl);
    hipLaunchKernelGGL(k_tower_mfma, dim3(2048), dim3(256), 0, stream, h16, agg, s12,
        postW + (size_t)i*64*832, postb + i*64, clinW + (size_t)i*4096, clinb + i*64, ybuf);
    hipLaunchKernelGGL(k_bnpart, dim3(512), dim3(256), 0, stream, ybuf, part);
    hipLaunchKernelGGL(k_bnfin, dim3(1), dim3(64), 0, stream, part, bng + i*64, bnb + i*64, bnsc, bnsh);
  }
  hipLaunchKernelGGL(k_bnapply16, dim3(4096), dim3(256), 0, stream, ybuf, h16, bnsc, bnsh);

  hipMemsetAsync(A, 0, (size_t)GG*128*4, stream);
  hipMemsetAsync(cs, 0, (size_t)GG*64*4, stream);
  for (int s = 0; s < 3; ++s){
    hipLaunchKernelGGL(k_lstm_lit, dim3(GG), dim3(256), 0, stream, A, cs, Wih, Whh, bih, bhh);
    hipLaunchKernelGGL(k_edot, dim3(2048), dim3(256), 0, stream, h16, A, batch, escr);
    hipLaunchKernelGGL(k_attn, dim3(GG), dim3(64), 0, stream, h16, escr, gptr, A);
  }
  hipLaunchKernelGGL(k_mlp, dim3(GG), dim3(64), 0, stream, A, tt, pp, W1, b1, W2, b2, W3, b3, (float*)d_out);
}

// Round 15
// 1293.829 us; speedup vs baseline: 3.5186x; 1.0658x over previous
//
#include <hip/hip_runtime.h>
#include <hip/hip_bf16.h>
#include <math.h>

#define NN 131072
#define EE 524288
#define GG 4096

typedef __attribute__((ext_vector_type(8))) _Float16 half8;
typedef __attribute__((ext_vector_type(4))) _Float16 half4;
typedef __attribute__((ext_vector_type(4))) float f32x4;

__device__ __forceinline__ float sigmoidf_(float x){ return 1.0f/(1.0f+expf(-x)); }

// ---- grouping / CSR (integer atomics only) --------------------------------
__global__ void k_gptr(const int* batch, int* gptr){
  int g = blockIdx.x*256+threadIdx.x;
  if (g > GG) return;
  if (g == GG){ gptr[GG]=NN; return; }
  int lo=0, hi=NN;
  while(lo<hi){ int mid=(lo+hi)>>1; if(batch[mid]<g) lo=mid+1; else hi=mid; }
  gptr[g]=lo;
}

__global__ void k_deg(const int* dst, int* deg){
  int e = blockIdx.x*256+threadIdx.x;
  if(e<EE) atomicAdd(&deg[dst[e]], 1);
}

// hierarchical scan
__global__ __launch_bounds__(256) void k_scan_part(const int* deg, int* part){
  __shared__ int red[256];
  int b=blockIdx.x, t=threadIdx.x;
  red[t] = deg[b*256+t];
  __syncthreads();
  for(int off=128; off>0; off>>=1){
    if(t<off) red[t]+=red[t+off];
    __syncthreads();
  }
  if(t==0) part[b]=red[0];
}

__global__ __launch_bounds__(512) void k_scan_top(int* part){
  __shared__ int s[512];
  int t=threadIdx.x;
  s[t]=part[t];
  __syncthreads();
  for(int off=1; off<512; off<<=1){
    int v=s[t];
    int add=(t>=off)?s[t-off]:0;
    __syncthreads();
    s[t]=v+add;
    __syncthreads();
  }
  part[t] = (t==0)?0:s[t-1];
}

__global__ __launch_bounds__(256) void k_scan_apply(const int* deg, const int* part, int* rowptr){
  __shared__ int s[256];
  int b=blockIdx.x, t=threadIdx.x;
  int v0=deg[b*256+t];
  s[t]=v0;
  __syncthreads();
  for(int off=1; off<256; off<<=1){
    int v=s[t];
    int add=(t>=off)?s[t-off]:0;
    __syncthreads();
    s[t]=v+add;
    __syncthreads();
  }
  rowptr[b*256+t] = part[b] + s[t]-v0;
  if(b==511 && t==255) rowptr[NN] = part[b] + s[t];
}

// fill CSR-ordered edge streams
__global__ void k_fill(const int* dst, const int* src, const float* ea,
                       const int* rowptr, int* cursor, int* srcord, float* eaord){
  int e = blockIdx.x*256+threadIdx.x;
  if(e>=EE) return;
  int d = dst[e];
  int pos = atomicAdd(&cursor[d], 1);
  int idx = rowptr[d]+pos;
  srcord[idx] = src[e];
  #pragma unroll
  for(int q=0;q<6;q++) eaord[(size_t)idx*6+q] = ea[(size_t)e*6+q];
}

// ---- y0 = x @ lin1W.T + b (pre-activation) --------------------------------
__global__ __launch_bounds__(256) void k_lin1_s(const float* x, const float* W, const float* b, float* y0){
  __shared__ float sW[2048];
  __shared__ float sb[64];
  int t=threadIdx.x;
  for(int i=t;i<2048;i+=256) sW[i]=W[i];
  if(t<64) sb[t]=b[t];
  __syncthreads();
  int n = blockIdx.x*4 + (t>>6);
  int j = t&63;
  float acc = sb[j];
  for(int k=0;k<32;k++) acc += x[n*32+k]*sW[j*32+k];
  y0[(size_t)n*64+j] = acc;
}

// ---- k_bnmsg: h=relu(y*sc+sh) fp16; g12 = h @ [Wd|Ws].T fp16 (MFMA) -------
// Vectorized staging: thread t -> row t>>2, cols (t&3)*16..+16.
__global__ __launch_bounds__(256) void k_bnmsg(const float* y, const float* sc, const float* sh,
      const float* preW, _Float16* h16, _Float16* g12){
  __shared__ _Float16 sAh[64][72];
  __shared__ _Float16 sB0[64][72];
  __shared__ _Float16 sB1[64][72];
  __shared__ float ssc[64], ssh[64];
  int t=threadIdx.x;
  int rb = blockIdx.x*64;
  if(t<64){ ssc[t] = sc? sc[t] : 1.0f; ssh[t] = sh? sh[t] : 0.0f; }
  __syncthreads();
  int sr = t>>2, c0 = (t&3)*16;
  {
    const float* yr = &y[(size_t)(rb+sr)*64 + c0];
    float4 q0 = *(const float4*)&yr[0];
    float4 q1 = *(const float4*)&yr[4];
    float4 q2 = *(const float4*)&yr[8];
    float4 q3 = *(const float4*)&yr[12];
    float vv[16] = {q0.x,q0.y,q0.z,q0.w, q1.x,q1.y,q1.z,q1.w,
                    q2.x,q2.y,q2.z,q2.w, q3.x,q3.y,q3.z,q3.w};
    half8 h0, h1;
    #pragma unroll
    for(int q=0;q<8;q++){
      h0[q] = (_Float16)fmaxf(vv[q]  *ssc[c0+q]   + ssh[c0+q],   0.0f);
      h1[q] = (_Float16)fmaxf(vv[8+q]*ssc[c0+8+q] + ssh[c0+8+q], 0.0f);
    }
    *(half8*)&sAh[sr][c0]   = h0;
    *(half8*)&sAh[sr][c0+8] = h1;
    *(half8*)&h16[(size_t)(rb+sr)*64 + c0]     = h0;
    *(half8*)&h16[(size_t)(rb+sr)*64 + c0 + 8] = h1;
    // B matrices: sB0[c][k]=preW[c*192+k], sB1[c][k]=preW[c*192+64+k]; c=sr, k=c0..
    const float* w0 = &preW[(size_t)sr*192 + c0];
    const float* w1 = &preW[(size_t)sr*192 + 64 + c0];
    float4 a0=*(const float4*)&w0[0], a1=*(const float4*)&w0[4], a2=*(const float4*)&w0[8], a3=*(const float4*)&w0[12];
    float4 b0=*(const float4*)&w1[0], b1=*(const float4*)&w1[4], b2=*(const float4*)&w1[8], b3=*(const float4*)&w1[12];
    half8 w0h, w0h2, w1h, w1h2;
    float wa[16]={a0.x,a0.y,a0.z,a0.w,a1.x,a1.y,a1.z,a1.w,a2.x,a2.y,a2.z,a2.w,a3.x,a3.y,a3.z,a3.w};
    float wb[16]={b0.x,b0.y,b0.z,b0.w,b1.x,b1.y,b1.z,b1.w,b2.x,b2.y,b2.z,b2.w,b3.x,b3.y,b3.z,b3.w};
    #pragma unroll
    for(int q=0;q<8;q++){ w0h[q]=(_Float16)wa[q]; w0h2[q]=(_Float16)wa[8+q]; w1h[q]=(_Float16)wb[q]; w1h2[q]=(_Float16)wb[8+q]; }
    *(half8*)&sB0[sr][c0]   = w0h;  *(half8*)&sB0[sr][c0+8] = w0h2;
    *(half8*)&sB1[sr][c0]   = w1h;  *(half8*)&sB1[sr][c0+8] = w1h2;
  }
  __syncthreads();
  int w=t>>6, l=t&63;
  f32x4 acc0[4]={}, acc1[4]={};
  #pragma unroll
  for(int kk=0; kk<2; ++kk){
    half8 a = *(const half8*)&sAh[w*16+(l&15)][kk*32+(l>>4)*8];
    #pragma unroll
    for(int n16=0;n16<4;++n16){
      half8 b0 = *(const half8*)&sB0[n16*16+(l&15)][kk*32+(l>>4)*8];
      half8 b1 = *(const half8*)&sB1[n16*16+(l&15)][kk*32+(l>>4)*8];
      acc0[n16] = __builtin_amdgcn_mfma_f32_16x16x32_f16(a,b0,acc0[n16],0,0,0);
      acc1[n16] = __builtin_amdgcn_mfma_f32_16x16x32_f16(a,b1,acc1[n16],0,0,0);
    }
  }
  #pragma unroll
  for(int n16=0;n16<4;++n16){
    #pragma unroll
    for(int reg=0; reg<4; ++reg){
      int row = w*16+(l>>4)*4+reg;
      int col = n16*16+(l&15);
      g12[(size_t)(rb+row)*128 + col]      = (_Float16)acc0[n16][reg];
      g12[(size_t)(rb+row)*128 + 64 + col] = (_Float16)acc1[n16][reg];
    }
  }
}

// ---- gather: 2-node x 2-edge interleave (4 loads in flight) ---------------
__global__ __launch_bounds__(256) void k_gather_f(const int* rowptr, const int* srcord,
      const float* eaord, const _Float16* g12, const float* preW, const float* preb,
      const float* eW, const float* eb, _Float16* agg, float* s12, float avgdl){
  __shared__ float sWf[64][6];
  __shared__ float sbf[64];
  int t=threadIdx.x;
  for(int i=t; i<384; i+=256){
    int j=i/6, d=i-j*6;
    float a=0.0f;
    for(int k=0;k<64;k++) a += preW[j*192+128+k]*eW[k*6+d];
    sWf[j][d]=a;
  }
  if(t<64){
    float a=preb[t];
    for(int k=0;k<64;k++) a += preW[t*192+128+k]*eb[k];
    sbf[t]=a;
  }
  __syncthreads();
  int w=t>>6, j=t&63;
  float wf0=sWf[j][0], wf1=sWf[j][1], wf2=sWf[j][2];
  float wf3=sWf[j][3], wf4=sWf[j][4], wf5=sWf[j][5];
  float bfj=sbf[j];
  auto edot6=[&](int idx)->float{
    float2 a0=*(const float2*)&eaord[(size_t)idx*6];
    float2 a1=*(const float2*)&eaord[(size_t)idx*6+2];
    float2 a2=*(const float2*)&eaord[(size_t)idx*6+4];
    return a0.x*wf0+a0.y*wf1+a1.x*wf2+a1.y*wf3+a2.x*wf4+a2.y*wf5;
  };
  for(int it=0; it<8; it+=2){
    int nA = (blockIdx.x*4+w) + it*16384;
    int nB = nA + 16384;
    int loA=rowptr[nA], hiA=rowptr[nA+1];
    int loB=rowptr[nB], hiB=rowptr[nB+1];
    float mdA = (float)g12[(size_t)nA*128+j] + bfj;
    float mdB = (float)g12[(size_t)nB*128+j] + bfj;
    float sumA=0.0f,sqA=0.0f,mnA=1e30f,mxA=-1e30f;
    float sumB=0.0f,sqB=0.0f,mnB=1e30f,mxB=-1e30f;
    int ia=loA, ib=loB;
    while(ia+1<hiA && ib+1<hiB){
      int sa0=srcord[ia], sa1=srcord[ia+1];
      int sb0=srcord[ib], sb1=srcord[ib+1];
      float ga0=(float)g12[(size_t)sa0*128+64+j];
      float ga1=(float)g12[(size_t)sa1*128+64+j];
      float gb0=(float)g12[(size_t)sb0*128+64+j];
      float gb1=(float)g12[(size_t)sb1*128+64+j];
      float m0 = mdA + ga0 + edot6(ia);
      float m1 = mdA + ga1 + edot6(ia+1);
      float p0 = mdB + gb0 + edot6(ib);
      float p1 = mdB + gb1 + edot6(ib+1);
      sumA += m0; sqA += m0*m0; mnA=fminf(mnA,m0); mxA=fmaxf(mxA,m0);
      sumA += m1; sqA += m1*m1; mnA=fminf(mnA,m1); mxA=fmaxf(mxA,m1);
      sumB += p0; sqB += p0*p0; mnB=fminf(mnB,p0); mxB=fmaxf(mxB,p0);
      sumB += p1; sqB += p1*p1; mnB=fminf(mnB,p1); mxB=fmaxf(mxB,p1);
      ia+=2; ib+=2;
    }
    for(; ia+1<hiA; ia+=2){
      int s0=srcord[ia], s1=srcord[ia+1];
      float g0=(float)g12[(size_t)s0*128+64+j];
      float g1=(float)g12[(size_t)s1*128+64+j];
      float m0 = mdA + g0 + edot6(ia);
      float m1 = mdA + g1 + edot6(ia+1);
      sumA += m0; sqA += m0*m0; mnA=fminf(mnA,m0); mxA=fmaxf(mxA,m0);
      sumA += m1; sqA += m1*m1; mnA=fminf(mnA,m1); mxA=fmaxf(mxA,m1);
    }
    if(ia<hiA){
      int s0=srcord[ia];
      float g0=(float)g12[(size_t)s0*128+64+j];
      float m0 = mdA + g0 + edot6(ia);
      sumA += m0; sqA += m0*m0; mnA=fminf(mnA,m0); mxA=fmaxf(mxA,m0);
    }
    for(; ib+1<hiB; ib+=2){
      int s0=srcord[ib], s1=srcord[ib+1];
      float g0=(float)g12[(size_t)s0*128+64+j];
      float g1=(float)g12[(size_t)s1*128+64+j];
      float p0 = mdB + g0 + edot6(ib);
      float p1 = mdB + g1 + edot6(ib+1);
      sumB += p0; sqB += p0*p0; mnB=fminf(mnB,p0); mxB=fmaxf(mxB,p0);
      sumB += p1; sqB += p1*p1; mnB=fminf(mnB,p1); mxB=fmaxf(mxB,p1);
    }
    if(ib<hiB){
      int s0=srcord[ib];
      float g0=(float)g12[(size_t)s0*128+64+j];
      float p0 = mdB + g0 + edot6(ib);
      sumB += p0; sqB += p0*p0; mnB=fminf(mnB,p0); mxB=fmaxf(mxB,p0);
    }
    // finalize A
    {
      int c = hiA-loA;
      float cm = fmaxf((float)c, 1.0f);
      float mean = sumA/cm;
      float sd = sqrtf(fmaxf(sqA/cm - mean*mean, 0.0f)+1e-5f);
      bool has = c>0;
      size_t base = (size_t)nA*256;
      agg[base+j]     = (_Float16)mean;
      agg[base+64+j]  = (_Float16)(has?mnA:0.0f);
      agg[base+128+j] = (_Float16)(has?mxA:0.0f);
      agg[base+192+j] = (_Float16)sd;
      if(j==0){ float ld=logf(cm+1.0f); s12[nA*2]=ld/avgdl; s12[nA*2+1]=avgdl/ld; }
    }
    // finalize B
    {
      int c = hiB-loB;
      float cm = fmaxf((float)c, 1.0f);
      float mean = sumB/cm;
      float sd = sqrtf(fmaxf(sqB/cm - mean*mean, 0.0f)+1e-5f);
      bool has = c>0;
      size_t base = (size_t)nB*256;
      agg[base+j]     = (_Float16)mean;
      agg[base+64+j]  = (_Float16)(has?mnB:0.0f);
      agg[base+128+j] = (_Float16)(has?mxB:0.0f);
      agg[base+192+j] = (_Float16)sd;
      if(j==0){ float ld=logf(cm+1.0f); s12[nB*2]=ld/avgdl; s12[nB*2+1]=avgdl/ld; }
    }
  }
}

// ---- k_tower_mfma: vectorized staging + fp16 MFMA -------------------------
__global__ __launch_bounds__(256) void k_tower_mfma(const _Float16* h16, const _Float16* agg, const float* s12,
        const float* poW, const float* pob, const float* clW, const float* clb, float* y2){
  __shared__ _Float16 sAh[64][72];
  __shared__ _Float16 sBh[64][72];
  __shared__ float sS[128];
  int t = threadIdx.x;
  int rb = blockIdx.x*64;
  int w = t>>6, l = t&63;
  int sr = t>>2, c0 = (t&3)*16;
  if (t < 128) sS[t] = s12[(size_t)(rb+(t>>1))*2 + (t&1)];
  f32x4 acc[4] = {};
  for (int kt=0; kt<13; ++kt){
    __syncthreads();
    // ---- A' tile: rows sr, cols c0..c0+16 ----
    half8 h0, h1;
    if (kt==0){
      h0 = *(const half8*)&h16[(size_t)(rb+sr)*64 + c0];
      h1 = *(const half8*)&h16[(size_t)(rb+sr)*64 + c0 + 8];
    } else if (kt<5){
      h0 = *(const half8*)&agg[(size_t)(rb+sr)*256 + (kt-1)*64 + c0];
      h1 = *(const half8*)&agg[(size_t)(rb+sr)*256 + (kt-1)*64 + c0 + 8];
    } else {
      int off = (kt<9)? (kt-5)*64 : (kt-9)*64;
      float s = (kt<9)? sS[sr*2] : sS[sr*2+1];
      half8 p0 = *(const half8*)&agg[(size_t)(rb+sr)*256 + off + c0];
      half8 p1 = *(const half8*)&agg[(size_t)(rb+sr)*256 + off + c0 + 8];
      #pragma unroll
      for(int q=0;q<8;q++){ h0[q]=(_Float16)(s*(float)p0[q]); h1[q]=(_Float16)(s*(float)p1[q]); }
    }
    *(half8*)&sAh[sr][c0]   = h0;
    *(half8*)&sAh[sr][c0+8] = h1;
    // ---- B tile: sBh[c][k] = poW[c*832 + kt*64 + k]; c=sr, k=c0.. ----
    {
      const float* wr = &poW[(size_t)sr*832 + kt*64 + c0];
      float4 a0=*(const float4*)&wr[0], a1=*(const float4*)&wr[4], a2=*(const float4*)&wr[8], a3=*(const float4*)&wr[12];
      float wa[16]={a0.x,a0.y,a0.z,a0.w,a1.x,a1.y,a1.z,a1.w,a2.x,a2.y,a2.z,a2.w,a3.x,a3.y,a3.z,a3.w};
      half8 b0, b1;
      #pragma unroll
      for(int q=0;q<8;q++){ b0[q]=(_Float16)wa[q]; b1[q]=(_Float16)wa[8+q]; }
      *(half8*)&sBh[sr][c0]   = b0;
      *(half8*)&sBh[sr][c0+8] = b1;
    }
    __syncthreads();
    #pragma unroll
    for (int kk=0; kk<2; ++kk){
      half8 a = *(const half8*)&sAh[w*16 + (l&15)][kk*32 + (l>>4)*8];
      #pragma unroll
      for (int n16=0; n16<4; ++n16){
        half8 b = *(const half8*)&sBh[n16*16 + (l&15)][kk*32 + (l>>4)*8];
        acc[n16] = __builtin_amdgcn_mfma_f32_16x16x32_f16(a, b, acc[n16], 0, 0, 0);
      }
    }
  }
  __syncthreads();
  // y1 (+bias) -> fp16 into sAh (D layout: col=lane&15, row=(lane>>4)*4+reg)
  #pragma unroll
  for (int n16=0; n16<4; ++n16){
    #pragma unroll
    for (int reg=0; reg<4; ++reg){
      int row = w*16 + (l>>4)*4 + reg;
      int col = n16*16 + (l&15);
      sAh[row][col] = (_Float16)(acc[n16][reg] + pob[col]);
    }
  }
  // clinW staging (vectorized)
  {
    const float* wr = &clW[(size_t)sr*64 + c0];
    float4 a0=*(const float4*)&wr[0], a1=*(const float4*)&wr[4], a2=*(const float4*)&wr[8], a3=*(const float4*)&wr[12];
    float wa[16]={a0.x,a0.y,a0.z,a0.w,a1.x,a1.y,a1.z,a1.w,a2.x,a2.y,a2.z,a2.w,a3.x,a3.y,a3.z,a3.w};
    half8 b0, b1;
    #pragma unroll
    for(int q=0;q<8;q++){ b0[q]=(_Float16)wa[q]; b1[q]=(_Float16)wa[8+q]; }
    *(half8*)&sBh[sr][c0]   = b0;
    *(half8*)&sBh[sr][c0+8] = b1;
  }
  __syncthreads();
  f32x4 cacc[4] = {};
  #pragma unroll
  for (int kk=0; kk<2; ++kk){
    half8 a = *(const half8*)&sAh[w*16 + (l&15)][kk*32 + (l>>4)*8];
    #pragma unroll
    for (int n16=0; n16<4; ++n16){
      half8 b = *(const half8*)&sBh[n16*16 + (l&15)][kk*32 + (l>>4)*8];
      cacc[n16] = __builtin_amdgcn_mfma_f32_16x16x32_f16(a, b, cacc[n16], 0, 0, 0);
    }
  }
  #pragma unroll
  for (int n16=0; n16<4; ++n16){
    #pragma unroll
    for (int reg=0; reg<4; ++reg){
      int row = w*16 + (l>>4)*4 + reg;
      int col = n16*16 + (l&15);
      y2[(size_t)(rb+row)*64 + col] = cacc[n16][reg] + clb[col];
    }
  }
}

// ---- BN: partials (double, no atomics) -> finalize ------------------------
__global__ __launch_bounds__(256) void k_bnpart(const float* y, double* part){
  __shared__ double sS[256], sQ[256];
  int t=threadIdx.x;
  int c=t&63, q=t>>6;
  int b=blockIdx.x;
  double s=0.0, s2=0.0;
  for(int i=0;i<64;i++){
    int n = b*256 + q + i*4;
    double v = (double)y[(size_t)n*64+c];
    s += v; s2 += v*v;
  }
  sS[t]=s; sQ[t]=s2;
  __syncthreads();
  if(t<64){
    double S=sS[t]+sS[t+64]+sS[t+128]+sS[t+192];
    double Q=sQ[t]+sQ[t+64]+sQ[t+128]+sQ[t+192];
    part[b*128+t]=S; part[b*128+64+t]=Q;
  }
}

__global__ void k_bnfin(const double* part, const float* g, const float* bb, float* sc, float* sh){
  int c = threadIdx.x;
  if(c>=64) return;
  double S=0.0, Q=0.0;
  for(int b=0;b<512;b++){ S+=part[b*128+c]; Q+=part[b*128+64+c]; }
  double mean = S/(double)NN;
  double var  = Q/(double)NN - mean*mean;
  float scale = g[c] * (float)(1.0/sqrt(var+1e-5));
  sc[c]=scale;
  sh[c]=bb[c] - (float)mean*scale;
}

// ---- final BN apply -> h16 (for set2set) ----------------------------------
__global__ void k_bnapply16(const float* y, _Float16* h16, const float* sc, const float* sh){
  int idx = blockIdx.x*256+threadIdx.x;
  const float4* y4=(const float4*)y;
  for(int i=idx; i<NN*16; i+=256*4096){
    int c4=(i&15)*4;
    float4 v=y4[i];
    half4 r;
    r.x=(_Float16)fmaxf(v.x*sc[c4+0]+sh[c4+0],0.0f);
    r.y=(_Float16)fmaxf(v.y*sc[c4+1]+sh[c4+1],0.0f);
    r.z=(_Float16)fmaxf(v.z*sc[c4+2]+sh[c4+2],0.0f);
    r.w=(_Float16)fmaxf(v.w*sc[c4+3]+sh[c4+3],0.0f);
    *(half4*)&h16[(size_t)i*4] = r;
  }
}

// ---- set2set (literal LSTM: raw Wih/Whh) ----------------------------------
__global__ __launch_bounds__(256) void k_lstm_lit(float* A, float* cs,
      const float* Wih, const float* Whh, const float* bih, const float* bhh){
  __shared__ float sA[128]; __shared__ float sg[256];
  int g=blockIdx.x, t=threadIdx.x;
  if(t<128) sA[t]=A[g*128+t];
  __syncthreads();
  float a = bih[t] + bhh[t];
  for(int k=0;k<128;k++) a += Wih[t*128+k]*sA[k];
  for(int k=0;k<64;k++)  a += Whh[t*64+k]*sA[k];
  sg[t]=a;
  __syncthreads();
  if(t<64){
    float ig=sg[t], fg=sg[64+t], gg=sg[128+t], og=sg[192+t];
    float c = sigmoidf_(fg)*cs[g*64+t] + sigmoidf_(ig)*tanhf(gg);
    float hv = sigmoidf_(og)*tanhf(c);
    cs[g*64+t]=c;
    A[g*128+t]=hv;
  }
}

__global__ __launch_bounds__(256) void k_edot(const _Float16* h16, const float* A, const int* batch, float* e){
  int t=threadIdx.x, w=t>>6, j=t&63;
  for(int it=0;it<16;++it){
    int n=(blockIdx.x*4+w)+it*8192;
    int g=batch[n];
    float v=(float)h16[(size_t)n*64+j]*A[g*128+j];
    #pragma unroll
    for(int m=32;m;m>>=1) v+=__shfl_xor(v,m,64);
    if(j==0) e[n]=v;
  }
}

__global__ __launch_bounds__(64) void k_attn(const _Float16* h16, const float* e, const int* gptr, float* A){
  int g=blockIdx.x, j=threadIdx.x;
  int lo=gptr[g], hi=gptr[g+1];
  if(lo>=hi){ A[g*128+64+j]=0.0f; return; }
  float mx=-1e30f;
  for(int n=lo+j;n<hi;n+=64) mx=fmaxf(mx,e[n]);
  #pragma unroll
  for(int m=32;m;m>>=1) mx=fmaxf(mx,__shfl_xor(mx,m,64));
  float s=0.0f;
  for(int n=lo+j;n<hi;n+=64) s+=expf(e[n]-mx);
  #pragma unroll
  for(int m=32;m;m>>=1) s+=__shfl_xor(s,m,64);
  float inv=1.0f/(s+1e-16f);
  float r=0.0f;
  for(int n=lo;n<hi;++n){
    float a=expf(e[n]-mx)*inv;
    r+=a*(float)h16[(size_t)n*64+j];
  }
  A[g*128+64+j]=r;
}

__global__ __launch_bounds__(64) void k_mlp(const float* A, const float* tt, const float* pp,
     const float* W1,const float* b1,const float* W2,const float* b2,const float* W3,const float* b3,
     float* out){
  __shared__ float si[130]; __shared__ float o1[64]; __shared__ float o2[32];
  int g=blockIdx.x, t=threadIdx.x;
  si[t]=A[g*128+t]; si[64+t]=A[g*128+64+t];
  if(t==0){ si[128]=tt[g]; si[129]=pp[g]; }
  __syncthreads();
  float a=b1[t];
  for(int k=0;k<130;k++) a+=W1[t*130+k]*si[k];
  o1[t]=fmaxf(a,0.0f);
  __syncthreads();
  if(t<32){
    float a2=b2[t];
    #pragma unroll 4
    for(int k=0;k<64;k++) a2+=W2[t*64+k]*o1[k];
    o2[t]=fmaxf(a2,0.0f);
  }
  __syncthreads();
  float v = (t<32)? o2[t]*W3[t] : 0.0f;
  #pragma unroll
  for(int m=32;m;m>>=1) v+=__shfl_xor(v,m,64);
  if(t==0) out[g]=v+b3[0];
}

// ---- host -----------------------------------------------------------------
extern "C" void kernel_launch(void* const* d_in, const int* in_sizes, int n_in,
                              void* d_out, int out_size, void* d_ws, size_t ws_size,
                              hipStream_t stream) {
  static const int want[28] = {4194304,3145728,4096,4096,2048,64,1152,192,36864,192,
                               159744,192,12288,192,192,192,32768,16384,256,256,
                               8320,64,2048,32,32,1,1048576,131072};
  if (n_in != 28 || out_size != GG) return;
  for (int i=0;i<28;i++) if (in_sizes[i] != want[i]) return;

  const float* x     = (const float*)d_in[0];
  const float* ea    = (const float*)d_in[1];
  const float* tt    = (const float*)d_in[2];
  const float* pp    = (const float*)d_in[3];
  const float* lin1W = (const float*)d_in[4];
  const float* lin1b = (const float*)d_in[5];
  const float* edgeW = (const float*)d_in[6];
  const float* edgeb = (const float*)d_in[7];
  const float* preW  = (const float*)d_in[8];
  const float* preb  = (const float*)d_in[9];
  const float* postW = (const float*)d_in[10];
  const float* postb = (const float*)d_in[11];
  const float* clinW = (const float*)d_in[12];
  const float* clinb = (const float*)d_in[13];
  const float* bng   = (const float*)d_in[14];
  const float* bnb   = (const float*)d_in[15];
  const float* Wih   = (const float*)d_in[16];
  const float* Whh   = (const float*)d_in[17];
  const float* bih   = (const float*)d_in[18];
  const float* bhh   = (const float*)d_in[19];
  const float* W1    = (const float*)d_in[20];
  const float* b1    = (const float*)d_in[21];
  const float* W2    = (const float*)d_in[22];
  const float* b2    = (const float*)d_in[23];
  const float* W3    = (const float*)d_in[24];
  const float* b3    = (const float*)d_in[25];
  const int*   eidx  = (const int*)d_in[26];
  const int*   batch = (const int*)d_in[27];
  const int* esrc = eidx;
  const int* edst = eidx + EE;

  char* w = (char*)d_ws;
  auto alloc = [&](size_t bytes)->char*{ char* p=w; w += ((bytes+255)/256)*256; return p; };
  _Float16* agg  = (_Float16*)alloc((size_t)NN*256*2);  // 64MiB fp16
  _Float16* g12  = (_Float16*)alloc((size_t)NN*128*2);  // 32MiB fp16 (ybuf fp32 aliases)
  _Float16* h16  = (_Float16*)alloc((size_t)NN*64*2);   // 16MiB fp16
  int*   deg    = (int*)alloc((size_t)NN*4);
  int*   cursor = (int*)alloc((size_t)NN*4);
  int*   rowptr = (int*)alloc((size_t)(NN+1)*4);
  int*   spart  = (int*)alloc(512*4);
  int*   srcord = (int*)alloc((size_t)EE*4);
  float* eaord  = (float*)alloc((size_t)EE*6*4);
  float* s12   = (float*)alloc((size_t)NN*2*4);
  double* part = (double*)alloc((size_t)512*128*8);
  float* bnsc  = (float*)alloc(256);
  float* bnsh  = (float*)alloc(256);
  int*   gptr  = (int*)alloc((GG+1)*4);
  size_t need = (size_t)(w - (char*)d_ws);
  if (need > ws_size) return;
  float* ybuf = (float*)g12;
  float* A    = (float*)g12;
  float* cs   = (float*)g12 + (size_t)GG*128;
  float* escr = (float*)g12 + (size_t)GG*192;

  double num = 13107.0*log(2.0)+26214.0*log(3.0)+65536.0*log(4.0)+26215.0*log(5.0);
  float avgdl = (float)(num/131072.0);

  hipMemsetAsync(deg, 0, (size_t)NN*4, stream);
  hipMemsetAsync(cursor, 0, (size_t)NN*4, stream);
  hipLaunchKernelGGL(k_deg, dim3(2048), dim3(256), 0, stream, edst, deg);
  hipLaunchKernelGGL(k_scan_part, dim3(512), dim3(256), 0, stream, deg, spart);
  hipLaunchKernelGGL(k_scan_top, dim3(1), dim3(512), 0, stream, spart);
  hipLaunchKernelGGL(k_scan_apply, dim3(512), dim3(256), 0, stream, deg, spart, rowptr);
  hipLaunchKernelGGL(k_fill, dim3(2048), dim3(256), 0, stream, edst, esrc, ea, rowptr, cursor, srcord, eaord);

  hipLaunchKernelGGL(k_gptr, dim3(17), dim3(256), 0, stream, batch, gptr);
  hipLaunchKernelGGL(k_lin1_s, dim3(32768), dim3(256), 0, stream, x, lin1W, lin1b, ybuf);

  for (int i = 0; i < 3; ++i){
    const float* sc_i = (i==0)? nullptr : bnsc;
    const float* sh_i = (i==0)? nullptr : bnsh;
    hipLaunchKernelGGL(k_bnmsg, dim3(2048), dim3(256), 0, stream, ybuf, sc_i, sh_i,
        preW + (size_t)i*64*192, h16, g12);
    hipLaunchKernelGGL(k_gather_f, dim3(4096), dim3(256), 0, stream, rowptr, srcord, eaord, g12,
        preW + (size_t)i*64*192, preb + i*64, edgeW + (size_t)i*384, edgeb + i*64, agg, s12, avgdl);
    hipLaunchKernelGGL(k_tower_mfma, dim3(2048), dim3(256), 0, stream, h16, agg, s12,
        postW + (size_t)i*64*832, postb + i*64, clinW + (size_t)i*4096, clinb + i*64, ybuf);
    hipLaunchKernelGGL(k_bnpart, dim3(512), dim3(256), 0, stream, ybuf, part);
    hipLaunchKernelGGL(k_bnfin, dim3(1), dim3(64), 0, stream, part, bng + i*64, bnb + i*64, bnsc, bnsh);
  }
  hipLaunchKernelGGL(k_bnapply16, dim3(4096), dim3(256), 0, stream, ybuf, h16, bnsc, bnsh);

  hipMemsetAsync(A, 0, (size_t)GG*128*4, stream);
  hipMemsetAsync(cs, 0, (size_t)GG*64*4, stream);
  for (int s = 0; s < 3; ++s){
    hipLaunchKernelGGL(k_lstm_lit, dim3(GG), dim3(256), 0, stream, A, cs, Wih, Whh, bih, bhh);
    hipLaunchKernelGGL(k_edot, dim3(2048), dim3(256), 0, stream, h16, A, batch, escr);
    hipLaunchKernelGGL(k_attn, dim3(GG), dim3(64), 0, stream, h16, escr, gptr, A);
  }
  hipLaunchKernelGGL(k_mlp, dim3(GG), dim3(64), 0, stream, A, tt, pp, W1, b1, W2, b2, W3, b3, (float*)d_out);
}